// Round 8
// baseline (623.693 us; speedup 1.0000x reference)
//
#include <hip/hip_runtime.h>
#include <stdint.h>

typedef unsigned short u16;
typedef __attribute__((ext_vector_type(8))) short bf16x8;
typedef __attribute__((ext_vector_type(4))) float f32x4;

static const int N_NODES = 131072;   // B*T*NN = 128*128*8
static const int N_EDGES = 1048576;

__device__ __forceinline__ float u2f(u16 u){
  union{uint32_t i; float f;} w; w.i = ((uint32_t)u)<<16; return w.f;
}
__device__ __forceinline__ u16 f2u(float f){
  union{float f; uint32_t u;} v; v.f=f;
  uint32_t u=v.u;
  u += 0x7fff + ((u>>16)&1);   // round-to-nearest-even
  return (u16)(u>>16);
}
// internal-buffer typed access
__device__ __forceinline__ float ldv(const float* p, int i){ return p[i]; }
__device__ __forceinline__ float ldv(const u16* p, int i){ return u2f(p[i]); }
__device__ __forceinline__ void stv(float* p, int i, float v){ p[i]=v; }
__device__ __forceinline__ void stv(u16* p, int i, float v){ p[i]=f2u(v); }
__device__ __forceinline__ float4 ld4(const float* p, int i){ return *(const float4*)(p+i); }
__device__ __forceinline__ float4 ld4(const u16* p, int i){
  ushort4 u = *(const ushort4*)(p+i);
  return make_float4(u2f(u.x), u2f(u.y), u2f(u.z), u2f(u.w));
}
__device__ __forceinline__ void st4(float* p, int i, float4 v){ *(float4*)(p+i) = v; }
__device__ __forceinline__ void st4(u16* p, int i, float4 v){
  p[i]=f2u(v.x); p[i+1]=f2u(v.y); p[i+2]=f2u(v.z); p[i+3]=f2u(v.w);
}
// external-input access, runtime dtype
__device__ __forceinline__ float ldmix(const void* p, int i, int isbf){
  return isbf ? u2f(((const u16*)p)[i]) : ((const float*)p)[i];
}
__device__ __forceinline__ float4 ld4mix(const void* p, int i, int isbf){
  if (isbf){ return ld4((const u16*)p, i); }
  return ld4((const float*)p, i);
}

// ---------------- dtype detection ----------------
__global__ void k_detect(const uint32_t* __restrict__ x, int* __restrict__ flag){
  if (threadIdx.x==0 && blockIdx.x==0){
    int cnt=0;
    for (int i=0;i<256;i++){
      uint32_t e=(x[i]>>7)&0xFFu;
      if (e>=0x6Fu && e<=0x85u) cnt++;
    }
    *flag = (cnt>=128) ? 1 : 0;
  }
}

// ---------------- graph prep: bucket counting sort ----------------
// bucket = dst >> 7 (1024 buckets x 128 nodes). Edge packed: src(17b) | dstLow7 << 17.
__global__ __launch_bounds__(256) void k_bcount(const int* __restrict__ dst, int* __restrict__ bcnt){
  __shared__ int h[1024];
  int tid = threadIdx.x;
  for (int i=tid;i<1024;i+=256) h[i]=0;
  __syncthreads();
  int base = blockIdx.x*4096;
  #pragma unroll
  for (int i=0;i<16;i++){
    int e = base + i*256 + tid;
    atomicAdd(&h[(dst[e] & (N_NODES-1))>>7], 1);
  }
  __syncthreads();
  for (int i=tid;i<1024;i+=256) if (h[i]) atomicAdd(&bcnt[i], h[i]);
}

__global__ __launch_bounds__(1024) void k_bscan(const int* __restrict__ bcnt, int* __restrict__ barr,
                                                int* __restrict__ cur){
  __shared__ int sc[1024];
  int t = threadIdx.x;
  int v = bcnt[t]; sc[t]=v; __syncthreads();
  for (int d=1; d<1024; d<<=1){
    int o = (t>=d) ? sc[t-d] : 0; __syncthreads();
    sc[t] += o; __syncthreads();
  }
  int ex = sc[t]-v;
  barr[t] = ex; cur[t] = ex;
  if (t==1023) barr[1024] = sc[t];
}

__global__ __launch_bounds__(256) void k_bscatter(const int* __restrict__ src, const int* __restrict__ dst,
                                                  int* __restrict__ cur, uint32_t* __restrict__ ebuf){
  int base = blockIdx.x*1024;
  #pragma unroll
  for (int i=0;i<4;i++){
    int e = base + i*256 + threadIdx.x;
    int s = src[e] & (N_NODES-1);
    int d = dst[e] & (N_NODES-1);
    int b = d >> 7;
    int pos = atomicAdd(&cur[b], 1);
    ebuf[pos] = (uint32_t)s | ((uint32_t)(d & 127) << 17);
  }
}

// per-bucket counting sort by node-low7 + emit offs/deg/dinv + fused dinv-prescale of x (F=32)
template<typename T>
__global__ __launch_bounds__(256) void k_bsort(const uint32_t* __restrict__ ebuf, const int* __restrict__ barr,
                                               const void* __restrict__ x, const int* __restrict__ flag,
                                               int* __restrict__ adj, int* __restrict__ offs,
                                               int* __restrict__ deg, float* __restrict__ dinv,
                                               T* __restrict__ Bout){
  __shared__ uint32_t ein[2048], outs[2048];
  __shared__ int hist[128], sc[128], cu[128];
  __shared__ float dv[128];
  int b = blockIdx.x, tid = threadIdx.x;
  int lo = barr[b], hi = barr[b+1];
  int cnt = hi - lo; if (cnt > 2048) cnt = 2048; if (cnt < 0) cnt = 0;
  if (tid < 128) hist[tid] = 0;
  __syncthreads();
  for (int i=tid; i<cnt; i+=256){
    uint32_t p = ebuf[lo+i];
    ein[i] = p;
    atomicAdd(&hist[(p>>17)&127], 1);
  }
  __syncthreads();
  if (tid < 128) sc[tid] = hist[tid];
  __syncthreads();
  for (int d=1; d<128; d<<=1){
    int v = 0;
    if (tid < 128 && tid >= d) v = sc[tid-d];
    __syncthreads();
    if (tid < 128) sc[tid] += v;
    __syncthreads();
  }
  if (tid < 128){
    int ex = sc[tid] - hist[tid];
    int node = b*128 + tid;
    offs[node] = lo + ex;
    deg[node]  = hist[tid];
    float rs = rsqrtf((float)hist[tid] + 1.0f);
    dinv[node] = rs;
    dv[tid] = rs;
    cu[tid] = ex;
  }
  __syncthreads();
  for (int i=tid; i<cnt; i+=256){
    uint32_t p = ein[i];
    int pos = atomicAdd(&cu[(p>>17)&127], 1);
    outs[pos] = p & 0x1FFFFu;
  }
  __syncthreads();
  for (int i=tid; i<cnt; i+=256) adj[lo+i] = (int)outs[i];
  // fused prescale: Bout[node,c] = dinv[node]*x[node,c], nodes of this bucket
  int isbf = *flag;
  for (int u=tid; u<4096; u+=256){
    int nl = u>>5, c = u&31;
    int idx = ((b<<7) + nl)*32 + c;
    stv(Bout, idx, dv[nl]*ldmix(x, idx, isbf));
  }
}

// ---- GCN aggregation on prescaled rows: out[n] = dinv[n]*(Xs[n] + sum_in Xs[s]) ----
template<int F, typename T>
__global__ __launch_bounds__(256) void k_aggp(const T* __restrict__ Xs,
                                              const int* __restrict__ adj, const int* __restrict__ offs,
                                              const int* __restrict__ deg, const float* __restrict__ dinv,
                                              T* __restrict__ out){
  constexpr int LOG = (F==64) ? 6 : 5;
  int c = threadIdx.x & (F-1);
  int slot = threadIdx.x >> LOG;
  int n = blockIdx.x*(256>>LOG) + slot;
  int o = offs[n] & (N_EDGES-1);
  int cnt = min(deg[n], 8192);
  float acc = ldv(Xs, (n<<LOG)+c);            // prescaled self term
  int e = 0;
  for (; e+8 <= cnt; e += 8){
    int s0 = adj[o+e+0] & (N_NODES-1);
    int s1 = adj[o+e+1] & (N_NODES-1);
    int s2 = adj[o+e+2] & (N_NODES-1);
    int s3 = adj[o+e+3] & (N_NODES-1);
    int s4 = adj[o+e+4] & (N_NODES-1);
    int s5 = adj[o+e+5] & (N_NODES-1);
    int s6 = adj[o+e+6] & (N_NODES-1);
    int s7 = adj[o+e+7] & (N_NODES-1);
    float x0 = ldv(Xs, (s0<<LOG)+c);
    float x1 = ldv(Xs, (s1<<LOG)+c);
    float x2 = ldv(Xs, (s2<<LOG)+c);
    float x3 = ldv(Xs, (s3<<LOG)+c);
    float x4 = ldv(Xs, (s4<<LOG)+c);
    float x5 = ldv(Xs, (s5<<LOG)+c);
    float x6 = ldv(Xs, (s6<<LOG)+c);
    float x7 = ldv(Xs, (s7<<LOG)+c);
    acc += ((x0+x1)+(x2+x3)) + ((x4+x5)+(x6+x7));
  }
  if (e + 4 <= cnt){
    int s0 = adj[o+e+0] & (N_NODES-1);
    int s1 = adj[o+e+1] & (N_NODES-1);
    int s2 = adj[o+e+2] & (N_NODES-1);
    int s3 = adj[o+e+3] & (N_NODES-1);
    float x0 = ldv(Xs, (s0<<LOG)+c);
    float x1 = ldv(Xs, (s1<<LOG)+c);
    float x2 = ldv(Xs, (s2<<LOG)+c);
    float x3 = ldv(Xs, (s3<<LOG)+c);
    acc += (x0+x1)+(x2+x3);
    e += 4;
  }
  for (; e<cnt; e++){
    int s = adj[o+e] & (N_NODES-1);
    acc += ldv(Xs, (s<<LOG)+c);
  }
  stv(out, (n<<LOG)+c, dinv[n]*acc);
}

// ---- combine GCN weight with temporal-conv weight; write bf16 TRANSPOSED  ----
template<int Kin>
__global__ __launch_bounds__(64) void k_wcomb(const void* __restrict__ gW, const void* __restrict__ gb,
                                              const void* __restrict__ tw, const int* __restrict__ flag,
                                              u16* __restrict__ Wtb, float* __restrict__ braw){
  int isbf = *flag;
  int r = blockIdx.x;
  int co = threadIdx.x;
  if (r < 3*Kin){
    int k = r / Kin, j = r % Kin;
    float acc = 0.f;
    for (int c=0; c<64; c++)
      acc += ldmix(gW, j*64+c, isbf) * ldmix(tw, co*192 + c*3 + k, isbf);
    Wtb[co*(3*Kin) + r] = f2u(acc);
  } else {
    int k = r - 3*Kin;
    float acc = 0.f;
    for (int c=0; c<64; c++)
      acc += ldmix(gb, c, isbf) * ldmix(tw, co*192 + c*3 + k, isbf);
    braw[k*64 + co] = acc;
  }
}

// ---- fused linear+temporal-conv via bf16 MFMA ----
template<int Kin, typename T>
__global__ __launch_bounds__(256) void k_tconv3(const T* __restrict__ A, const u16* __restrict__ Wtb,
                                                const float* __restrict__ braw, const void* __restrict__ tb,
                                                const int* __restrict__ flag, T* __restrict__ out){
  constexpr int K  = 3*Kin;
  constexpr int SA = Kin + 8;          // u16 stride, 16B-aligned rows
  constexpr int SW = K + 8;
  constexpr int JH = Kin/2;            // dwords per At row (payload)
  constexpr int JL = (Kin==64) ? 5 : 4;
  __shared__ alignas(16) u16 At[130*SA];
  __shared__ alignas(16) u16 Wl[64*SW];
  __shared__ float ball[64], bs0[64], bs2[64];

  int isbf = *flag;
  int bid = blockIdx.x;
  int b = bid>>3, v = bid&7;
  const int tid = threadIdx.x;

  if (tid < 64){
    float b0=braw[tid], b1=braw[64+tid], b2=braw[128+tid];
    ball[tid] = ldmix(tb, tid, isbf) + b0 + b1 + b2;
    bs0[tid] = b0; bs2[tid] = b2;
  }
  {
    const uint32_t* Wg = (const uint32_t*)Wtb;
    uint32_t* Wd = (uint32_t*)Wl;
    for (int u=tid; u<64*(K/2); u+=256){
      int co = u/(K/2), jd = u - co*(K/2);
      Wd[co*(SW/2) + jd] = Wg[u];
    }
  }
  {
    uint32_t* Ad = (uint32_t*)At;
    for (int u=tid; u<130*JH; u+=256){
      int t1 = u >> JL, jd = u & (JH-1);
      int t = t1 - 1;
      uint32_t pack = 0;
      if (t >= 0 && t < 128){
        int idx = (((b*128+t)*8+v))*Kin + (jd<<1);
        float x0 = ldv(A, idx), x1 = ldv(A, idx+1);
        pack = (uint32_t)f2u(x0) | ((uint32_t)f2u(x1) << 16);
      }
      Ad[t1*(SA/2) + jd] = pack;
    }
  }
  __syncthreads();

  int wv_ = tid >> 6, lane = tid & 63;
  int q = lane >> 4, l16 = lane & 15;
  int tb0 = wv_ * 32;

  f32x4 acc[2][4];
  #pragma unroll
  for (int mt=0; mt<2; mt++)
    #pragma unroll
    for (int nt=0; nt<4; nt++)
      acc[mt][nt] = (f32x4){0.f,0.f,0.f,0.f};

  #pragma unroll
  for (int s=0; s<K/32; s++){
    int kk = (32*s)/Kin;
    int j0 = 32*s - kk*Kin;
    int col = j0 + q*8;
    bf16x8 afr[2], bfr[4];
    #pragma unroll
    for (int mt=0; mt<2; mt++){
      int row = tb0 + mt*16 + l16 + kk;
      afr[mt] = *(const bf16x8*)&At[row*SA + col];
    }
    #pragma unroll
    for (int nt=0; nt<4; nt++){
      int co = nt*16 + l16;
      bfr[nt] = *(const bf16x8*)&Wl[co*SW + 32*s + q*8];
    }
    #pragma unroll
    for (int mt=0; mt<2; mt++)
      #pragma unroll
      for (int nt=0; nt<4; nt++)
        acc[mt][nt] = __builtin_amdgcn_mfma_f32_16x16x32_bf16(afr[mt], bfr[nt], acc[mt][nt], 0, 0, 0);
  }

  #pragma unroll
  for (int mt=0; mt<2; mt++){
    #pragma unroll
    for (int r=0; r<4; r++){
      int t = tb0 + mt*16 + q*4 + r;
      int base = (((b*128+t)*8+v)) << 6;
      #pragma unroll
      for (int nt=0; nt<4; nt++){
        int co = nt*16 + l16;
        float val = acc[mt][nt][r] + ball[co];
        if (t == 0)   val -= bs0[co];
        if (t == 127) val -= bs2[co];
        stv(out, base + co, val);
      }
    }
  }
}

// ---- BN stats: per-channel sum / sumsq (float4) ----
template<typename T>
__global__ __launch_bounds__(256) void k_stats(const T* __restrict__ X, float* __restrict__ stats){
  int cq = (threadIdx.x & 15) << 2;   // co-quad
  int g  = threadIdx.x >> 4;          // 16 row-groups
  float4 s  = make_float4(0.f,0.f,0.f,0.f);
  float4 s2 = make_float4(0.f,0.f,0.f,0.f);
  for (int row = blockIdx.x*16 + g; row < N_NODES; row += gridDim.x*16){
    float4 v = ld4(X, (row<<6) + cq);
    s.x += v.x; s.y += v.y; s.z += v.z; s.w += v.w;
    s2.x += v.x*v.x; s2.y += v.y*v.y; s2.z += v.z*v.z; s2.w += v.w*v.w;
  }
  __shared__ float sh[16][64], sh2[16][64];
  *(float4*)&sh[g][cq]  = s;
  *(float4*)&sh2[g][cq] = s2;
  __syncthreads();
  if (threadIdx.x < 64){
    int co = threadIdx.x;
    float a = 0.f, a2 = 0.f;
    #pragma unroll
    for (int gg=0; gg<16; gg++){ a += sh[gg][co]; a2 += sh2[gg][co]; }
    atomicAdd(&stats[co], a);
    atomicAdd(&stats[64+co], a2);
  }
}

// ---- BN-apply + ReLU + 1x1 conv + tanh (+ optional dinv-prescale) + scrambled view write ----
template<typename T>
__global__ __launch_bounds__(256) void k_bnfuse(const T* __restrict__ X, const float* __restrict__ stats,
                                                const void* __restrict__ gam, const void* __restrict__ bet,
                                                const void* __restrict__ ow, const void* __restrict__ ob,
                                                const int* __restrict__ flag, const float* __restrict__ presc,
                                                T* __restrict__ out){
  __shared__ float y_s[64*68];     // stride 68: 16B-aligned float4 per ci-quad
  __shared__ float ow_s[64*64];    // [co][ci]
  __shared__ float kk[64], bsh[64];
  int isbf = *flag;
  int bid = blockIdx.x;
  int b = bid>>4, rem = bid&15, v = rem>>1, thi = rem&1;
  int t0 = thi<<6;
  const float invM = 1.0f/131072.0f;
  if (threadIdx.x < 64){
    int ci = threadIdx.x;
    float mu = stats[ci]*invM;
    float var = stats[64+ci]*invM - mu*mu;
    float rs = rsqrtf(fmaxf(var, 0.f) + 1e-5f);
    float kv = rs*ldmix(gam, ci, isbf);
    kk[ci] = kv;
    bsh[ci] = ldmix(bet, ci, isbf) - mu*kv;
  }
  for (int u=threadIdx.x; u<1024; u+=256){
    int r = u>>4, cq = (u&15)<<2;
    *(float4*)&ow_s[(r<<6)+cq] = ld4mix(ow, (r<<6)+cq, isbf);
  }
  __syncthreads();
  for (int u=threadIdx.x; u<1024; u+=256){
    int tl = u>>4, cq = (u&15)<<2;
    int t = t0 + tl;
    float4 val = ld4(X, (((b*128+t)*8+v)<<6) + cq);
    float4 kq = *(const float4*)&kk[cq];
    float4 bq = *(const float4*)&bsh[cq];
    val.x = fmaxf(val.x*kq.x + bq.x, 0.f);
    val.y = fmaxf(val.y*kq.y + bq.y, 0.f);
    val.z = fmaxf(val.z*kq.z + bq.z, 0.f);
    val.w = fmaxf(val.w*kq.w + bq.w, 0.f);
    *(float4*)&y_s[tl*68 + cq] = val;
  }
  __syncthreads();
  int l = threadIdx.x & 63, wg = threadIdx.x >> 6;
  float acc[16];
  #pragma unroll
  for (int c8=0; c8<16; c8++) acc[c8] = ldmix(ob, wg*16 + c8, isbf);
  for (int ci=0; ci<64; ci+=4){
    float4 y4 = *(const float4*)&y_s[l*68 + ci];
    #pragma unroll
    for (int c8=0; c8<16; c8++){
      float4 w4 = *(const float4*)&ow_s[((wg*16+c8)<<6) + ci];
      acc[c8] += y4.x*w4.x + y4.y*w4.y + y4.z*w4.z + y4.w*w4.w;
    }
  }
  #pragma unroll
  for (int c8=0; c8<16; c8++){
    int co = wg*16 + c8;
    float z = tanhf(acc[c8]);
    int r = (b<<10) + (co<<4) + (v<<1) + thi;
    if (presc) z *= presc[r];     // lane-uniform broadcast
    stv(out, (r<<6) + l, z);
  }
}

// ---- final: out[b,v] = mean_{t,f}( x3 @ reg_w + reg_b ) ----
template<typename T>
__global__ __launch_bounds__(256) void k_final(const T* __restrict__ X, const void* __restrict__ rw,
                                               const void* __restrict__ rb, const int* __restrict__ flag,
                                               void* __restrict__ out){
  __shared__ float rw_s[64];
  __shared__ float rbs_s;
  __shared__ float wred[4];
  int isbf = *flag;
  int bid = blockIdx.x;
  int b = bid>>3, v = bid&7;
  if (threadIdx.x < 64){
    float s = 0.f;
    #pragma unroll
    for (int f=0; f<8; f++) s += ldmix(rw, threadIdx.x*8 + f, isbf);
    rw_s[threadIdx.x] = s;
  }
  if (threadIdx.x == 0){
    float s = 0.f;
    for (int f=0; f<8; f++) s += ldmix(rb, f, isbf);
    rbs_s = s;
  }
  __syncthreads();
  float acc = 0.f;
  for (int i=threadIdx.x; i<128*64; i+=256){
    int t = i>>6, j = i&63;
    acc += ldv(X, (((b*128+t)*8+v)<<6) + j) * rw_s[j];
  }
  for (int off=32; off; off>>=1) acc += __shfl_down(acc, off);
  if ((threadIdx.x & 63) == 0) wred[threadIdx.x>>6] = acc;
  __syncthreads();
  if (threadIdx.x == 0){
    float r = wred[0]+wred[1]+wred[2]+wred[3];
    float val = r*(1.0f/1024.0f) + rbs_s*0.125f;
    if (isbf) ((u16*)out)[bid] = f2u(val);
    else      ((float*)out)[bid] = val;
  }
}

// ---------------- host pipeline ----------------
template<typename T>
static void run_pipe(void* const* d_in, void* out, char* p, hipStream_t stream){
  auto alloc = [&](size_t bytes){ void* r = (void*)p; p += (bytes + 255) & ~(size_t)255; return r; };
  T*     A    = (T*)    alloc(sizeof(T)*(size_t)N_NODES*64);
  T*     B    = (T*)    alloc(sizeof(T)*(size_t)N_NODES*64);
  int*   deg  = (int*)  alloc(sizeof(int)*N_NODES);
  float* dinv = (float*)alloc(sizeof(float)*N_NODES);
  int*   offs = (int*)  alloc(sizeof(int)*N_NODES);
  int*   adj  = (int*)  alloc(sizeof(int)*N_EDGES);
  int*   bcnt = (int*)  alloc(sizeof(int)*1024);
  int*   barr = (int*)  alloc(sizeof(int)*1056);
  int*   cur  = (int*)  alloc(sizeof(int)*1024);
  float* stats= (float*)alloc(sizeof(float)*128);
  int*   flag = (int*)  alloc(sizeof(int)*64);
  u16*   Wtb  = (u16*)  alloc(sizeof(u16)*192*64);
  float* braw = (float*)alloc(sizeof(float)*192);
  uint32_t* ebuf = (uint32_t*)A;   // alias: dead before A's first real use

  const void* x   = d_in[0];
  const int* edge = (const int*)d_in[1];
  const void* g1w = d_in[2];  const void* g1b = d_in[3];
  const void* t1w = d_in[4];  const void* t1b = d_in[5];
  const void* bn1g= d_in[6];  const void* bn1b= d_in[7];
  const void* o1w = d_in[8];  const void* o1b = d_in[9];
  const void* g2w = d_in[10]; const void* g2b = d_in[11];
  const void* t2w = d_in[12]; const void* t2b = d_in[13];
  const void* bn2g= d_in[14]; const void* bn2b= d_in[15];
  const void* o2w = d_in[16]; const void* o2b = d_in[17];
  const void* rw  = d_in[18]; const void* rb  = d_in[19];
  const int* src = edge;
  const int* dst = edge + N_EDGES;

  k_detect<<<1, 64, 0, stream>>>((const uint32_t*)x, flag);

  // graph prep: bucket counting sort (no hot-path global atomic scatter)
  hipMemsetAsync(bcnt, 0, sizeof(int)*1024, stream);
  k_bcount  <<<256, 256, 0, stream>>>(dst, bcnt);
  k_bscan   <<<1, 1024, 0, stream>>>(bcnt, barr, cur);
  k_bscatter<<<1024, 256, 0, stream>>>(src, dst, cur, ebuf);
  k_bsort<T><<<1024, 256, 0, stream>>>(ebuf, barr, x, flag, adj, offs, deg, dinv, B);  // B = dinv*x

  // ---- layer 1 ----
  k_aggp<32,T>   <<<N_NODES/8, 256, 0, stream>>>(B, adj, offs, deg, dinv, A);
  k_wcomb<32>    <<<3*32+3, 64, 0, stream>>>(g1w, g1b, t1w, flag, Wtb, braw);
  k_tconv3<32,T> <<<1024, 256, 0, stream>>>(A, Wtb, braw, t1b, flag, B);
  hipMemsetAsync(stats, 0, sizeof(float)*128, stream);
  k_stats<T>     <<<512, 256, 0, stream>>>(B, stats);
  k_bnfuse<T>    <<<2048, 256, 0, stream>>>(B, stats, bn1g, bn1b, o1w, o1b, flag, dinv, A);  // A prescaled

  // ---- layer 2 ----
  k_aggp<64,T>   <<<N_NODES/4, 256, 0, stream>>>(A, adj, offs, deg, dinv, B);
  k_wcomb<64>    <<<3*64+3, 64, 0, stream>>>(g2w, g2b, t2w, flag, Wtb, braw);
  k_tconv3<64,T> <<<1024, 256, 0, stream>>>(B, Wtb, braw, t2b, flag, A);
  hipMemsetAsync(stats, 0, sizeof(float)*128, stream);
  k_stats<T>     <<<512, 256, 0, stream>>>(A, stats);
  k_bnfuse<T>    <<<2048, 256, 0, stream>>>(A, stats, bn2g, bn2b, o2w, o2b, flag, (const float*)nullptr, B);

  // ---- regression + mean ----
  k_final<T><<<1024, 256, 0, stream>>>(B, rw, rb, flag, out);
}

extern "C" void kernel_launch(void* const* d_in, const int* in_sizes, int n_in,
                              void* d_out, int out_size, void* d_ws, size_t ws_size,
                              hipStream_t stream){
  (void)in_sizes; (void)n_in; (void)out_size;
  const size_t csr_bytes = 3*sizeof(int)*(size_t)N_NODES + sizeof(int)*(size_t)N_EDGES + 131072;
  const size_t need_f32  = 2*sizeof(float)*(size_t)N_NODES*64 + csr_bytes;   // ~73 MB
  if (ws_size >= need_f32)
    run_pipe<float>(d_in, d_out, (char*)d_ws, stream);
  else
    run_pipe<u16>(d_in, d_out, (char*)d_ws, stream);
}

// Round 9
// 424.246 us; speedup vs baseline: 1.4701x; 1.4701x over previous
//
#include <hip/hip_runtime.h>
#include <stdint.h>

typedef unsigned short u16;
typedef __attribute__((ext_vector_type(8))) short bf16x8;
typedef __attribute__((ext_vector_type(4))) float f32x4;

static const int N_NODES = 131072;   // B*T*NN = 128*128*8
static const int N_EDGES = 1048576;

__device__ __forceinline__ float u2f(u16 u){
  union{uint32_t i; float f;} w; w.i = ((uint32_t)u)<<16; return w.f;
}
__device__ __forceinline__ u16 f2u(float f){
  union{float f; uint32_t u;} v; v.f=f;
  uint32_t u=v.u;
  u += 0x7fff + ((u>>16)&1);   // round-to-nearest-even
  return (u16)(u>>16);
}
// internal-buffer typed access
__device__ __forceinline__ float ldv(const float* p, int i){ return p[i]; }
__device__ __forceinline__ float ldv(const u16* p, int i){ return u2f(p[i]); }
__device__ __forceinline__ void stv(float* p, int i, float v){ p[i]=v; }
__device__ __forceinline__ void stv(u16* p, int i, float v){ p[i]=f2u(v); }
__device__ __forceinline__ float4 ld4(const float* p, int i){ return *(const float4*)(p+i); }
__device__ __forceinline__ float4 ld4(const u16* p, int i){
  ushort4 u = *(const ushort4*)(p+i);
  return make_float4(u2f(u.x), u2f(u.y), u2f(u.z), u2f(u.w));
}
__device__ __forceinline__ void st4(float* p, int i, float4 v){ *(float4*)(p+i) = v; }
__device__ __forceinline__ void st4(u16* p, int i, float4 v){
  p[i]=f2u(v.x); p[i+1]=f2u(v.y); p[i+2]=f2u(v.z); p[i+3]=f2u(v.w);
}
// external-input access, runtime dtype
__device__ __forceinline__ float ldmix(const void* p, int i, int isbf){
  return isbf ? u2f(((const u16*)p)[i]) : ((const float*)p)[i];
}
__device__ __forceinline__ float4 ld4mix(const void* p, int i, int isbf){
  if (isbf){ return ld4((const u16*)p, i); }
  return ld4((const float*)p, i);
}

// ---------------- dtype detection ----------------
__global__ void k_detect(const uint32_t* __restrict__ x, int* __restrict__ flag){
  if (threadIdx.x==0 && blockIdx.x==0){
    int cnt=0;
    for (int i=0;i<256;i++){
      uint32_t e=(x[i]>>7)&0xFFu;
      if (e>=0x6Fu && e<=0x85u) cnt++;
    }
    *flag = (cnt>=128) ? 1 : 0;
  }
}

// ---------------- graph prep: two-pass counting sort, NO global atomics ----------------
// bucket = dst >> 9  (256 buckets x 512 nodes). Edge packed: src(17b) | dstLow9 << 17.
__global__ __launch_bounds__(256) void k_hist(const int* __restrict__ dst, int* __restrict__ H){
  __shared__ int h[256];
  int tid = threadIdx.x;
  h[tid] = 0;
  __syncthreads();
  int base = blockIdx.x*4096;
  #pragma unroll
  for (int i=0;i<16;i++){
    int e = base + i*256 + tid;
    atomicAdd(&h[(dst[e] & (N_NODES-1))>>9], 1);
  }
  __syncthreads();
  H[blockIdx.x*256 + tid] = h[tid];
}

__global__ __launch_bounds__(256) void k_colscan(const int* __restrict__ H, int* __restrict__ P,
                                                 int* __restrict__ bt){
  __shared__ int sc[256];
  int b = blockIdx.x, tid = threadIdx.x;
  int v = H[tid*256 + b];
  sc[tid] = v; __syncthreads();
  for (int d=1; d<256; d<<=1){
    int o = (tid>=d) ? sc[tid-d] : 0; __syncthreads();
    sc[tid] += o; __syncthreads();
  }
  P[tid*256 + b] = sc[tid] - v;
  if (tid==255) bt[b] = sc[255];
}

__global__ __launch_bounds__(256) void k_bbscan(const int* __restrict__ bt, int* __restrict__ bb){
  __shared__ int sc[256];
  int t = threadIdx.x;
  int v = bt[t]; sc[t]=v; __syncthreads();
  for (int d=1; d<256; d<<=1){
    int o = (t>=d) ? sc[t-d] : 0; __syncthreads();
    sc[t] += o; __syncthreads();
  }
  bb[t] = sc[t]-v;
  if (t==255) bb[256] = sc[t];
}

__global__ __launch_bounds__(256) void k_scatter2(const int* __restrict__ src, const int* __restrict__ dst,
                                                  const int* __restrict__ P, const int* __restrict__ bb,
                                                  uint32_t* __restrict__ ebuf){
  __shared__ int cu[256];
  int tid = threadIdx.x;
  cu[tid] = bb[tid] + P[blockIdx.x*256 + tid];
  __syncthreads();
  int base = blockIdx.x*4096;
  #pragma unroll
  for (int i=0;i<16;i++){
    int e = base + i*256 + tid;
    int s = src[e] & (N_NODES-1);
    int d = dst[e] & (N_NODES-1);
    int pos = atomicAdd(&cu[d>>9], 1);           // LDS atomic only
    ebuf[pos] = (uint32_t)s | ((uint32_t)(d & 511) << 17);
  }
}

// per-bucket counting sort by node-low9 + emit offs/deg/dinv + fused dinv-prescale of x (F=32)
template<typename T>
__global__ __launch_bounds__(512) void k_bsort2(const uint32_t* __restrict__ ebuf, const int* __restrict__ bb,
                                                const void* __restrict__ x, const int* __restrict__ flag,
                                                int* __restrict__ adj, int* __restrict__ offs,
                                                int* __restrict__ deg, float* __restrict__ dinv,
                                                T* __restrict__ Bout){
  __shared__ uint32_t ein[5120], outs[5120];
  __shared__ int hist[512], sc[512], cu[512];
  __shared__ float dv[512];
  int b = blockIdx.x, tid = threadIdx.x;
  int lo = bb[b], hi = bb[b+1];
  int cnt = hi - lo; if (cnt > 5120) cnt = 5120; if (cnt < 0) cnt = 0;
  hist[tid] = 0;
  __syncthreads();
  for (int i=tid; i<cnt; i+=512){
    uint32_t p = ebuf[lo+i];
    ein[i] = p;
    atomicAdd(&hist[(p>>17)&511], 1);
  }
  __syncthreads();
  sc[tid] = hist[tid];
  __syncthreads();
  for (int d=1; d<512; d<<=1){
    int v = (tid>=d) ? sc[tid-d] : 0;
    __syncthreads();
    sc[tid] += v;
    __syncthreads();
  }
  {
    int ex = sc[tid] - hist[tid];
    int node = b*512 + tid;
    offs[node] = lo + ex;
    deg[node]  = hist[tid];
    float rs = rsqrtf((float)hist[tid] + 1.0f);
    dinv[node] = rs;
    dv[tid] = rs;
    cu[tid] = ex;
  }
  __syncthreads();
  for (int i=tid; i<cnt; i+=512){
    uint32_t p = ein[i];
    int pos = atomicAdd(&cu[(p>>17)&511], 1);
    outs[pos] = p & 0x1FFFFu;
  }
  __syncthreads();
  for (int i=tid; i<cnt; i+=512) adj[lo+i] = (int)outs[i];
  // fused prescale: Bout[node,c] = dinv[node]*x[node,c], 512 nodes of this bucket
  int isbf = *flag;
  for (int u=tid; u<16384; u+=512){
    int nl = u>>5, c = u&31;
    int idx = ((b<<9) + nl)*32 + c;
    stv(Bout, idx, dv[nl]*ldmix(x, idx, isbf));
  }
}

// ---- GCN aggregation on prescaled rows: out[n] = dinv[n]*(Xs[n] + sum_in Xs[s]) ----
template<int F, typename T>
__global__ __launch_bounds__(256) void k_aggp(const T* __restrict__ Xs,
                                              const int* __restrict__ adj, const int* __restrict__ offs,
                                              const int* __restrict__ deg, const float* __restrict__ dinv,
                                              T* __restrict__ out){
  constexpr int LOG = (F==64) ? 6 : 5;
  int c = threadIdx.x & (F-1);
  int slot = threadIdx.x >> LOG;
  int n = blockIdx.x*(256>>LOG) + slot;
  int o = offs[n] & (N_EDGES-1);
  int cnt = min(deg[n], 8192);
  float acc = ldv(Xs, (n<<LOG)+c);            // prescaled self term
  int e = 0;
  for (; e+8 <= cnt; e += 8){
    int s0 = adj[o+e+0] & (N_NODES-1);
    int s1 = adj[o+e+1] & (N_NODES-1);
    int s2 = adj[o+e+2] & (N_NODES-1);
    int s3 = adj[o+e+3] & (N_NODES-1);
    int s4 = adj[o+e+4] & (N_NODES-1);
    int s5 = adj[o+e+5] & (N_NODES-1);
    int s6 = adj[o+e+6] & (N_NODES-1);
    int s7 = adj[o+e+7] & (N_NODES-1);
    float x0 = ldv(Xs, (s0<<LOG)+c);
    float x1 = ldv(Xs, (s1<<LOG)+c);
    float x2 = ldv(Xs, (s2<<LOG)+c);
    float x3 = ldv(Xs, (s3<<LOG)+c);
    float x4 = ldv(Xs, (s4<<LOG)+c);
    float x5 = ldv(Xs, (s5<<LOG)+c);
    float x6 = ldv(Xs, (s6<<LOG)+c);
    float x7 = ldv(Xs, (s7<<LOG)+c);
    acc += ((x0+x1)+(x2+x3)) + ((x4+x5)+(x6+x7));
  }
  if (e + 4 <= cnt){
    int s0 = adj[o+e+0] & (N_NODES-1);
    int s1 = adj[o+e+1] & (N_NODES-1);
    int s2 = adj[o+e+2] & (N_NODES-1);
    int s3 = adj[o+e+3] & (N_NODES-1);
    float x0 = ldv(Xs, (s0<<LOG)+c);
    float x1 = ldv(Xs, (s1<<LOG)+c);
    float x2 = ldv(Xs, (s2<<LOG)+c);
    float x3 = ldv(Xs, (s3<<LOG)+c);
    acc += (x0+x1)+(x2+x3);
    e += 4;
  }
  for (; e<cnt; e++){
    int s = adj[o+e] & (N_NODES-1);
    acc += ldv(Xs, (s<<LOG)+c);
  }
  stv(out, (n<<LOG)+c, dinv[n]*acc);
}

// ---- combine GCN weight with temporal-conv weight; write bf16 TRANSPOSED  ----
template<int Kin>
__global__ __launch_bounds__(64) void k_wcomb(const void* __restrict__ gW, const void* __restrict__ gb,
                                              const void* __restrict__ tw, const int* __restrict__ flag,
                                              u16* __restrict__ Wtb, float* __restrict__ braw){
  int isbf = *flag;
  int r = blockIdx.x;
  int co = threadIdx.x;
  if (r < 3*Kin){
    int k = r / Kin, j = r % Kin;
    float acc = 0.f;
    for (int c=0; c<64; c++)
      acc += ldmix(gW, j*64+c, isbf) * ldmix(tw, co*192 + c*3 + k, isbf);
    Wtb[co*(3*Kin) + r] = f2u(acc);
  } else {
    int k = r - 3*Kin;
    float acc = 0.f;
    for (int c=0; c<64; c++)
      acc += ldmix(gb, c, isbf) * ldmix(tw, co*192 + c*3 + k, isbf);
    braw[k*64 + co] = acc;
  }
}

// ---- fused linear+temporal-conv via bf16 MFMA ----
template<int Kin, typename T>
__global__ __launch_bounds__(256) void k_tconv3(const T* __restrict__ A, const u16* __restrict__ Wtb,
                                                const float* __restrict__ braw, const void* __restrict__ tb,
                                                const int* __restrict__ flag, T* __restrict__ out){
  constexpr int K  = 3*Kin;
  constexpr int SA = Kin + 8;          // u16 stride, 16B-aligned rows
  constexpr int SW = K + 8;
  constexpr int JH = Kin/2;            // dwords per At row (payload)
  constexpr int JL = (Kin==64) ? 5 : 4;
  __shared__ alignas(16) u16 At[130*SA];
  __shared__ alignas(16) u16 Wl[64*SW];
  __shared__ float ball[64], bs0[64], bs2[64];

  int isbf = *flag;
  int bid = blockIdx.x;
  int b = bid>>3, v = bid&7;
  const int tid = threadIdx.x;

  if (tid < 64){
    float b0=braw[tid], b1=braw[64+tid], b2=braw[128+tid];
    ball[tid] = ldmix(tb, tid, isbf) + b0 + b1 + b2;
    bs0[tid] = b0; bs2[tid] = b2;
  }
  {
    const uint32_t* Wg = (const uint32_t*)Wtb;
    uint32_t* Wd = (uint32_t*)Wl;
    for (int u=tid; u<64*(K/2); u+=256){
      int co = u/(K/2), jd = u - co*(K/2);
      Wd[co*(SW/2) + jd] = Wg[u];
    }
  }
  {
    uint32_t* Ad = (uint32_t*)At;
    for (int u=tid; u<130*JH; u+=256){
      int t1 = u >> JL, jd = u & (JH-1);
      int t = t1 - 1;
      uint32_t pack = 0;
      if (t >= 0 && t < 128){
        int idx = (((b*128+t)*8+v))*Kin + (jd<<1);
        float x0 = ldv(A, idx), x1 = ldv(A, idx+1);
        pack = (uint32_t)f2u(x0) | ((uint32_t)f2u(x1) << 16);
      }
      Ad[t1*(SA/2) + jd] = pack;
    }
  }
  __syncthreads();

  int wv_ = tid >> 6, lane = tid & 63;
  int q = lane >> 4, l16 = lane & 15;
  int tb0 = wv_ * 32;

  f32x4 acc[2][4];
  #pragma unroll
  for (int mt=0; mt<2; mt++)
    #pragma unroll
    for (int nt=0; nt<4; nt++)
      acc[mt][nt] = (f32x4){0.f,0.f,0.f,0.f};

  #pragma unroll
  for (int s=0; s<K/32; s++){
    int kk = (32*s)/Kin;
    int j0 = 32*s - kk*Kin;
    int col = j0 + q*8;
    bf16x8 afr[2], bfr[4];
    #pragma unroll
    for (int mt=0; mt<2; mt++){
      int row = tb0 + mt*16 + l16 + kk;
      afr[mt] = *(const bf16x8*)&At[row*SA + col];
    }
    #pragma unroll
    for (int nt=0; nt<4; nt++){
      int co = nt*16 + l16;
      bfr[nt] = *(const bf16x8*)&Wl[co*SW + 32*s + q*8];
    }
    #pragma unroll
    for (int mt=0; mt<2; mt++)
      #pragma unroll
      for (int nt=0; nt<4; nt++)
        acc[mt][nt] = __builtin_amdgcn_mfma_f32_16x16x32_bf16(afr[mt], bfr[nt], acc[mt][nt], 0, 0, 0);
  }

  #pragma unroll
  for (int mt=0; mt<2; mt++){
    #pragma unroll
    for (int r=0; r<4; r++){
      int t = tb0 + mt*16 + q*4 + r;
      int base = (((b*128+t)*8+v)) << 6;
      #pragma unroll
      for (int nt=0; nt<4; nt++){
        int co = nt*16 + l16;
        float val = acc[mt][nt][r] + ball[co];
        if (t == 0)   val -= bs0[co];
        if (t == 127) val -= bs2[co];
        stv(out, base + co, val);
      }
    }
  }
}

// ---- BN stats: per-channel sum / sumsq (float4) ----
template<typename T>
__global__ __launch_bounds__(256) void k_stats(const T* __restrict__ X, float* __restrict__ stats){
  int cq = (threadIdx.x & 15) << 2;   // co-quad
  int g  = threadIdx.x >> 4;          // 16 row-groups
  float4 s  = make_float4(0.f,0.f,0.f,0.f);
  float4 s2 = make_float4(0.f,0.f,0.f,0.f);
  for (int row = blockIdx.x*16 + g; row < N_NODES; row += gridDim.x*16){
    float4 v = ld4(X, (row<<6) + cq);
    s.x += v.x; s.y += v.y; s.z += v.z; s.w += v.w;
    s2.x += v.x*v.x; s2.y += v.y*v.y; s2.z += v.z*v.z; s2.w += v.w*v.w;
  }
  __shared__ float sh[16][64], sh2[16][64];
  *(float4*)&sh[g][cq]  = s;
  *(float4*)&sh2[g][cq] = s2;
  __syncthreads();
  if (threadIdx.x < 64){
    int co = threadIdx.x;
    float a = 0.f, a2 = 0.f;
    #pragma unroll
    for (int gg=0; gg<16; gg++){ a += sh[gg][co]; a2 += sh2[gg][co]; }
    atomicAdd(&stats[co], a);
    atomicAdd(&stats[64+co], a2);
  }
}

// ---- BN-apply + ReLU + 1x1 conv + tanh (+ optional dinv-prescale) + scrambled view write ----
template<typename T>
__global__ __launch_bounds__(256) void k_bnfuse(const T* __restrict__ X, const float* __restrict__ stats,
                                                const void* __restrict__ gam, const void* __restrict__ bet,
                                                const void* __restrict__ ow, const void* __restrict__ ob,
                                                const int* __restrict__ flag, const float* __restrict__ presc,
                                                T* __restrict__ out){
  __shared__ float y_s[64*68];     // stride 68: 16B-aligned float4 per ci-quad
  __shared__ float ow_s[64*64];    // [co][ci]
  __shared__ float kk[64], bsh[64];
  int isbf = *flag;
  int bid = blockIdx.x;
  int b = bid>>4, rem = bid&15, v = rem>>1, thi = rem&1;
  int t0 = thi<<6;
  const float invM = 1.0f/131072.0f;
  if (threadIdx.x < 64){
    int ci = threadIdx.x;
    float mu = stats[ci]*invM;
    float var = stats[64+ci]*invM - mu*mu;
    float rs = rsqrtf(fmaxf(var, 0.f) + 1e-5f);
    float kv = rs*ldmix(gam, ci, isbf);
    kk[ci] = kv;
    bsh[ci] = ldmix(bet, ci, isbf) - mu*kv;
  }
  for (int u=threadIdx.x; u<1024; u+=256){
    int r = u>>4, cq = (u&15)<<2;
    *(float4*)&ow_s[(r<<6)+cq] = ld4mix(ow, (r<<6)+cq, isbf);
  }
  __syncthreads();
  for (int u=threadIdx.x; u<1024; u+=256){
    int tl = u>>4, cq = (u&15)<<2;
    int t = t0 + tl;
    float4 val = ld4(X, (((b*128+t)*8+v)<<6) + cq);
    float4 kq = *(const float4*)&kk[cq];
    float4 bq = *(const float4*)&bsh[cq];
    val.x = fmaxf(val.x*kq.x + bq.x, 0.f);
    val.y = fmaxf(val.y*kq.y + bq.y, 0.f);
    val.z = fmaxf(val.z*kq.z + bq.z, 0.f);
    val.w = fmaxf(val.w*kq.w + bq.w, 0.f);
    *(float4*)&y_s[tl*68 + cq] = val;
  }
  __syncthreads();
  int l = threadIdx.x & 63, wg = threadIdx.x >> 6;
  float acc[16];
  #pragma unroll
  for (int c8=0; c8<16; c8++) acc[c8] = ldmix(ob, wg*16 + c8, isbf);
  for (int ci=0; ci<64; ci+=4){
    float4 y4 = *(const float4*)&y_s[l*68 + ci];
    #pragma unroll
    for (int c8=0; c8<16; c8++){
      float4 w4 = *(const float4*)&ow_s[((wg*16+c8)<<6) + ci];
      acc[c8] += y4.x*w4.x + y4.y*w4.y + y4.z*w4.z + y4.w*w4.w;
    }
  }
  #pragma unroll
  for (int c8=0; c8<16; c8++){
    int co = wg*16 + c8;
    float z = tanhf(acc[c8]);
    int r = (b<<10) + (co<<4) + (v<<1) + thi;
    if (presc) z *= presc[r];     // lane-uniform broadcast
    stv(out, (r<<6) + l, z);
  }
}

// ---- final: out[b,v] = mean_{t,f}( x3 @ reg_w + reg_b ) ----
template<typename T>
__global__ __launch_bounds__(256) void k_final(const T* __restrict__ X, const void* __restrict__ rw,
                                               const void* __restrict__ rb, const int* __restrict__ flag,
                                               void* __restrict__ out){
  __shared__ float rw_s[64];
  __shared__ float rbs_s;
  __shared__ float wred[4];
  int isbf = *flag;
  int bid = blockIdx.x;
  int b = bid>>3, v = bid&7;
  if (threadIdx.x < 64){
    float s = 0.f;
    #pragma unroll
    for (int f=0; f<8; f++) s += ldmix(rw, threadIdx.x*8 + f, isbf);
    rw_s[threadIdx.x] = s;
  }
  if (threadIdx.x == 0){
    float s = 0.f;
    for (int f=0; f<8; f++) s += ldmix(rb, f, isbf);
    rbs_s = s;
  }
  __syncthreads();
  float acc = 0.f;
  for (int i=threadIdx.x; i<128*64; i+=256){
    int t = i>>6, j = i&63;
    acc += ldv(X, (((b*128+t)*8+v)<<6) + j) * rw_s[j];
  }
  for (int off=32; off; off>>=1) acc += __shfl_down(acc, off);
  if ((threadIdx.x & 63) == 0) wred[threadIdx.x>>6] = acc;
  __syncthreads();
  if (threadIdx.x == 0){
    float r = wred[0]+wred[1]+wred[2]+wred[3];
    float val = r*(1.0f/1024.0f) + rbs_s*0.125f;
    if (isbf) ((u16*)out)[bid] = f2u(val);
    else      ((float*)out)[bid] = val;
  }
}

// ---------------- host pipeline ----------------
template<typename T>
static void run_pipe(void* const* d_in, void* out, char* p, hipStream_t stream){
  auto alloc = [&](size_t bytes){ void* r = (void*)p; p += (bytes + 255) & ~(size_t)255; return r; };
  T*     A    = (T*)    alloc(sizeof(T)*(size_t)N_NODES*64);
  T*     B    = (T*)    alloc(sizeof(T)*(size_t)N_NODES*64);
  int*   deg  = (int*)  alloc(sizeof(int)*N_NODES);
  float* dinv = (float*)alloc(sizeof(float)*N_NODES);
  int*   offs = (int*)  alloc(sizeof(int)*N_NODES);
  int*   adj  = (int*)  alloc(sizeof(int)*N_EDGES);
  int*   H    = (int*)  alloc(sizeof(int)*256*256);
  int*   P    = (int*)  alloc(sizeof(int)*256*256);
  int*   bt   = (int*)  alloc(sizeof(int)*256);
  int*   bb   = (int*)  alloc(sizeof(int)*260);
  float* stats= (float*)alloc(sizeof(float)*128);
  int*   flag = (int*)  alloc(sizeof(int)*64);
  u16*   Wtb  = (u16*)  alloc(sizeof(u16)*192*64);
  float* braw = (float*)alloc(sizeof(float)*192);
  uint32_t* ebuf = (uint32_t*)A;   // alias: dead before A's first real use

  const void* x   = d_in[0];
  const int* edge = (const int*)d_in[1];
  const void* g1w = d_in[2];  const void* g1b = d_in[3];
  const void* t1w = d_in[4];  const void* t1b = d_in[5];
  const void* bn1g= d_in[6];  const void* bn1b= d_in[7];
  const void* o1w = d_in[8];  const void* o1b = d_in[9];
  const void* g2w = d_in[10]; const void* g2b = d_in[11];
  const void* t2w = d_in[12]; const void* t2b = d_in[13];
  const void* bn2g= d_in[14]; const void* bn2b= d_in[15];
  const void* o2w = d_in[16]; const void* o2b = d_in[17];
  const void* rw  = d_in[18]; const void* rb  = d_in[19];
  const int* src = edge;
  const int* dst = edge + N_EDGES;

  k_detect<<<1, 64, 0, stream>>>((const uint32_t*)x, flag);

  // graph prep: two-pass counting sort, zero global atomics
  k_hist    <<<256, 256, 0, stream>>>(dst, H);
  k_colscan <<<256, 256, 0, stream>>>(H, P, bt);
  k_bbscan  <<<1, 256, 0, stream>>>(bt, bb);
  k_scatter2<<<256, 256, 0, stream>>>(src, dst, P, bb, ebuf);
  k_bsort2<T><<<256, 512, 0, stream>>>(ebuf, bb, x, flag, adj, offs, deg, dinv, B);  // B = dinv*x

  // ---- layer 1 ----
  k_aggp<32,T>   <<<N_NODES/8, 256, 0, stream>>>(B, adj, offs, deg, dinv, A);
  k_wcomb<32>    <<<3*32+3, 64, 0, stream>>>(g1w, g1b, t1w, flag, Wtb, braw);
  k_tconv3<32,T> <<<1024, 256, 0, stream>>>(A, Wtb, braw, t1b, flag, B);
  hipMemsetAsync(stats, 0, sizeof(float)*128, stream);
  k_stats<T>     <<<512, 256, 0, stream>>>(B, stats);
  k_bnfuse<T>    <<<2048, 256, 0, stream>>>(B, stats, bn1g, bn1b, o1w, o1b, flag, dinv, A);  // A prescaled

  // ---- layer 2 ----
  k_aggp<64,T>   <<<N_NODES/4, 256, 0, stream>>>(A, adj, offs, deg, dinv, B);
  k_wcomb<64>    <<<3*64+3, 64, 0, stream>>>(g2w, g2b, t2w, flag, Wtb, braw);
  k_tconv3<64,T> <<<1024, 256, 0, stream>>>(B, Wtb, braw, t2b, flag, A);
  hipMemsetAsync(stats, 0, sizeof(float)*128, stream);
  k_stats<T>     <<<512, 256, 0, stream>>>(A, stats);
  k_bnfuse<T>    <<<2048, 256, 0, stream>>>(A, stats, bn2g, bn2b, o2w, o2b, flag, (const float*)nullptr, B);

  // ---- regression + mean ----
  k_final<T><<<1024, 256, 0, stream>>>(B, rw, rb, flag, out);
}

extern "C" void kernel_launch(void* const* d_in, const int* in_sizes, int n_in,
                              void* d_out, int out_size, void* d_ws, size_t ws_size,
                              hipStream_t stream){
  (void)in_sizes; (void)n_in; (void)out_size;
  const size_t csr_bytes = 3*sizeof(int)*(size_t)N_NODES + sizeof(int)*(size_t)N_EDGES + 786432;
  const size_t need_f32  = 2*sizeof(float)*(size_t)N_NODES*64 + csr_bytes;   // ~73.5 MB
  if (ws_size >= need_f32)
    run_pipe<float>(d_in, d_out, (char*)d_ws, stream);
  else
    run_pipe<u16>(d_in, d_out, (char*)d_ws, stream);
}

// Round 10
// 406.986 us; speedup vs baseline: 1.5325x; 1.0424x over previous
//
#include <hip/hip_runtime.h>
#include <stdint.h>

typedef unsigned short u16;
typedef __attribute__((ext_vector_type(8))) short bf16x8;
typedef __attribute__((ext_vector_type(4))) float f32x4;

static const int N_NODES = 131072;   // B*T*NN = 128*128*8
static const int N_EDGES = 1048576;

__device__ __forceinline__ float u2f(u16 u){
  union{uint32_t i; float f;} w; w.i = ((uint32_t)u)<<16; return w.f;
}
__device__ __forceinline__ u16 f2u(float f){
  union{float f; uint32_t u;} v; v.f=f;
  uint32_t u=v.u;
  u += 0x7fff + ((u>>16)&1);   // round-to-nearest-even
  return (u16)(u>>16);
}
__device__ __forceinline__ float ldv(const float* p, int i){ return p[i]; }
__device__ __forceinline__ float ldv(const u16* p, int i){ return u2f(p[i]); }
__device__ __forceinline__ void stv(float* p, int i, float v){ p[i]=v; }
__device__ __forceinline__ void stv(u16* p, int i, float v){ p[i]=f2u(v); }
__device__ __forceinline__ float4 ld4(const float* p, int i){ return *(const float4*)(p+i); }
__device__ __forceinline__ float4 ld4(const u16* p, int i){
  ushort4 u = *(const ushort4*)(p+i);
  return make_float4(u2f(u.x), u2f(u.y), u2f(u.z), u2f(u.w));
}
__device__ __forceinline__ float ldmix(const void* p, int i, int isbf){
  return isbf ? u2f(((const u16*)p)[i]) : ((const float*)p)[i];
}
__device__ __forceinline__ float4 ld4mix(const void* p, int i, int isbf){
  if (isbf){ return ld4((const u16*)p, i); }
  return ld4((const float*)p, i);
}

// ---------------- dtype detection ----------------
__global__ void k_detect(const uint32_t* __restrict__ x, int* __restrict__ flag){
  if (threadIdx.x==0 && blockIdx.x==0){
    int cnt=0;
    for (int i=0;i<256;i++){
      uint32_t e=(x[i]>>7)&0xFFu;
      if (e>=0x6Fu && e<=0x85u) cnt++;
    }
    *flag = (cnt>=128) ? 1 : 0;
  }
}

// ---------------- graph prep: two-pass counting sort, NO global atomics ----------------
__global__ __launch_bounds__(256) void k_hist(const int* __restrict__ dst, int* __restrict__ H){
  __shared__ int h[256];
  int tid = threadIdx.x;
  h[tid] = 0;
  __syncthreads();
  int base = blockIdx.x*4096;
  #pragma unroll
  for (int i=0;i<16;i++){
    int e = base + i*256 + tid;
    atomicAdd(&h[(dst[e] & (N_NODES-1))>>9], 1);
  }
  __syncthreads();
  H[blockIdx.x*256 + tid] = h[tid];
}

__global__ __launch_bounds__(256) void k_colscan(const int* __restrict__ H, int* __restrict__ P,
                                                 int* __restrict__ bt){
  __shared__ int sc[256];
  int b = blockIdx.x, tid = threadIdx.x;
  int v = H[tid*256 + b];
  sc[tid] = v; __syncthreads();
  for (int d=1; d<256; d<<=1){
    int o = (tid>=d) ? sc[tid-d] : 0; __syncthreads();
    sc[tid] += o; __syncthreads();
  }
  P[tid*256 + b] = sc[tid] - v;
  if (tid==255) bt[b] = sc[255];
}

__global__ __launch_bounds__(256) void k_bbscan(const int* __restrict__ bt, int* __restrict__ bb){
  __shared__ int sc[256];
  int t = threadIdx.x;
  int v = bt[t]; sc[t]=v; __syncthreads();
  for (int d=1; d<256; d<<=1){
    int o = (t>=d) ? sc[t-d] : 0; __syncthreads();
    sc[t] += o; __syncthreads();
  }
  bb[t] = sc[t]-v;
  if (t==255) bb[256] = sc[t];
}

__global__ __launch_bounds__(256) void k_scatter2(const int* __restrict__ src, const int* __restrict__ dst,
                                                  const int* __restrict__ P, const int* __restrict__ bb,
                                                  uint32_t* __restrict__ ebuf){
  __shared__ int cu[256];
  int tid = threadIdx.x;
  cu[tid] = bb[tid] + P[blockIdx.x*256 + tid];
  __syncthreads();
  int base = blockIdx.x*4096;
  #pragma unroll
  for (int i=0;i<16;i++){
    int e = base + i*256 + tid;
    int s = src[e] & (N_NODES-1);
    int d = dst[e] & (N_NODES-1);
    int pos = atomicAdd(&cu[d>>9], 1);           // LDS atomic only
    ebuf[pos] = (uint32_t)s | ((uint32_t)(d & 511) << 17);
  }
}

// per-bucket counting sort + emit offs/deg/dinv + fused dinv-prescale of x -> bf16 (F=32)
__global__ __launch_bounds__(512) void k_bsort2(const uint32_t* __restrict__ ebuf, const int* __restrict__ bb,
                                                const void* __restrict__ x, const int* __restrict__ flag,
                                                int* __restrict__ adj, int* __restrict__ offs,
                                                int* __restrict__ deg, float* __restrict__ dinv,
                                                u16* __restrict__ Bout){
  __shared__ uint32_t ein[5120], outs[5120];
  __shared__ int hist[512], sc[512], cu[512];
  __shared__ float dv[512];
  int b = blockIdx.x, tid = threadIdx.x;
  int lo = bb[b], hi = bb[b+1];
  int cnt = hi - lo; if (cnt > 5120) cnt = 5120; if (cnt < 0) cnt = 0;
  hist[tid] = 0;
  __syncthreads();
  for (int i=tid; i<cnt; i+=512){
    uint32_t p = ebuf[lo+i];
    ein[i] = p;
    atomicAdd(&hist[(p>>17)&511], 1);
  }
  __syncthreads();
  sc[tid] = hist[tid];
  __syncthreads();
  for (int d=1; d<512; d<<=1){
    int v = (tid>=d) ? sc[tid-d] : 0;
    __syncthreads();
    sc[tid] += v;
    __syncthreads();
  }
  {
    int ex = sc[tid] - hist[tid];
    int node = b*512 + tid;
    offs[node] = lo + ex;
    deg[node]  = hist[tid];
    float rs = rsqrtf((float)hist[tid] + 1.0f);
    dinv[node] = rs;
    dv[tid] = rs;
    cu[tid] = ex;
  }
  __syncthreads();
  for (int i=tid; i<cnt; i+=512){
    uint32_t p = ein[i];
    int pos = atomicAdd(&cu[(p>>17)&511], 1);
    outs[pos] = p & 0x1FFFFu;
  }
  __syncthreads();
  for (int i=tid; i<cnt; i+=512) adj[lo+i] = (int)outs[i];
  int isbf = *flag;
  for (int u=tid; u<16384; u+=512){
    int nl = u>>5, c = u&31;
    int idx = ((b<<9) + nl)*32 + c;
    stv(Bout, idx, dv[nl]*ldmix(x, idx, isbf));
  }
}

// ---- GCN aggregation on prescaled bf16 rows: out[n] = bf16(dinv[n]*(Xs[n] + sum_in Xs[s])) ----
template<int F>
__global__ __launch_bounds__(256) void k_aggp(const u16* __restrict__ Xs,
                                              const int* __restrict__ adj, const int* __restrict__ offs,
                                              const int* __restrict__ deg, const float* __restrict__ dinv,
                                              u16* __restrict__ out){
  constexpr int LOG = (F==64) ? 6 : 5;
  int c = threadIdx.x & (F-1);
  int slot = threadIdx.x >> LOG;
  int n = blockIdx.x*(256>>LOG) + slot;
  int o = offs[n] & (N_EDGES-1);
  int cnt = min(deg[n], 8192);
  float acc = ldv(Xs, (n<<LOG)+c);            // prescaled self term
  int e = 0;
  for (; e+8 <= cnt; e += 8){
    int s0 = adj[o+e+0] & (N_NODES-1);
    int s1 = adj[o+e+1] & (N_NODES-1);
    int s2 = adj[o+e+2] & (N_NODES-1);
    int s3 = adj[o+e+3] & (N_NODES-1);
    int s4 = adj[o+e+4] & (N_NODES-1);
    int s5 = adj[o+e+5] & (N_NODES-1);
    int s6 = adj[o+e+6] & (N_NODES-1);
    int s7 = adj[o+e+7] & (N_NODES-1);
    float x0 = ldv(Xs, (s0<<LOG)+c);
    float x1 = ldv(Xs, (s1<<LOG)+c);
    float x2 = ldv(Xs, (s2<<LOG)+c);
    float x3 = ldv(Xs, (s3<<LOG)+c);
    float x4 = ldv(Xs, (s4<<LOG)+c);
    float x5 = ldv(Xs, (s5<<LOG)+c);
    float x6 = ldv(Xs, (s6<<LOG)+c);
    float x7 = ldv(Xs, (s7<<LOG)+c);
    acc += ((x0+x1)+(x2+x3)) + ((x4+x5)+(x6+x7));
  }
  if (e + 4 <= cnt){
    int s0 = adj[o+e+0] & (N_NODES-1);
    int s1 = adj[o+e+1] & (N_NODES-1);
    int s2 = adj[o+e+2] & (N_NODES-1);
    int s3 = adj[o+e+3] & (N_NODES-1);
    float x0 = ldv(Xs, (s0<<LOG)+c);
    float x1 = ldv(Xs, (s1<<LOG)+c);
    float x2 = ldv(Xs, (s2<<LOG)+c);
    float x3 = ldv(Xs, (s3<<LOG)+c);
    acc += (x0+x1)+(x2+x3);
    e += 4;
  }
  for (; e<cnt; e++){
    int s = adj[o+e] & (N_NODES-1);
    acc += ldv(Xs, (s<<LOG)+c);
  }
  stv(out, (n<<LOG)+c, dinv[n]*acc);
}

// ---- combine GCN weight with temporal-conv weight; write bf16 TRANSPOSED  ----
template<int Kin>
__global__ __launch_bounds__(64) void k_wcomb(const void* __restrict__ gW, const void* __restrict__ gb,
                                              const void* __restrict__ tw, const int* __restrict__ flag,
                                              u16* __restrict__ Wtb, float* __restrict__ braw){
  int isbf = *flag;
  int r = blockIdx.x;
  int co = threadIdx.x;
  if (r < 3*Kin){
    int k = r / Kin, j = r % Kin;
    float acc = 0.f;
    for (int c=0; c<64; c++)
      acc += ldmix(gW, j*64+c, isbf) * ldmix(tw, co*192 + c*3 + k, isbf);
    Wtb[co*(3*Kin) + r] = f2u(acc);
  } else {
    int k = r - 3*Kin;
    float acc = 0.f;
    for (int c=0; c<64; c++)
      acc += ldmix(gb, c, isbf) * ldmix(tw, co*192 + c*3 + k, isbf);
    braw[k*64 + co] = acc;
  }
}

// ---- fused linear+temporal-conv via bf16 MFMA; input bf16, output fp32 ----
template<int Kin>
__global__ __launch_bounds__(256) void k_tconv3(const u16* __restrict__ A, const u16* __restrict__ Wtb,
                                                const float* __restrict__ braw, const void* __restrict__ tb,
                                                const int* __restrict__ flag, float* __restrict__ out){
  constexpr int K  = 3*Kin;
  constexpr int SA = Kin + 8;
  constexpr int SW = K + 8;
  constexpr int JH = Kin/2;
  constexpr int JL = (Kin==64) ? 5 : 4;
  __shared__ alignas(16) u16 At[130*SA];
  __shared__ alignas(16) u16 Wl[64*SW];
  __shared__ float ball[64], bs0[64], bs2[64];

  int isbf = *flag;
  int bid = blockIdx.x;
  int b = bid>>3, v = bid&7;
  const int tid = threadIdx.x;

  if (tid < 64){
    float b0=braw[tid], b1=braw[64+tid], b2=braw[128+tid];
    ball[tid] = ldmix(tb, tid, isbf) + b0 + b1 + b2;
    bs0[tid] = b0; bs2[tid] = b2;
  }
  {
    const uint32_t* Wg = (const uint32_t*)Wtb;
    uint32_t* Wd = (uint32_t*)Wl;
    for (int u=tid; u<64*(K/2); u+=256){
      int co = u/(K/2), jd = u - co*(K/2);
      Wd[co*(SW/2) + jd] = Wg[u];
    }
  }
  {
    uint32_t* Ad = (uint32_t*)At;
    const uint32_t* Ag = (const uint32_t*)A;
    for (int u=tid; u<130*JH; u+=256){
      int t1 = u >> JL, jd = u & (JH-1);
      int t = t1 - 1;
      uint32_t pack = 0;
      if (t >= 0 && t < 128)
        pack = Ag[((((b*128+t)*8+v))*Kin >> 1) + jd];     // direct bf16-pair copy
      Ad[t1*(SA/2) + jd] = pack;
    }
  }
  __syncthreads();

  int wv_ = tid >> 6, lane = tid & 63;
  int q = lane >> 4, l16 = lane & 15;
  int tb0 = wv_ * 32;

  f32x4 acc[2][4];
  #pragma unroll
  for (int mt=0; mt<2; mt++)
    #pragma unroll
    for (int nt=0; nt<4; nt++)
      acc[mt][nt] = (f32x4){0.f,0.f,0.f,0.f};

  #pragma unroll
  for (int s=0; s<K/32; s++){
    int kk = (32*s)/Kin;
    int j0 = 32*s - kk*Kin;
    int col = j0 + q*8;
    bf16x8 afr[2], bfr[4];
    #pragma unroll
    for (int mt=0; mt<2; mt++){
      int row = tb0 + mt*16 + l16 + kk;
      afr[mt] = *(const bf16x8*)&At[row*SA + col];
    }
    #pragma unroll
    for (int nt=0; nt<4; nt++){
      int co = nt*16 + l16;
      bfr[nt] = *(const bf16x8*)&Wl[co*SW + 32*s + q*8];
    }
    #pragma unroll
    for (int mt=0; mt<2; mt++)
      #pragma unroll
      for (int nt=0; nt<4; nt++)
        acc[mt][nt] = __builtin_amdgcn_mfma_f32_16x16x32_bf16(afr[mt], bfr[nt], acc[mt][nt], 0, 0, 0);
  }

  #pragma unroll
  for (int mt=0; mt<2; mt++){
    #pragma unroll
    for (int r=0; r<4; r++){
      int t = tb0 + mt*16 + q*4 + r;
      int base = (((b*128+t)*8+v)) << 6;
      #pragma unroll
      for (int nt=0; nt<4; nt++){
        int co = nt*16 + l16;
        float val = acc[mt][nt][r] + ball[co];
        if (t == 0)   val -= bs0[co];
        if (t == 127) val -= bs2[co];
        out[base + co] = val;
      }
    }
  }
}

// ---- BN stats: per-channel sum / sumsq (float4, fp32 input) ----
__global__ __launch_bounds__(256) void k_stats(const float* __restrict__ X, float* __restrict__ stats){
  int cq = (threadIdx.x & 15) << 2;
  int g  = threadIdx.x >> 4;
  float4 s  = make_float4(0.f,0.f,0.f,0.f);
  float4 s2 = make_float4(0.f,0.f,0.f,0.f);
  for (int row = blockIdx.x*16 + g; row < N_NODES; row += gridDim.x*16){
    float4 v = ld4(X, (row<<6) + cq);
    s.x += v.x; s.y += v.y; s.z += v.z; s.w += v.w;
    s2.x += v.x*v.x; s2.y += v.y*v.y; s2.z += v.z*v.z; s2.w += v.w*v.w;
  }
  __shared__ float sh[16][64], sh2[16][64];
  *(float4*)&sh[g][cq]  = s;
  *(float4*)&sh2[g][cq] = s2;
  __syncthreads();
  if (threadIdx.x < 64){
    int co = threadIdx.x;
    float a = 0.f, a2 = 0.f;
    #pragma unroll
    for (int gg=0; gg<16; gg++){ a += sh[gg][co]; a2 += sh2[gg][co]; }
    atomicAdd(&stats[co], a);
    atomicAdd(&stats[64+co], a2);
  }
}

// ---- BN-apply + ReLU + 1x1 conv + tanh (+ optional dinv-prescale) + scrambled bf16 write ----
__global__ __launch_bounds__(256) void k_bnfuse(const float* __restrict__ X, const float* __restrict__ stats,
                                                const void* __restrict__ gam, const void* __restrict__ bet,
                                                const void* __restrict__ ow, const void* __restrict__ ob,
                                                const int* __restrict__ flag, const float* __restrict__ presc,
                                                u16* __restrict__ out){
  __shared__ float y_s[64*68];
  __shared__ float ow_s[64*64];
  __shared__ float kk[64], bsh[64];
  int isbf = *flag;
  int bid = blockIdx.x;
  int b = bid>>4, rem = bid&15, v = rem>>1, thi = rem&1;
  int t0 = thi<<6;
  const float invM = 1.0f/131072.0f;
  if (threadIdx.x < 64){
    int ci = threadIdx.x;
    float mu = stats[ci]*invM;
    float var = stats[64+ci]*invM - mu*mu;
    float rs = rsqrtf(fmaxf(var, 0.f) + 1e-5f);
    float kv = rs*ldmix(gam, ci, isbf);
    kk[ci] = kv;
    bsh[ci] = ldmix(bet, ci, isbf) - mu*kv;
  }
  for (int u=threadIdx.x; u<1024; u+=256){
    int r = u>>4, cq = (u&15)<<2;
    *(float4*)&ow_s[(r<<6)+cq] = ld4mix(ow, (r<<6)+cq, isbf);
  }
  __syncthreads();
  for (int u=threadIdx.x; u<1024; u+=256){
    int tl = u>>4, cq = (u&15)<<2;
    int t = t0 + tl;
    float4 val = ld4(X, (((b*128+t)*8+v)<<6) + cq);
    float4 kq = *(const float4*)&kk[cq];
    float4 bq = *(const float4*)&bsh[cq];
    val.x = fmaxf(val.x*kq.x + bq.x, 0.f);
    val.y = fmaxf(val.y*kq.y + bq.y, 0.f);
    val.z = fmaxf(val.z*kq.z + bq.z, 0.f);
    val.w = fmaxf(val.w*kq.w + bq.w, 0.f);
    *(float4*)&y_s[tl*68 + cq] = val;
  }
  __syncthreads();
  int l = threadIdx.x & 63, wg = threadIdx.x >> 6;
  float acc[16];
  #pragma unroll
  for (int c8=0; c8<16; c8++) acc[c8] = ldmix(ob, wg*16 + c8, isbf);
  for (int ci=0; ci<64; ci+=4){
    float4 y4 = *(const float4*)&y_s[l*68 + ci];
    #pragma unroll
    for (int c8=0; c8<16; c8++){
      float4 w4 = *(const float4*)&ow_s[((wg*16+c8)<<6) + ci];
      acc[c8] += y4.x*w4.x + y4.y*w4.y + y4.z*w4.z + y4.w*w4.w;
    }
  }
  #pragma unroll
  for (int c8=0; c8<16; c8++){
    int co = wg*16 + c8;
    float z = tanhf(acc[c8]);
    int r = (b<<10) + (co<<4) + (v<<1) + thi;
    if (presc) z *= presc[r];
    stv(out, (r<<6) + l, z);
  }
}

// ---- final: out[b,v] = mean_{t,f}( x3 @ reg_w + reg_b ), bf16 input ----
__global__ __launch_bounds__(256) void k_final(const u16* __restrict__ X, const void* __restrict__ rw,
                                               const void* __restrict__ rb, const int* __restrict__ flag,
                                               void* __restrict__ out){
  __shared__ float rw_s[64];
  __shared__ float rbs_s;
  __shared__ float wred[4];
  int isbf = *flag;
  int bid = blockIdx.x;
  int b = bid>>3, v = bid&7;
  if (threadIdx.x < 64){
    float s = 0.f;
    #pragma unroll
    for (int f=0; f<8; f++) s += ldmix(rw, threadIdx.x*8 + f, isbf);
    rw_s[threadIdx.x] = s;
  }
  if (threadIdx.x == 0){
    float s = 0.f;
    for (int f=0; f<8; f++) s += ldmix(rb, f, isbf);
    rbs_s = s;
  }
  __syncthreads();
  float acc = 0.f;
  for (int i=threadIdx.x; i<128*64; i+=256){
    int t = i>>6, j = i&63;
    acc += ldv(X, (((b*128+t)*8+v)<<6) + j) * rw_s[j];
  }
  for (int off=32; off; off>>=1) acc += __shfl_down(acc, off);
  if ((threadIdx.x & 63) == 0) wred[threadIdx.x>>6] = acc;
  __syncthreads();
  if (threadIdx.x == 0){
    float r = wred[0]+wred[1]+wred[2]+wred[3];
    float val = r*(1.0f/1024.0f) + rbs_s*0.125f;
    if (isbf) ((u16*)out)[bid] = f2u(val);
    else      ((float*)out)[bid] = val;
  }
}

extern "C" void kernel_launch(void* const* d_in, const int* in_sizes, int n_in,
                              void* d_out, int out_size, void* d_ws, size_t ws_size,
                              hipStream_t stream){
  (void)in_sizes; (void)n_in; (void)out_size; (void)ws_size;
  char* p = (char*)d_ws;
  auto alloc = [&](size_t bytes){ void* r = (void*)p; p += (bytes + 255) & ~(size_t)255; return r; };
  u16*   U1   = (u16*)  alloc(sizeof(u16)*(size_t)N_NODES*64);  // Bs16 | A16 ; later D16
  u16*   U2   = (u16*)  alloc(sizeof(u16)*(size_t)N_NODES*64);  // E16 ; later F16
  float* C    = (float*)alloc(sizeof(float)*(size_t)N_NODES*64);// tconv out (fp32)
  int*   deg  = (int*)  alloc(sizeof(int)*N_NODES);
  float* dinv = (float*)alloc(sizeof(float)*N_NODES);
  int*   offs = (int*)  alloc(sizeof(int)*N_NODES);
  int*   adj  = (int*)  alloc(sizeof(int)*N_EDGES);
  int*   H    = (int*)  alloc(sizeof(int)*256*256);
  int*   P    = (int*)  alloc(sizeof(int)*256*256);
  int*   bt   = (int*)  alloc(sizeof(int)*256);
  int*   bb   = (int*)  alloc(sizeof(int)*260);
  float* stats= (float*)alloc(sizeof(float)*128);
  int*   flag = (int*)  alloc(sizeof(int)*64);
  u16*   Wtb  = (u16*)  alloc(sizeof(u16)*192*64);
  float* braw = (float*)alloc(sizeof(float)*192);
  uint32_t* ebuf = (uint32_t*)C;             // alias: C dead until tconv1
  u16* Bs16 = U1;                            // N x 32 bf16 (prescaled x)
  u16* A16  = U1 + (size_t)N_NODES*32;       // N x 32 bf16 (agg1 out)
  u16* D16  = U1;                            // N x 64 bf16 (bnfuse1 out, prescaled)
  u16* E16  = U2;                            // N x 64 bf16 (agg2 out)
  u16* F16  = U2;                            // N x 64 bf16 (bnfuse2 out)

  const void* x   = d_in[0];
  const int* edge = (const int*)d_in[1];
  const void* g1w = d_in[2];  const void* g1b = d_in[3];
  const void* t1w = d_in[4];  const void* t1b = d_in[5];
  const void* bn1g= d_in[6];  const void* bn1b= d_in[7];
  const void* o1w = d_in[8];  const void* o1b = d_in[9];
  const void* g2w = d_in[10]; const void* g2b = d_in[11];
  const void* t2w = d_in[12]; const void* t2b = d_in[13];
  const void* bn2g= d_in[14]; const void* bn2b= d_in[15];
  const void* o2w = d_in[16]; const void* o2b = d_in[17];
  const void* rw  = d_in[18]; const void* rb  = d_in[19];
  const int* src = edge;
  const int* dst = edge + N_EDGES;

  k_detect<<<1, 64, 0, stream>>>((const uint32_t*)x, flag);

  // graph prep: two-pass counting sort, zero global atomics
  k_hist    <<<256, 256, 0, stream>>>(dst, H);
  k_colscan <<<256, 256, 0, stream>>>(H, P, bt);
  k_bbscan  <<<1, 256, 0, stream>>>(bt, bb);
  k_scatter2<<<256, 256, 0, stream>>>(src, dst, P, bb, ebuf);
  k_bsort2  <<<256, 512, 0, stream>>>(ebuf, bb, x, flag, adj, offs, deg, dinv, Bs16);

  // ---- layer 1 ----
  k_aggp<32>   <<<N_NODES/8, 256, 0, stream>>>(Bs16, adj, offs, deg, dinv, A16);
  k_wcomb<32>  <<<3*32+3, 64, 0, stream>>>(g1w, g1b, t1w, flag, Wtb, braw);
  k_tconv3<32> <<<1024, 256, 0, stream>>>(A16, Wtb, braw, t1b, flag, C);
  hipMemsetAsync(stats, 0, sizeof(float)*128, stream);
  k_stats      <<<512, 256, 0, stream>>>(C, stats);
  k_bnfuse     <<<2048, 256, 0, stream>>>(C, stats, bn1g, bn1b, o1w, o1b, flag, dinv, D16);

  // ---- layer 2 ----
  k_aggp<64>   <<<N_NODES/4, 256, 0, stream>>>(D16, adj, offs, deg, dinv, E16);
  k_wcomb<64>  <<<3*64+3, 64, 0, stream>>>(g2w, g2b, t2w, flag, Wtb, braw);
  k_tconv3<64> <<<1024, 256, 0, stream>>>(E16, Wtb, braw, t2b, flag, C);
  hipMemsetAsync(stats, 0, sizeof(float)*128, stream);
  k_stats      <<<512, 256, 0, stream>>>(C, stats);
  k_bnfuse     <<<2048, 256, 0, stream>>>(C, stats, bn2g, bn2b, o2w, o2b, flag, (const float*)nullptr, F16);

  // ---- regression + mean ----
  k_final<<<1024, 256, 0, stream>>>(F16, rw, rb, flag, d_out);
}

// Round 11
// 367.990 us; speedup vs baseline: 1.6949x; 1.1060x over previous
//
#include <hip/hip_runtime.h>
#include <stdint.h>

typedef unsigned short u16;
typedef __attribute__((ext_vector_type(8))) short bf16x8;
typedef __attribute__((ext_vector_type(4))) float f32x4;

static const int N_NODES = 131072;   // B*T*NN = 128*128*8
static const int N_EDGES = 1048576;

__device__ __forceinline__ float u2f(u16 u){
  union{uint32_t i; float f;} w; w.i = ((uint32_t)u)<<16; return w.f;
}
__device__ __forceinline__ u16 f2u(float f){
  union{float f; uint32_t u;} v; v.f=f;
  uint32_t u=v.u;
  u += 0x7fff + ((u>>16)&1);   // round-to-nearest-even
  return (u16)(u>>16);
}
__device__ __forceinline__ float bits2f(uint32_t b){
  union{uint32_t i; float f;} w; w.i = b; return w.f;
}
__device__ __forceinline__ float ldv(const float* p, int i){ return p[i]; }
__device__ __forceinline__ float ldv(const u16* p, int i){ return u2f(p[i]); }
__device__ __forceinline__ void stv(float* p, int i, float v){ p[i]=v; }
__device__ __forceinline__ void stv(u16* p, int i, float v){ p[i]=f2u(v); }
__device__ __forceinline__ float4 ld4(const float* p, int i){ return *(const float4*)(p+i); }
__device__ __forceinline__ float4 ld4(const u16* p, int i){
  ushort4 u = *(const ushort4*)(p+i);
  return make_float4(u2f(u.x), u2f(u.y), u2f(u.z), u2f(u.w));
}
__device__ __forceinline__ float ldmix(const void* p, int i, int isbf){
  return isbf ? u2f(((const u16*)p)[i]) : ((const float*)p)[i];
}
__device__ __forceinline__ float4 ld4mix(const void* p, int i, int isbf){
  if (isbf){ return ld4((const u16*)p, i); }
  return ld4((const float*)p, i);
}

// ---------------- dtype detection ----------------
__global__ void k_detect(const uint32_t* __restrict__ x, int* __restrict__ flag){
  if (threadIdx.x==0 && blockIdx.x==0){
    int cnt=0;
    for (int i=0;i<256;i++){
      uint32_t e=(x[i]>>7)&0xFFu;
      if (e>=0x6Fu && e<=0x85u) cnt++;
    }
    *flag = (cnt>=128) ? 1 : 0;
  }
}

// ---------------- graph prep: two-pass counting sort, NO global atomics ----------------
__global__ __launch_bounds__(256) void k_hist(const int* __restrict__ dst, int* __restrict__ H){
  __shared__ int h[256];
  int tid = threadIdx.x;
  h[tid] = 0;
  __syncthreads();
  int base = blockIdx.x*4096;
  #pragma unroll
  for (int i=0;i<16;i++){
    int e = base + i*256 + tid;
    atomicAdd(&h[(dst[e] & (N_NODES-1))>>9], 1);
  }
  __syncthreads();
  H[blockIdx.x*256 + tid] = h[tid];
}

__global__ __launch_bounds__(256) void k_colscan(const int* __restrict__ H, int* __restrict__ P,
                                                 int* __restrict__ bt){
  __shared__ int sc[256];
  int b = blockIdx.x, tid = threadIdx.x;
  int v = H[tid*256 + b];
  sc[tid] = v; __syncthreads();
  for (int d=1; d<256; d<<=1){
    int o = (tid>=d) ? sc[tid-d] : 0; __syncthreads();
    sc[tid] += o; __syncthreads();
  }
  P[tid*256 + b] = sc[tid] - v;
  if (tid==255) bt[b] = sc[255];
}

__global__ __launch_bounds__(256) void k_bbscan(const int* __restrict__ bt, int* __restrict__ bb){
  __shared__ int sc[256];
  int t = threadIdx.x;
  int v = bt[t]; sc[t]=v; __syncthreads();
  for (int d=1; d<256; d<<=1){
    int o = (t>=d) ? sc[t-d] : 0; __syncthreads();
    sc[t] += o; __syncthreads();
  }
  bb[t] = sc[t]-v;
  if (t==255) bb[256] = sc[t];
}

__global__ __launch_bounds__(256) void k_scatter2(const int* __restrict__ src, const int* __restrict__ dst,
                                                  const int* __restrict__ P, const int* __restrict__ bb,
                                                  uint32_t* __restrict__ ebuf){
  __shared__ int cu[256];
  int tid = threadIdx.x;
  cu[tid] = bb[tid] + P[blockIdx.x*256 + tid];
  __syncthreads();
  int base = blockIdx.x*4096;
  #pragma unroll
  for (int i=0;i<16;i++){
    int e = base + i*256 + tid;
    int s = src[e] & (N_NODES-1);
    int d = dst[e] & (N_NODES-1);
    int pos = atomicAdd(&cu[d>>9], 1);           // LDS atomic only
    ebuf[pos] = (uint32_t)s | ((uint32_t)(d & 511) << 17);
  }
}

// per-bucket counting sort + emit offs/deg/dinv + fused dinv-prescale of x -> bf16 (F=32)
__global__ __launch_bounds__(512) void k_bsort2(const uint32_t* __restrict__ ebuf, const int* __restrict__ bb,
                                                const void* __restrict__ x, const int* __restrict__ flag,
                                                int* __restrict__ adj, int* __restrict__ offs,
                                                int* __restrict__ deg, float* __restrict__ dinv,
                                                u16* __restrict__ Bout){
  __shared__ uint32_t ein[5120], outs[5120];
  __shared__ int hist[512], sc[512], cu[512];
  __shared__ float dv[512];
  int b = blockIdx.x, tid = threadIdx.x;
  int lo = bb[b], hi = bb[b+1];
  int cnt = hi - lo; if (cnt > 5120) cnt = 5120; if (cnt < 0) cnt = 0;
  hist[tid] = 0;
  __syncthreads();
  for (int i=tid; i<cnt; i+=512){
    uint32_t p = ebuf[lo+i];
    ein[i] = p;
    atomicAdd(&hist[(p>>17)&511], 1);
  }
  __syncthreads();
  sc[tid] = hist[tid];
  __syncthreads();
  for (int d=1; d<512; d<<=1){
    int v = (tid>=d) ? sc[tid-d] : 0;
    __syncthreads();
    sc[tid] += v;
    __syncthreads();
  }
  {
    int ex = sc[tid] - hist[tid];
    int node = b*512 + tid;
    offs[node] = lo + ex;
    deg[node]  = hist[tid];
    float rs = rsqrtf((float)hist[tid] + 1.0f);
    dinv[node] = rs;
    dv[tid] = rs;
    cu[tid] = ex;
  }
  __syncthreads();
  for (int i=tid; i<cnt; i+=512){
    uint32_t p = ein[i];
    int pos = atomicAdd(&cu[(p>>17)&511], 1);
    outs[pos] = p & 0x1FFFFu;
  }
  __syncthreads();
  for (int i=tid; i<cnt; i+=512) adj[lo+i] = (int)outs[i];
  int isbf = *flag;
  for (int u=tid; u<16384; u+=512){
    int nl = u>>5, c = u&31;
    int idx = ((b<<9) + nl)*32 + c;
    stv(Bout, idx, dv[nl]*ldmix(x, idx, isbf));
  }
}

// ---- GCN aggregation, chunked multi-node-per-wave gather ----
// F=64: wave = 8 nodes x 8 chunks(16B).  F=32: wave = 16 nodes x 4 chunks.
// One gather instruction covers (64/CH) nodes' rows; lane-local accumulation, no reduction.
__device__ __forceinline__ void acc16(uint4 a, float* acc){
  acc[0] += bits2f(a.x<<16); acc[1] += bits2f(a.x&0xFFFF0000u);
  acc[2] += bits2f(a.y<<16); acc[3] += bits2f(a.y&0xFFFF0000u);
  acc[4] += bits2f(a.z<<16); acc[5] += bits2f(a.z&0xFFFF0000u);
  acc[6] += bits2f(a.w<<16); acc[7] += bits2f(a.w&0xFFFF0000u);
}
template<int F>
__global__ __launch_bounds__(256) void k_aggp2(const u16* __restrict__ Xs,
                                               const int* __restrict__ adj, const int* __restrict__ offs,
                                               const int* __restrict__ deg, const float* __restrict__ dinv,
                                               u16* __restrict__ out){
  constexpr int CH  = F/8;            // 16B chunks per row: 8 (F=64) or 4 (F=32)
  constexpr int GPW = 64/CH;          // nodes per wave: 8 or 16
  int tid = threadIdx.x;
  int wv = tid>>6, lane = tid&63;
  int g = lane / CH;
  int k = lane % CH;
  int n = blockIdx.x*(4*GPW) + wv*GPW + g;
  int o = offs[n] & (N_EDGES-1);
  int cnt = min(deg[n], 8192);
  const uint4* X4 = (const uint4*)Xs;
  uint4 sv = X4[(size_t)n*CH + k];              // contiguous 1KB per wave
  float acc[8] = {0,0,0,0,0,0,0,0};
  acc16(sv, acc);
  int e = 0;
  for (; e+4 <= cnt; e += 4){
    int i0 = adj[o+e+0] & (N_NODES-1);
    int i1 = adj[o+e+1] & (N_NODES-1);
    int i2 = adj[o+e+2] & (N_NODES-1);
    int i3 = adj[o+e+3] & (N_NODES-1);
    uint4 a0 = X4[(size_t)i0*CH + k];
    uint4 a1 = X4[(size_t)i1*CH + k];
    uint4 a2 = X4[(size_t)i2*CH + k];
    uint4 a3 = X4[(size_t)i3*CH + k];
    acc16(a0, acc); acc16(a1, acc); acc16(a2, acc); acc16(a3, acc);
  }
  for (; e < cnt; e++){
    int s = adj[o+e] & (N_NODES-1);
    uint4 a = X4[(size_t)s*CH + k];
    acc16(a, acc);
  }
  float dv = dinv[n];
  uint4 r;
  r.x = (uint32_t)f2u(acc[0]*dv) | ((uint32_t)f2u(acc[1]*dv) << 16);
  r.y = (uint32_t)f2u(acc[2]*dv) | ((uint32_t)f2u(acc[3]*dv) << 16);
  r.z = (uint32_t)f2u(acc[4]*dv) | ((uint32_t)f2u(acc[5]*dv) << 16);
  r.w = (uint32_t)f2u(acc[6]*dv) | ((uint32_t)f2u(acc[7]*dv) << 16);
  ((uint4*)out)[(size_t)n*CH + k] = r;          // contiguous 1KB per wave
}

// ---- combine GCN weight with temporal-conv weight; write bf16 TRANSPOSED  ----
template<int Kin>
__global__ __launch_bounds__(64) void k_wcomb(const void* __restrict__ gW, const void* __restrict__ gb,
                                              const void* __restrict__ tw, const int* __restrict__ flag,
                                              u16* __restrict__ Wtb, float* __restrict__ braw){
  int isbf = *flag;
  int r = blockIdx.x;
  int co = threadIdx.x;
  if (r < 3*Kin){
    int k = r / Kin, j = r % Kin;
    float acc = 0.f;
    for (int c=0; c<64; c++)
      acc += ldmix(gW, j*64+c, isbf) * ldmix(tw, co*192 + c*3 + k, isbf);
    Wtb[co*(3*Kin) + r] = f2u(acc);
  } else {
    int k = r - 3*Kin;
    float acc = 0.f;
    for (int c=0; c<64; c++)
      acc += ldmix(gb, c, isbf) * ldmix(tw, co*192 + c*3 + k, isbf);
    braw[k*64 + co] = acc;
  }
}

// ---- fused linear+temporal-conv via bf16 MFMA; input bf16, output fp32 ----
template<int Kin>
__global__ __launch_bounds__(256) void k_tconv3(const u16* __restrict__ A, const u16* __restrict__ Wtb,
                                                const float* __restrict__ braw, const void* __restrict__ tb,
                                                const int* __restrict__ flag, float* __restrict__ out){
  constexpr int K  = 3*Kin;
  constexpr int SA = Kin + 8;
  constexpr int SW = K + 8;
  constexpr int JH = Kin/2;
  constexpr int JL = (Kin==64) ? 5 : 4;
  __shared__ alignas(16) u16 At[130*SA];
  __shared__ alignas(16) u16 Wl[64*SW];
  __shared__ float ball[64], bs0[64], bs2[64];

  int isbf = *flag;
  int bid = blockIdx.x;
  int b = bid>>3, v = bid&7;
  const int tid = threadIdx.x;

  if (tid < 64){
    float b0=braw[tid], b1=braw[64+tid], b2=braw[128+tid];
    ball[tid] = ldmix(tb, tid, isbf) + b0 + b1 + b2;
    bs0[tid] = b0; bs2[tid] = b2;
  }
  {
    const uint32_t* Wg = (const uint32_t*)Wtb;
    uint32_t* Wd = (uint32_t*)Wl;
    for (int u=tid; u<64*(K/2); u+=256){
      int co = u/(K/2), jd = u - co*(K/2);
      Wd[co*(SW/2) + jd] = Wg[u];
    }
  }
  {
    uint32_t* Ad = (uint32_t*)At;
    const uint32_t* Ag = (const uint32_t*)A;
    for (int u=tid; u<130*JH; u+=256){
      int t1 = u >> JL, jd = u & (JH-1);
      int t = t1 - 1;
      uint32_t pack = 0;
      if (t >= 0 && t < 128)
        pack = Ag[((((b*128+t)*8+v))*Kin >> 1) + jd];     // direct bf16-pair copy
      Ad[t1*(SA/2) + jd] = pack;
    }
  }
  __syncthreads();

  int wv_ = tid >> 6, lane = tid & 63;
  int q = lane >> 4, l16 = lane & 15;
  int tb0 = wv_ * 32;

  f32x4 acc[2][4];
  #pragma unroll
  for (int mt=0; mt<2; mt++)
    #pragma unroll
    for (int nt=0; nt<4; nt++)
      acc[mt][nt] = (f32x4){0.f,0.f,0.f,0.f};

  #pragma unroll
  for (int s=0; s<K/32; s++){
    int kk = (32*s)/Kin;
    int j0 = 32*s - kk*Kin;
    int col = j0 + q*8;
    bf16x8 afr[2], bfr[4];
    #pragma unroll
    for (int mt=0; mt<2; mt++){
      int row = tb0 + mt*16 + l16 + kk;
      afr[mt] = *(const bf16x8*)&At[row*SA + col];
    }
    #pragma unroll
    for (int nt=0; nt<4; nt++){
      int co = nt*16 + l16;
      bfr[nt] = *(const bf16x8*)&Wl[co*SW + 32*s + q*8];
    }
    #pragma unroll
    for (int mt=0; mt<2; mt++)
      #pragma unroll
      for (int nt=0; nt<4; nt++)
        acc[mt][nt] = __builtin_amdgcn_mfma_f32_16x16x32_bf16(afr[mt], bfr[nt], acc[mt][nt], 0, 0, 0);
  }

  #pragma unroll
  for (int mt=0; mt<2; mt++){
    #pragma unroll
    for (int r=0; r<4; r++){
      int t = tb0 + mt*16 + q*4 + r;
      int base = (((b*128+t)*8+v)) << 6;
      #pragma unroll
      for (int nt=0; nt<4; nt++){
        int co = nt*16 + l16;
        float val = acc[mt][nt][r] + ball[co];
        if (t == 0)   val -= bs0[co];
        if (t == 127) val -= bs2[co];
        out[base + co] = val;
      }
    }
  }
}

// ---- BN stats: per-channel sum / sumsq (float4, fp32 input) ----
__global__ __launch_bounds__(256) void k_stats(const float* __restrict__ X, float* __restrict__ stats){
  int cq = (threadIdx.x & 15) << 2;
  int g  = threadIdx.x >> 4;
  float4 s  = make_float4(0.f,0.f,0.f,0.f);
  float4 s2 = make_float4(0.f,0.f,0.f,0.f);
  for (int row = blockIdx.x*16 + g; row < N_NODES; row += gridDim.x*16){
    float4 v = ld4(X, (row<<6) + cq);
    s.x += v.x; s.y += v.y; s.z += v.z; s.w += v.w;
    s2.x += v.x*v.x; s2.y += v.y*v.y; s2.z += v.z*v.z; s2.w += v.w*v.w;
  }
  __shared__ float sh[16][64], sh2[16][64];
  *(float4*)&sh[g][cq]  = s;
  *(float4*)&sh2[g][cq] = s2;
  __syncthreads();
  if (threadIdx.x < 64){
    int co = threadIdx.x;
    float a = 0.f, a2 = 0.f;
    #pragma unroll
    for (int gg=0; gg<16; gg++){ a += sh[gg][co]; a2 += sh2[gg][co]; }
    atomicAdd(&stats[co], a);
    atomicAdd(&stats[64+co], a2);
  }
}

// ---- BN-apply + ReLU + 1x1 conv + tanh (+ optional dinv-prescale) + scrambled bf16 write ----
__global__ __launch_bounds__(256) void k_bnfuse(const float* __restrict__ X, const float* __restrict__ stats,
                                                const void* __restrict__ gam, const void* __restrict__ bet,
                                                const void* __restrict__ ow, const void* __restrict__ ob,
                                                const int* __restrict__ flag, const float* __restrict__ presc,
                                                u16* __restrict__ out){
  __shared__ float y_s[64*68];
  __shared__ float ow_s[64*64];
  __shared__ float kk[64], bsh[64];
  int isbf = *flag;
  int bid = blockIdx.x;
  int b = bid>>4, rem = bid&15, v = rem>>1, thi = rem&1;
  int t0 = thi<<6;
  const float invM = 1.0f/131072.0f;
  if (threadIdx.x < 64){
    int ci = threadIdx.x;
    float mu = stats[ci]*invM;
    float var = stats[64+ci]*invM - mu*mu;
    float rs = rsqrtf(fmaxf(var, 0.f) + 1e-5f);
    float kv = rs*ldmix(gam, ci, isbf);
    kk[ci] = kv;
    bsh[ci] = ldmix(bet, ci, isbf) - mu*kv;
  }
  for (int u=threadIdx.x; u<1024; u+=256){
    int r = u>>4, cq = (u&15)<<2;
    *(float4*)&ow_s[(r<<6)+cq] = ld4mix(ow, (r<<6)+cq, isbf);
  }
  __syncthreads();
  for (int u=threadIdx.x; u<1024; u+=256){
    int tl = u>>4, cq = (u&15)<<2;
    int t = t0 + tl;
    float4 val = ld4(X, (((b*128+t)*8+v)<<6) + cq);
    float4 kq = *(const float4*)&kk[cq];
    float4 bq = *(const float4*)&bsh[cq];
    val.x = fmaxf(val.x*kq.x + bq.x, 0.f);
    val.y = fmaxf(val.y*kq.y + bq.y, 0.f);
    val.z = fmaxf(val.z*kq.z + bq.z, 0.f);
    val.w = fmaxf(val.w*kq.w + bq.w, 0.f);
    *(float4*)&y_s[tl*68 + cq] = val;
  }
  __syncthreads();
  int l = threadIdx.x & 63, wg = threadIdx.x >> 6;
  float acc[16];
  #pragma unroll
  for (int c8=0; c8<16; c8++) acc[c8] = ldmix(ob, wg*16 + c8, isbf);
  for (int ci=0; ci<64; ci+=4){
    float4 y4 = *(const float4*)&y_s[l*68 + ci];
    #pragma unroll
    for (int c8=0; c8<16; c8++){
      float4 w4 = *(const float4*)&ow_s[((wg*16+c8)<<6) + ci];
      acc[c8] += y4.x*w4.x + y4.y*w4.y + y4.z*w4.z + y4.w*w4.w;
    }
  }
  #pragma unroll
  for (int c8=0; c8<16; c8++){
    int co = wg*16 + c8;
    float z = tanhf(acc[c8]);
    int r = (b<<10) + (co<<4) + (v<<1) + thi;
    if (presc) z *= presc[r];
    stv(out, (r<<6) + l, z);
  }
}

// ---- final: out[b,v] = mean_{t,f}( x3 @ reg_w + reg_b ), bf16 input ----
__global__ __launch_bounds__(256) void k_final(const u16* __restrict__ X, const void* __restrict__ rw,
                                               const void* __restrict__ rb, const int* __restrict__ flag,
                                               void* __restrict__ out){
  __shared__ float rw_s[64];
  __shared__ float rbs_s;
  __shared__ float wred[4];
  int isbf = *flag;
  int bid = blockIdx.x;
  int b = bid>>3, v = bid&7;
  if (threadIdx.x < 64){
    float s = 0.f;
    #pragma unroll
    for (int f=0; f<8; f++) s += ldmix(rw, threadIdx.x*8 + f, isbf);
    rw_s[threadIdx.x] = s;
  }
  if (threadIdx.x == 0){
    float s = 0.f;
    for (int f=0; f<8; f++) s += ldmix(rb, f, isbf);
    rbs_s = s;
  }
  __syncthreads();
  float acc = 0.f;
  for (int i=threadIdx.x; i<128*64; i+=256){
    int t = i>>6, j = i&63;
    acc += ldv(X, (((b*128+t)*8+v)<<6) + j) * rw_s[j];
  }
  for (int off=32; off; off>>=1) acc += __shfl_down(acc, off);
  if ((threadIdx.x & 63) == 0) wred[threadIdx.x>>6] = acc;
  __syncthreads();
  if (threadIdx.x == 0){
    float r = wred[0]+wred[1]+wred[2]+wred[3];
    float val = r*(1.0f/1024.0f) + rbs_s*0.125f;
    if (isbf) ((u16*)out)[bid] = f2u(val);
    else      ((float*)out)[bid] = val;
  }
}

extern "C" void kernel_launch(void* const* d_in, const int* in_sizes, int n_in,
                              void* d_out, int out_size, void* d_ws, size_t ws_size,
                              hipStream_t stream){
  (void)in_sizes; (void)n_in; (void)out_size; (void)ws_size;
  char* p = (char*)d_ws;
  auto alloc = [&](size_t bytes){ void* r = (void*)p; p += (bytes + 255) & ~(size_t)255; return r; };
  u16*   U1   = (u16*)  alloc(sizeof(u16)*(size_t)N_NODES*64);  // Bs16 | A16 ; later D16
  u16*   U2   = (u16*)  alloc(sizeof(u16)*(size_t)N_NODES*64);  // E16 ; later F16
  float* C    = (float*)alloc(sizeof(float)*(size_t)N_NODES*64);// tconv out (fp32)
  int*   deg  = (int*)  alloc(sizeof(int)*N_NODES);
  float* dinv = (float*)alloc(sizeof(float)*N_NODES);
  int*   offs = (int*)  alloc(sizeof(int)*N_NODES);
  int*   adj  = (int*)  alloc(sizeof(int)*N_EDGES);
  int*   H    = (int*)  alloc(sizeof(int)*256*256);
  int*   P    = (int*)  alloc(sizeof(int)*256*256);
  int*   bt   = (int*)  alloc(sizeof(int)*256);
  int*   bb   = (int*)  alloc(sizeof(int)*260);
  float* stats= (float*)alloc(sizeof(float)*128);
  int*   flag = (int*)  alloc(sizeof(int)*64);
  u16*   Wtb  = (u16*)  alloc(sizeof(u16)*192*64);
  float* braw = (float*)alloc(sizeof(float)*192);
  uint32_t* ebuf = (uint32_t*)C;             // alias: C dead until tconv1
  u16* Bs16 = U1;                            // N x 32 bf16 (prescaled x)
  u16* A16  = U1 + (size_t)N_NODES*32;       // N x 32 bf16 (agg1 out)
  u16* D16  = U1;                            // N x 64 bf16 (bnfuse1 out, prescaled)
  u16* E16  = U2;                            // N x 64 bf16 (agg2 out)
  u16* F16  = U2;                            // N x 64 bf16 (bnfuse2 out)

  const void* x   = d_in[0];
  const int* edge = (const int*)d_in[1];
  const void* g1w = d_in[2];  const void* g1b = d_in[3];
  const void* t1w = d_in[4];  const void* t1b = d_in[5];
  const void* bn1g= d_in[6];  const void* bn1b= d_in[7];
  const void* o1w = d_in[8];  const void* o1b = d_in[9];
  const void* g2w = d_in[10]; const void* g2b = d_in[11];
  const void* t2w = d_in[12]; const void* t2b = d_in[13];
  const void* bn2g= d_in[14]; const void* bn2b= d_in[15];
  const void* o2w = d_in[16]; const void* o2b = d_in[17];
  const void* rw  = d_in[18]; const void* rb  = d_in[19];
  const int* src = edge;
  const int* dst = edge + N_EDGES;

  k_detect<<<1, 64, 0, stream>>>((const uint32_t*)x, flag);

  // graph prep: two-pass counting sort, zero global atomics
  k_hist    <<<256, 256, 0, stream>>>(dst, H);
  k_colscan <<<256, 256, 0, stream>>>(H, P, bt);
  k_bbscan  <<<1, 256, 0, stream>>>(bt, bb);
  k_scatter2<<<256, 256, 0, stream>>>(src, dst, P, bb, ebuf);
  k_bsort2  <<<256, 512, 0, stream>>>(ebuf, bb, x, flag, adj, offs, deg, dinv, Bs16);

  // ---- layer 1 ----
  k_aggp2<32>  <<<N_NODES/64, 256, 0, stream>>>(Bs16, adj, offs, deg, dinv, A16);
  k_wcomb<32>  <<<3*32+3, 64, 0, stream>>>(g1w, g1b, t1w, flag, Wtb, braw);
  k_tconv3<32> <<<1024, 256, 0, stream>>>(A16, Wtb, braw, t1b, flag, C);
  hipMemsetAsync(stats, 0, sizeof(float)*128, stream);
  k_stats      <<<512, 256, 0, stream>>>(C, stats);
  k_bnfuse     <<<2048, 256, 0, stream>>>(C, stats, bn1g, bn1b, o1w, o1b, flag, dinv, D16);

  // ---- layer 2 ----
  k_aggp2<64>  <<<N_NODES/32, 256, 0, stream>>>(D16, adj, offs, deg, dinv, E16);
  k_wcomb<64>  <<<3*64+3, 64, 0, stream>>>(g2w, g2b, t2w, flag, Wtb, braw);
  k_tconv3<64> <<<1024, 256, 0, stream>>>(E16, Wtb, braw, t2b, flag, C);
  hipMemsetAsync(stats, 0, sizeof(float)*128, stream);
  k_stats      <<<512, 256, 0, stream>>>(C, stats);
  k_bnfuse     <<<2048, 256, 0, stream>>>(C, stats, bn2g, bn2b, o2w, o2b, flag, (const float*)nullptr, F16);

  // ---- regression + mean ----
  k_final<<<1024, 256, 0, stream>>>(F16, rw, rb, flag, d_out);
}

// Round 12
// 336.936 us; speedup vs baseline: 1.8511x; 1.0922x over previous
//
#include <hip/hip_runtime.h>
#include <stdint.h>

typedef unsigned short u16;
typedef __attribute__((ext_vector_type(8))) short bf16x8;
typedef __attribute__((ext_vector_type(4))) float f32x4;

static const int N_NODES = 131072;   // B*T*NN = 128*128*8
static const int N_EDGES = 1048576;

__device__ __forceinline__ float u2f(u16 u){
  union{uint32_t i; float f;} w; w.i = ((uint32_t)u)<<16; return w.f;
}
__device__ __forceinline__ u16 f2u(float f){
  union{float f; uint32_t u;} v; v.f=f;
  uint32_t u=v.u;
  u += 0x7fff + ((u>>16)&1);   // round-to-nearest-even
  return (u16)(u>>16);
}
__device__ __forceinline__ float bits2f(uint32_t b){
  union{uint32_t i; float f;} w; w.i = b; return w.f;
}
__device__ __forceinline__ float ldv(const float* p, int i){ return p[i]; }
__device__ __forceinline__ float ldv(const u16* p, int i){ return u2f(p[i]); }
__device__ __forceinline__ void stv(float* p, int i, float v){ p[i]=v; }
__device__ __forceinline__ void stv(u16* p, int i, float v){ p[i]=f2u(v); }
__device__ __forceinline__ float4 ld4(const float* p, int i){ return *(const float4*)(p+i); }
__device__ __forceinline__ float4 ld4(const u16* p, int i){
  ushort4 u = *(const ushort4*)(p+i);
  return make_float4(u2f(u.x), u2f(u.y), u2f(u.z), u2f(u.w));
}
__device__ __forceinline__ float ldmix(const void* p, int i, int isbf){
  return isbf ? u2f(((const u16*)p)[i]) : ((const float*)p)[i];
}
__device__ __forceinline__ float4 ld4mix(const void* p, int i, int isbf){
  if (isbf){ return ld4((const u16*)p, i); }
  return ld4((const float*)p, i);
}

// ---------------- dtype detection ----------------
__global__ void k_detect(const uint32_t* __restrict__ x, int* __restrict__ flag){
  if (threadIdx.x==0 && blockIdx.x==0){
    int cnt=0;
    for (int i=0;i<256;i++){
      uint32_t e=(x[i]>>7)&0xFFu;
      if (e>=0x6Fu && e<=0x85u) cnt++;
    }
    *flag = (cnt>=128) ? 1 : 0;
  }
}

// ---------------- graph prep: two-pass counting sort, NO global atomics ----------------
__global__ __launch_bounds__(256) void k_hist(const int* __restrict__ dst, int* __restrict__ H){
  __shared__ int h[256];
  int tid = threadIdx.x;
  h[tid] = 0;
  __syncthreads();
  int base = blockIdx.x*4096;
  #pragma unroll
  for (int i=0;i<16;i++){
    int e = base + i*256 + tid;
    atomicAdd(&h[(dst[e] & (N_NODES-1))>>9], 1);
  }
  __syncthreads();
  H[blockIdx.x*256 + tid] = h[tid];
}

__global__ __launch_bounds__(256) void k_colscan(const int* __restrict__ H, int* __restrict__ P,
                                                 int* __restrict__ bt){
  __shared__ int sc[256];
  int b = blockIdx.x, tid = threadIdx.x;
  int v = H[tid*256 + b];
  sc[tid] = v; __syncthreads();
  for (int d=1; d<256; d<<=1){
    int o = (tid>=d) ? sc[tid-d] : 0; __syncthreads();
    sc[tid] += o; __syncthreads();
  }
  P[tid*256 + b] = sc[tid] - v;
  if (tid==255) bt[b] = sc[255];
}

__global__ __launch_bounds__(256) void k_bbscan(const int* __restrict__ bt, int* __restrict__ bb){
  __shared__ int sc[256];
  int t = threadIdx.x;
  int v = bt[t]; sc[t]=v; __syncthreads();
  for (int d=1; d<256; d<<=1){
    int o = (t>=d) ? sc[t-d] : 0; __syncthreads();
    sc[t] += o; __syncthreads();
  }
  bb[t] = sc[t]-v;
  if (t==255) bb[256] = sc[t];
}

__global__ __launch_bounds__(256) void k_scatter2(const int* __restrict__ src, const int* __restrict__ dst,
                                                  const int* __restrict__ P, const int* __restrict__ bb,
                                                  uint32_t* __restrict__ ebuf){
  __shared__ int cu[256];
  int tid = threadIdx.x;
  cu[tid] = bb[tid] + P[blockIdx.x*256 + tid];
  __syncthreads();
  int base = blockIdx.x*4096;
  #pragma unroll
  for (int i=0;i<16;i++){
    int e = base + i*256 + tid;
    int s = src[e] & (N_NODES-1);
    int d = dst[e] & (N_NODES-1);
    int pos = atomicAdd(&cu[d>>9], 1);           // LDS atomic only
    ebuf[pos] = (uint32_t)s | ((uint32_t)(d & 511) << 17);
  }
}

// per-bucket counting sort + emit offs/deg/dinv + fused dinv-prescale of x -> bf16 (F=32)
__global__ __launch_bounds__(512) void k_bsort2(const uint32_t* __restrict__ ebuf, const int* __restrict__ bb,
                                                const void* __restrict__ x, const int* __restrict__ flag,
                                                int* __restrict__ adj, int* __restrict__ offs,
                                                int* __restrict__ deg, float* __restrict__ dinv,
                                                u16* __restrict__ Bout){
  __shared__ uint32_t ein[5120], outs[5120];
  __shared__ int hist[512], sc[512], cu[512];
  __shared__ float dv[512];
  int b = blockIdx.x, tid = threadIdx.x;
  int lo = bb[b], hi = bb[b+1];
  int cnt = hi - lo; if (cnt > 5120) cnt = 5120; if (cnt < 0) cnt = 0;
  hist[tid] = 0;
  __syncthreads();
  for (int i=tid; i<cnt; i+=512){
    uint32_t p = ebuf[lo+i];
    ein[i] = p;
    atomicAdd(&hist[(p>>17)&511], 1);
  }
  __syncthreads();
  sc[tid] = hist[tid];
  __syncthreads();
  for (int d=1; d<512; d<<=1){
    int v = (tid>=d) ? sc[tid-d] : 0;
    __syncthreads();
    sc[tid] += v;
    __syncthreads();
  }
  {
    int ex = sc[tid] - hist[tid];
    int node = b*512 + tid;
    offs[node] = lo + ex;
    deg[node]  = hist[tid];
    float rs = rsqrtf((float)hist[tid] + 1.0f);
    dinv[node] = rs;
    dv[tid] = rs;
    cu[tid] = ex;
  }
  __syncthreads();
  for (int i=tid; i<cnt; i+=512){
    uint32_t p = ein[i];
    int pos = atomicAdd(&cu[(p>>17)&511], 1);
    outs[pos] = p & 0x1FFFFu;
  }
  __syncthreads();
  for (int i=tid; i<cnt; i+=512) adj[lo+i] = (int)outs[i];
  int isbf = *flag;
  for (int u=tid; u<16384; u+=512){
    int nl = u>>5, c = u&31;
    int idx = ((b<<9) + nl)*32 + c;
    stv(Bout, idx, dv[nl]*ldmix(x, idx, isbf));
  }
}

// ---- GCN aggregation, chunked multi-node-per-wave gather ----
__device__ __forceinline__ void acc16(uint4 a, float* acc){
  acc[0] += bits2f(a.x<<16); acc[1] += bits2f(a.x&0xFFFF0000u);
  acc[2] += bits2f(a.y<<16); acc[3] += bits2f(a.y&0xFFFF0000u);
  acc[4] += bits2f(a.z<<16); acc[5] += bits2f(a.z&0xFFFF0000u);
  acc[6] += bits2f(a.w<<16); acc[7] += bits2f(a.w&0xFFFF0000u);
}
template<int F>
__global__ __launch_bounds__(256) void k_aggp2(const u16* __restrict__ Xs,
                                               const int* __restrict__ adj, const int* __restrict__ offs,
                                               const int* __restrict__ deg, const float* __restrict__ dinv,
                                               u16* __restrict__ out){
  constexpr int CH  = F/8;            // 16B chunks per row
  constexpr int GPW = 64/CH;          // nodes per wave
  int tid = threadIdx.x;
  int wv = tid>>6, lane = tid&63;
  int g = lane / CH;
  int k = lane % CH;
  int n = blockIdx.x*(4*GPW) + wv*GPW + g;
  int o = offs[n] & (N_EDGES-1);
  int cnt = min(deg[n], 8192);
  const uint4* X4 = (const uint4*)Xs;
  uint4 sv = X4[(size_t)n*CH + k];
  float acc[8] = {0,0,0,0,0,0,0,0};
  acc16(sv, acc);
  int e = 0;
  for (; e+4 <= cnt; e += 4){
    int i0 = adj[o+e+0] & (N_NODES-1);
    int i1 = adj[o+e+1] & (N_NODES-1);
    int i2 = adj[o+e+2] & (N_NODES-1);
    int i3 = adj[o+e+3] & (N_NODES-1);
    uint4 a0 = X4[(size_t)i0*CH + k];
    uint4 a1 = X4[(size_t)i1*CH + k];
    uint4 a2 = X4[(size_t)i2*CH + k];
    uint4 a3 = X4[(size_t)i3*CH + k];
    acc16(a0, acc); acc16(a1, acc); acc16(a2, acc); acc16(a3, acc);
  }
  for (; e < cnt; e++){
    int s = adj[o+e] & (N_NODES-1);
    uint4 a = X4[(size_t)s*CH + k];
    acc16(a, acc);
  }
  float dv = dinv[n];
  uint4 r;
  r.x = (uint32_t)f2u(acc[0]*dv) | ((uint32_t)f2u(acc[1]*dv) << 16);
  r.y = (uint32_t)f2u(acc[2]*dv) | ((uint32_t)f2u(acc[3]*dv) << 16);
  r.z = (uint32_t)f2u(acc[4]*dv) | ((uint32_t)f2u(acc[5]*dv) << 16);
  r.w = (uint32_t)f2u(acc[6]*dv) | ((uint32_t)f2u(acc[7]*dv) << 16);
  ((uint4*)out)[(size_t)n*CH + k] = r;
}

// ---- combine GCN weight with temporal-conv weight; write bf16 TRANSPOSED  ----
template<int Kin>
__global__ __launch_bounds__(64) void k_wcomb(const void* __restrict__ gW, const void* __restrict__ gb,
                                              const void* __restrict__ tw, const int* __restrict__ flag,
                                              u16* __restrict__ Wtb, float* __restrict__ braw){
  int isbf = *flag;
  int r = blockIdx.x;
  int co = threadIdx.x;
  if (r < 3*Kin){
    int k = r / Kin, j = r % Kin;
    float acc = 0.f;
    for (int c=0; c<64; c++)
      acc += ldmix(gW, j*64+c, isbf) * ldmix(tw, co*192 + c*3 + k, isbf);
    Wtb[co*(3*Kin) + r] = f2u(acc);
  } else {
    int k = r - 3*Kin;
    float acc = 0.f;
    for (int c=0; c<64; c++)
      acc += ldmix(gb, c, isbf) * ldmix(tw, co*192 + c*3 + k, isbf);
    braw[k*64 + co] = acc;
  }
}

// ---- fused linear+temporal-conv via bf16 MFMA; input bf16, output fp32 ----
template<int Kin>
__global__ __launch_bounds__(256) void k_tconv3(const u16* __restrict__ A, const u16* __restrict__ Wtb,
                                                const float* __restrict__ braw, const void* __restrict__ tb,
                                                const int* __restrict__ flag, float* __restrict__ out){
  constexpr int K  = 3*Kin;
  constexpr int SA = Kin + 8;
  constexpr int SW = K + 8;
  constexpr int JH = Kin/2;
  constexpr int JL = (Kin==64) ? 5 : 4;
  __shared__ alignas(16) u16 At[130*SA];
  __shared__ alignas(16) u16 Wl[64*SW];
  __shared__ float ball[64], bs0[64], bs2[64];

  int isbf = *flag;
  int bid = blockIdx.x;
  int b = bid>>3, v = bid&7;
  const int tid = threadIdx.x;

  if (tid < 64){
    float b0=braw[tid], b1=braw[64+tid], b2=braw[128+tid];
    ball[tid] = ldmix(tb, tid, isbf) + b0 + b1 + b2;
    bs0[tid] = b0; bs2[tid] = b2;
  }
  {
    const uint32_t* Wg = (const uint32_t*)Wtb;
    uint32_t* Wd = (uint32_t*)Wl;
    for (int u=tid; u<64*(K/2); u+=256){
      int co = u/(K/2), jd = u - co*(K/2);
      Wd[co*(SW/2) + jd] = Wg[u];
    }
  }
  {
    uint32_t* Ad = (uint32_t*)At;
    const uint32_t* Ag = (const uint32_t*)A;
    for (int u=tid; u<130*JH; u+=256){
      int t1 = u >> JL, jd = u & (JH-1);
      int t = t1 - 1;
      uint32_t pack = 0;
      if (t >= 0 && t < 128)
        pack = Ag[((((b*128+t)*8+v))*Kin >> 1) + jd];
      Ad[t1*(SA/2) + jd] = pack;
    }
  }
  __syncthreads();

  int wv_ = tid >> 6, lane = tid & 63;
  int q = lane >> 4, l16 = lane & 15;
  int tb0 = wv_ * 32;

  f32x4 acc[2][4];
  #pragma unroll
  for (int mt=0; mt<2; mt++)
    #pragma unroll
    for (int nt=0; nt<4; nt++)
      acc[mt][nt] = (f32x4){0.f,0.f,0.f,0.f};

  #pragma unroll
  for (int s=0; s<K/32; s++){
    int kk = (32*s)/Kin;
    int j0 = 32*s - kk*Kin;
    int col = j0 + q*8;
    bf16x8 afr[2], bfr[4];
    #pragma unroll
    for (int mt=0; mt<2; mt++){
      int row = tb0 + mt*16 + l16 + kk;
      afr[mt] = *(const bf16x8*)&At[row*SA + col];
    }
    #pragma unroll
    for (int nt=0; nt<4; nt++){
      int co = nt*16 + l16;
      bfr[nt] = *(const bf16x8*)&Wl[co*SW + 32*s + q*8];
    }
    #pragma unroll
    for (int mt=0; mt<2; mt++)
      #pragma unroll
      for (int nt=0; nt<4; nt++)
        acc[mt][nt] = __builtin_amdgcn_mfma_f32_16x16x32_bf16(afr[mt], bfr[nt], acc[mt][nt], 0, 0, 0);
  }

  #pragma unroll
  for (int mt=0; mt<2; mt++){
    #pragma unroll
    for (int r=0; r<4; r++){
      int t = tb0 + mt*16 + q*4 + r;
      int base = (((b*128+t)*8+v)) << 6;
      #pragma unroll
      for (int nt=0; nt<4; nt++){
        int co = nt*16 + l16;
        float val = acc[mt][nt][r] + ball[co];
        if (t == 0)   val -= bs0[co];
        if (t == 127) val -= bs2[co];
        out[base + co] = val;
      }
    }
  }
}

// ---- BN stats: per-channel sum / sumsq (float4, fp32 input) ----
__global__ __launch_bounds__(256) void k_stats(const float* __restrict__ X, float* __restrict__ stats){
  int cq = (threadIdx.x & 15) << 2;
  int g  = threadIdx.x >> 4;
  float4 s  = make_float4(0.f,0.f,0.f,0.f);
  float4 s2 = make_float4(0.f,0.f,0.f,0.f);
  for (int row = blockIdx.x*16 + g; row < N_NODES; row += gridDim.x*16){
    float4 v = ld4(X, (row<<6) + cq);
    s.x += v.x; s.y += v.y; s.z += v.z; s.w += v.w;
    s2.x += v.x*v.x; s2.y += v.y*v.y; s2.z += v.z*v.z; s2.w += v.w*v.w;
  }
  __shared__ float sh[16][64], sh2[16][64];
  *(float4*)&sh[g][cq]  = s;
  *(float4*)&sh2[g][cq] = s2;
  __syncthreads();
  if (threadIdx.x < 64){
    int co = threadIdx.x;
    float a = 0.f, a2 = 0.f;
    #pragma unroll
    for (int gg=0; gg<16; gg++){ a += sh[gg][co]; a2 += sh2[gg][co]; }
    atomicAdd(&stats[co], a);
    atomicAdd(&stats[64+co], a2);
  }
}

// ---- BN-apply + ReLU + 1x1 conv via bf16 MFMA + tanh (+ presc) + scrambled bf16 write ----
// block = (b,v): 128t x 64co tile.  Yl bf16 [128][72]; Wl bf16 [64][72] (= B^T layout).
__global__ __launch_bounds__(256) void k_bnfuse3(const float* __restrict__ X, const float* __restrict__ stats,
                                                 const void* __restrict__ gam, const void* __restrict__ bet,
                                                 const void* __restrict__ ow, const void* __restrict__ ob,
                                                 const int* __restrict__ flag, const float* __restrict__ presc,
                                                 u16* __restrict__ out){
  constexpr int SA = 72;
  __shared__ alignas(16) u16 Yl[128*SA];       // also reused as Zl in epilogue
  __shared__ alignas(16) u16 Wl[64*SA];
  __shared__ float kk[64], bsh[64], obs[64];
  int isbf = *flag;
  int bid = blockIdx.x;
  int b = bid>>3, v = bid&7;
  const int tid = threadIdx.x;
  const float invM = 1.0f/131072.0f;

  if (tid < 64){
    int ci = tid;
    float mu = stats[ci]*invM;
    float var = stats[64+ci]*invM - mu*mu;
    float rs = rsqrtf(fmaxf(var, 0.f) + 1e-5f);
    float kv = rs*ldmix(gam, ci, isbf);
    kk[ci] = kv;
    bsh[ci] = ldmix(bet, ci, isbf) - mu*kv;
    obs[ci] = ldmix(ob, ci, isbf);
  }
  // stage Wl[co][ci] = bf16(ow[co][ci])
  {
    uint32_t* Wd = (uint32_t*)Wl;
    for (int u=tid; u<64*32; u+=256){
      int co = u>>5, jd = u&31;
      float w0 = ldmix(ow, (co<<6) + (jd<<1), isbf);
      float w1 = ldmix(ow, (co<<6) + (jd<<1) + 1, isbf);
      Wd[co*(SA/2) + jd] = (uint32_t)f2u(w0) | ((uint32_t)f2u(w1) << 16);
    }
  }
  __syncthreads();
  // stage Yl[t][ci] = bf16(relu(X*kk + bsh))
  {
    uint32_t* Yd = (uint32_t*)Yl;
    for (int u=tid; u<128*32; u+=256){
      int t = u>>5, jd = u&31;
      int ci = jd<<1;
      int base = (((b*128+t)*8+v)) << 6;
      float y0 = fmaxf(X[base+ci]*kk[ci] + bsh[ci], 0.f);
      float y1 = fmaxf(X[base+ci+1]*kk[ci+1] + bsh[ci+1], 0.f);
      Yd[t*(SA/2) + jd] = (uint32_t)f2u(y0) | ((uint32_t)f2u(y1) << 16);
    }
  }
  __syncthreads();

  int wv_ = tid >> 6, lane = tid & 63;
  int q = lane >> 4, l16 = lane & 15;
  int tb0 = wv_ * 32;

  f32x4 acc[2][4];
  #pragma unroll
  for (int mt=0; mt<2; mt++)
    #pragma unroll
    for (int nt=0; nt<4; nt++)
      acc[mt][nt] = (f32x4){0.f,0.f,0.f,0.f};

  #pragma unroll
  for (int s=0; s<2; s++){
    int col = 32*s + q*8;
    bf16x8 afr[2], bfr[4];
    #pragma unroll
    for (int mt=0; mt<2; mt++){
      int row = tb0 + mt*16 + l16;
      afr[mt] = *(const bf16x8*)&Yl[row*SA + col];
    }
    #pragma unroll
    for (int nt=0; nt<4; nt++){
      int co = nt*16 + l16;
      bfr[nt] = *(const bf16x8*)&Wl[co*SA + col];
    }
    #pragma unroll
    for (int mt=0; mt<2; mt++)
      #pragma unroll
      for (int nt=0; nt<4; nt++)
        acc[mt][nt] = __builtin_amdgcn_mfma_f32_16x16x32_bf16(afr[mt], bfr[nt], acc[mt][nt], 0, 0, 0);
  }

  __syncthreads();   // all MFMA reads of Yl done; reuse as Zl
  #pragma unroll
  for (int mt=0; mt<2; mt++){
    #pragma unroll
    for (int r=0; r<4; r++){
      int t = tb0 + mt*16 + q*4 + r;
      #pragma unroll
      for (int nt=0; nt<4; nt++){
        int co = nt*16 + l16;
        Yl[t*SA + co] = f2u(acc[mt][nt][r] + obs[co]);
      }
    }
  }
  __syncthreads();
  // transpose-write epilogue: coalesced 128B global stores
  for (int u=tid; u<8192; u+=256){
    int l = u & 63;                 // t within 64-half, = lane
    int idx = u >> 6;               // 0..127
    int co = idx >> 1, thi = idx & 1;
    int t = (thi<<6) + l;
    float z = tanhf(u2f(Yl[t*SA + co]));
    int r = (b<<10) + (co<<4) + (v<<1) + thi;
    if (presc) z *= presc[r];       // lane-uniform
    out[(r<<6) + l] = f2u(z);
  }
}

// ---- final: out[b,v] = mean_{t,f}( x3 @ reg_w + reg_b ), bf16 input ----
__global__ __launch_bounds__(256) void k_final(const u16* __restrict__ X, const void* __restrict__ rw,
                                               const void* __restrict__ rb, const int* __restrict__ flag,
                                               void* __restrict__ out){
  __shared__ float rw_s[64];
  __shared__ float rbs_s;
  __shared__ float wred[4];
  int isbf = *flag;
  int bid = blockIdx.x;
  int b = bid>>3, v = bid&7;
  if (threadIdx.x < 64){
    float s = 0.f;
    #pragma unroll
    for (int f=0; f<8; f++) s += ldmix(rw, threadIdx.x*8 + f, isbf);
    rw_s[threadIdx.x] = s;
  }
  if (threadIdx.x == 0){
    float s = 0.f;
    for (int f=0; f<8; f++) s += ldmix(rb, f, isbf);
    rbs_s = s;
  }
  __syncthreads();
  float acc = 0.f;
  for (int i=threadIdx.x; i<128*64; i+=256){
    int t = i>>6, j = i&63;
    acc += ldv(X, (((b*128+t)*8+v)<<6) + j) * rw_s[j];
  }
  for (int off=32; off; off>>=1) acc += __shfl_down(acc, off);
  if ((threadIdx.x & 63) == 0) wred[threadIdx.x>>6] = acc;
  __syncthreads();
  if (threadIdx.x == 0){
    float r = wred[0]+wred[1]+wred[2]+wred[3];
    float val = r*(1.0f/1024.0f) + rbs_s*0.125f;
    if (isbf) ((u16*)out)[bid] = f2u(val);
    else      ((float*)out)[bid] = val;
  }
}

extern "C" void kernel_launch(void* const* d_in, const int* in_sizes, int n_in,
                              void* d_out, int out_size, void* d_ws, size_t ws_size,
                              hipStream_t stream){
  (void)in_sizes; (void)n_in; (void)out_size; (void)ws_size;
  char* p = (char*)d_ws;
  auto alloc = [&](size_t bytes){ void* r = (void*)p; p += (bytes + 255) & ~(size_t)255; return r; };
  u16*   U1   = (u16*)  alloc(sizeof(u16)*(size_t)N_NODES*64);  // Bs16 | A16 ; later D16
  u16*   U2   = (u16*)  alloc(sizeof(u16)*(size_t)N_NODES*64);  // E16 ; later F16
  float* C    = (float*)alloc(sizeof(float)*(size_t)N_NODES*64);// tconv out (fp32)
  int*   deg  = (int*)  alloc(sizeof(int)*N_NODES);
  float* dinv = (float*)alloc(sizeof(float)*N_NODES);
  int*   offs = (int*)  alloc(sizeof(int)*N_NODES);
  int*   adj  = (int*)  alloc(sizeof(int)*N_EDGES);
  int*   H    = (int*)  alloc(sizeof(int)*256*256);
  int*   P    = (int*)  alloc(sizeof(int)*256*256);
  int*   bt   = (int*)  alloc(sizeof(int)*256);
  int*   bb   = (int*)  alloc(sizeof(int)*260);
  float* stats= (float*)alloc(sizeof(float)*128);
  int*   flag = (int*)  alloc(sizeof(int)*64);
  u16*   Wtb  = (u16*)  alloc(sizeof(u16)*192*64);
  float* braw = (float*)alloc(sizeof(float)*192);
  uint32_t* ebuf = (uint32_t*)C;             // alias: C dead until tconv1
  u16* Bs16 = U1;                            // N x 32 bf16 (prescaled x)
  u16* A16  = U1 + (size_t)N_NODES*32;       // N x 32 bf16 (agg1 out)
  u16* D16  = U1;                            // N x 64 bf16 (bnfuse1 out, prescaled)
  u16* E16  = U2;                            // N x 64 bf16 (agg2 out)
  u16* F16  = U2;                            // N x 64 bf16 (bnfuse2 out)

  const void* x   = d_in[0];
  const int* edge = (const int*)d_in[1];
  const void* g1w = d_in[2];  const void* g1b = d_in[3];
  const void* t1w = d_in[4];  const void* t1b = d_in[5];
  const void* bn1g= d_in[6];  const void* bn1b= d_in[7];
  const void* o1w = d_in[8];  const void* o1b = d_in[9];
  const void* g2w = d_in[10]; const void* g2b = d_in[11];
  const void* t2w = d_in[12]; const void* t2b = d_in[13];
  const void* bn2g= d_in[14]; const void* bn2b= d_in[15];
  const void* o2w = d_in[16]; const void* o2b = d_in[17];
  const void* rw  = d_in[18]; const void* rb  = d_in[19];
  const int* src = edge;
  const int* dst = edge + N_EDGES;

  k_detect<<<1, 64, 0, stream>>>((const uint32_t*)x, flag);

  // graph prep: two-pass counting sort, zero global atomics
  k_hist    <<<256, 256, 0, stream>>>(dst, H);
  k_colscan <<<256, 256, 0, stream>>>(H, P, bt);
  k_bbscan  <<<1, 256, 0, stream>>>(bt, bb);
  k_scatter2<<<256, 256, 0, stream>>>(src, dst, P, bb, ebuf);
  k_bsort2  <<<256, 512, 0, stream>>>(ebuf, bb, x, flag, adj, offs, deg, dinv, Bs16);

  // ---- layer 1 ----
  k_aggp2<32>  <<<N_NODES/64, 256, 0, stream>>>(Bs16, adj, offs, deg, dinv, A16);
  k_wcomb<32>  <<<3*32+3, 64, 0, stream>>>(g1w, g1b, t1w, flag, Wtb, braw);
  k_tconv3<32> <<<1024, 256, 0, stream>>>(A16, Wtb, braw, t1b, flag, C);
  hipMemsetAsync(stats, 0, sizeof(float)*128, stream);
  k_stats      <<<512, 256, 0, stream>>>(C, stats);
  k_bnfuse3    <<<1024, 256, 0, stream>>>(C, stats, bn1g, bn1b, o1w, o1b, flag, dinv, D16);

  // ---- layer 2 ----
  k_aggp2<64>  <<<N_NODES/32, 256, 0, stream>>>(D16, adj, offs, deg, dinv, E16);
  k_wcomb<64>  <<<3*64+3, 64, 0, stream>>>(g2w, g2b, t2w, flag, Wtb, braw);
  k_tconv3<64> <<<1024, 256, 0, stream>>>(E16, Wtb, braw, t2b, flag, C);
  hipMemsetAsync(stats, 0, sizeof(float)*128, stream);
  k_stats      <<<512, 256, 0, stream>>>(C, stats);
  k_bnfuse3    <<<1024, 256, 0, stream>>>(C, stats, bn2g, bn2b, o2w, o2b, flag, (const float*)nullptr, F16);

  // ---- regression + mean ----
  k_final<<<1024, 256, 0, stream>>>(F16, rw, rb, flag, d_out);
}

// Round 13
// 335.590 us; speedup vs baseline: 1.8585x; 1.0040x over previous
//
#include <hip/hip_runtime.h>
#include <stdint.h>

typedef unsigned short u16;
typedef __attribute__((ext_vector_type(8))) short bf16x8;
typedef __attribute__((ext_vector_type(4))) float f32x4;

static const int N_NODES = 131072;   // B*T*NN = 128*128*8
static const int N_EDGES = 1048576;

__device__ __forceinline__ float u2f(u16 u){
  union{uint32_t i; float f;} w; w.i = ((uint32_t)u)<<16; return w.f;
}
__device__ __forceinline__ u16 f2u(float f){
  union{float f; uint32_t u;} v; v.f=f;
  uint32_t u=v.u;
  u += 0x7fff + ((u>>16)&1);   // round-to-nearest-even
  return (u16)(u>>16);
}
__device__ __forceinline__ float bits2f(uint32_t b){
  union{uint32_t i; float f;} w; w.i = b; return w.f;
}
__device__ __forceinline__ float ldv(const float* p, int i){ return p[i]; }
__device__ __forceinline__ float ldv(const u16* p, int i){ return u2f(p[i]); }
__device__ __forceinline__ void stv(float* p, int i, float v){ p[i]=v; }
__device__ __forceinline__ void stv(u16* p, int i, float v){ p[i]=f2u(v); }
__device__ __forceinline__ float4 ld4(const float* p, int i){ return *(const float4*)(p+i); }
__device__ __forceinline__ float4 ld4(const u16* p, int i){
  ushort4 u = *(const ushort4*)(p+i);
  return make_float4(u2f(u.x), u2f(u.y), u2f(u.z), u2f(u.w));
}
__device__ __forceinline__ float ldmix(const void* p, int i, int isbf){
  return isbf ? u2f(((const u16*)p)[i]) : ((const float*)p)[i];
}
__device__ __forceinline__ float4 ld4mix(const void* p, int i, int isbf){
  if (isbf){ return ld4((const u16*)p, i); }
  return ld4((const float*)p, i);
}

// ---------------- dtype detection ----------------
__global__ void k_detect(const uint32_t* __restrict__ x, int* __restrict__ flag){
  if (threadIdx.x==0 && blockIdx.x==0){
    int cnt=0;
    for (int i=0;i<256;i++){
      uint32_t e=(x[i]>>7)&0xFFu;
      if (e>=0x6Fu && e<=0x85u) cnt++;
    }
    *flag = (cnt>=128) ? 1 : 0;
  }
}

// ---------------- graph prep: two-pass counting sort, NO global atomics ----------------
__global__ __launch_bounds__(256) void k_hist(const int* __restrict__ dst, int* __restrict__ H){
  __shared__ int h[256];
  int tid = threadIdx.x;
  h[tid] = 0;
  __syncthreads();
  int base = blockIdx.x*4096;
  #pragma unroll
  for (int i=0;i<16;i++){
    int e = base + i*256 + tid;
    atomicAdd(&h[(dst[e] & (N_NODES-1))>>9], 1);
  }
  __syncthreads();
  H[blockIdx.x*256 + tid] = h[tid];
}

__global__ __launch_bounds__(256) void k_colscan(const int* __restrict__ H, int* __restrict__ P,
                                                 int* __restrict__ bt){
  __shared__ int sc[256];
  int b = blockIdx.x, tid = threadIdx.x;
  int v = H[tid*256 + b];
  sc[tid] = v; __syncthreads();
  for (int d=1; d<256; d<<=1){
    int o = (tid>=d) ? sc[tid-d] : 0; __syncthreads();
    sc[tid] += o; __syncthreads();
  }
  P[tid*256 + b] = sc[tid] - v;
  if (tid==255) bt[b] = sc[255];
}

__global__ __launch_bounds__(256) void k_bbscan(const int* __restrict__ bt, int* __restrict__ bb){
  __shared__ int sc[256];
  int t = threadIdx.x;
  int v = bt[t]; sc[t]=v; __syncthreads();
  for (int d=1; d<256; d<<=1){
    int o = (t>=d) ? sc[t-d] : 0; __syncthreads();
    sc[t] += o; __syncthreads();
  }
  bb[t] = sc[t]-v;
  if (t==255) bb[256] = sc[t];
}

__global__ __launch_bounds__(256) void k_scatter2(const int* __restrict__ src, const int* __restrict__ dst,
                                                  const int* __restrict__ P, const int* __restrict__ bb,
                                                  uint32_t* __restrict__ ebuf){
  __shared__ int cu[256];
  int tid = threadIdx.x;
  cu[tid] = bb[tid] + P[blockIdx.x*256 + tid];
  __syncthreads();
  int base = blockIdx.x*4096;
  #pragma unroll
  for (int i=0;i<16;i++){
    int e = base + i*256 + tid;
    int s = src[e] & (N_NODES-1);
    int d = dst[e] & (N_NODES-1);
    int pos = atomicAdd(&cu[d>>9], 1);           // LDS atomic only
    ebuf[pos] = (uint32_t)s | ((uint32_t)(d & 511) << 17);
  }
}

// per-bucket counting sort + emit offs/deg/dinv + fused dinv-prescale of x -> bf16 (F=32)
__global__ __launch_bounds__(512) void k_bsort2(const uint32_t* __restrict__ ebuf, const int* __restrict__ bb,
                                                const void* __restrict__ x, const int* __restrict__ flag,
                                                int* __restrict__ adj, int* __restrict__ offs,
                                                int* __restrict__ deg, float* __restrict__ dinv,
                                                u16* __restrict__ Bout){
  __shared__ uint32_t ein[5120], outs[5120];
  __shared__ int hist[512], sc[512], cu[512];
  __shared__ float dv[512];
  int b = blockIdx.x, tid = threadIdx.x;
  int lo = bb[b], hi = bb[b+1];
  int cnt = hi - lo; if (cnt > 5120) cnt = 5120; if (cnt < 0) cnt = 0;
  hist[tid] = 0;
  __syncthreads();
  for (int i=tid; i<cnt; i+=512){
    uint32_t p = ebuf[lo+i];
    ein[i] = p;
    atomicAdd(&hist[(p>>17)&511], 1);
  }
  __syncthreads();
  sc[tid] = hist[tid];
  __syncthreads();
  for (int d=1; d<512; d<<=1){
    int v = (tid>=d) ? sc[tid-d] : 0;
    __syncthreads();
    sc[tid] += v;
    __syncthreads();
  }
  {
    int ex = sc[tid] - hist[tid];
    int node = b*512 + tid;
    offs[node] = lo + ex;
    deg[node]  = hist[tid];
    float rs = rsqrtf((float)hist[tid] + 1.0f);
    dinv[node] = rs;
    dv[tid] = rs;
    cu[tid] = ex;
  }
  __syncthreads();
  for (int i=tid; i<cnt; i+=512){
    uint32_t p = ein[i];
    int pos = atomicAdd(&cu[(p>>17)&511], 1);
    outs[pos] = p & 0x1FFFFu;
  }
  __syncthreads();
  for (int i=tid; i<cnt; i+=512) adj[lo+i] = (int)outs[i];
  int isbf = *flag;
  for (int u=tid; u<16384; u+=512){
    int nl = u>>5, c = u&31;
    int idx = ((b<<9) + nl)*32 + c;
    stv(Bout, idx, dv[nl]*ldmix(x, idx, isbf));
  }
}

// ---- GCN aggregation, chunked multi-node-per-wave gather ----
__device__ __forceinline__ void acc16(uint4 a, float* acc){
  acc[0] += bits2f(a.x<<16); acc[1] += bits2f(a.x&0xFFFF0000u);
  acc[2] += bits2f(a.y<<16); acc[3] += bits2f(a.y&0xFFFF0000u);
  acc[4] += bits2f(a.z<<16); acc[5] += bits2f(a.z&0xFFFF0000u);
  acc[6] += bits2f(a.w<<16); acc[7] += bits2f(a.w&0xFFFF0000u);
}
template<int F>
__global__ __launch_bounds__(256) void k_aggp2(const u16* __restrict__ Xs,
                                               const int* __restrict__ adj, const int* __restrict__ offs,
                                               const int* __restrict__ deg, const float* __restrict__ dinv,
                                               u16* __restrict__ out){
  constexpr int CH  = F/8;            // 16B chunks per row
  constexpr int GPW = 64/CH;          // nodes per wave
  int tid = threadIdx.x;
  int wv = tid>>6, lane = tid&63;
  int g = lane / CH;
  int k = lane % CH;
  int n = blockIdx.x*(4*GPW) + wv*GPW + g;
  int o = offs[n] & (N_EDGES-1);
  int cnt = min(deg[n], 8192);
  const uint4* X4 = (const uint4*)Xs;
  uint4 sv = X4[(size_t)n*CH + k];
  float acc[8] = {0,0,0,0,0,0,0,0};
  acc16(sv, acc);
  int e = 0;
  for (; e+4 <= cnt; e += 4){
    int i0 = adj[o+e+0] & (N_NODES-1);
    int i1 = adj[o+e+1] & (N_NODES-1);
    int i2 = adj[o+e+2] & (N_NODES-1);
    int i3 = adj[o+e+3] & (N_NODES-1);
    uint4 a0 = X4[(size_t)i0*CH + k];
    uint4 a1 = X4[(size_t)i1*CH + k];
    uint4 a2 = X4[(size_t)i2*CH + k];
    uint4 a3 = X4[(size_t)i3*CH + k];
    acc16(a0, acc); acc16(a1, acc); acc16(a2, acc); acc16(a3, acc);
  }
  for (; e < cnt; e++){
    int s = adj[o+e] & (N_NODES-1);
    uint4 a = X4[(size_t)s*CH + k];
    acc16(a, acc);
  }
  float dv = dinv[n];
  uint4 r;
  r.x = (uint32_t)f2u(acc[0]*dv) | ((uint32_t)f2u(acc[1]*dv) << 16);
  r.y = (uint32_t)f2u(acc[2]*dv) | ((uint32_t)f2u(acc[3]*dv) << 16);
  r.z = (uint32_t)f2u(acc[4]*dv) | ((uint32_t)f2u(acc[5]*dv) << 16);
  r.w = (uint32_t)f2u(acc[6]*dv) | ((uint32_t)f2u(acc[7]*dv) << 16);
  ((uint4*)out)[(size_t)n*CH + k] = r;
}

// ---- combine GCN weight with temporal-conv weight; write bf16 TRANSPOSED  ----
template<int Kin>
__global__ __launch_bounds__(64) void k_wcomb(const void* __restrict__ gW, const void* __restrict__ gb,
                                              const void* __restrict__ tw, const int* __restrict__ flag,
                                              u16* __restrict__ Wtb, float* __restrict__ braw){
  int isbf = *flag;
  int r = blockIdx.x;
  int co = threadIdx.x;
  if (r < 3*Kin){
    int k = r / Kin, j = r % Kin;
    float acc = 0.f;
    for (int c=0; c<64; c++)
      acc += ldmix(gW, j*64+c, isbf) * ldmix(tw, co*192 + c*3 + k, isbf);
    Wtb[co*(3*Kin) + r] = f2u(acc);
  } else {
    int k = r - 3*Kin;
    float acc = 0.f;
    for (int c=0; c<64; c++)
      acc += ldmix(gb, c, isbf) * ldmix(tw, co*192 + c*3 + k, isbf);
    braw[k*64 + co] = acc;
  }
}

// ---- fused linear+temporal-conv via bf16 MFMA + fused BN-stats; input bf16, output fp32 ----
template<int Kin>
__global__ __launch_bounds__(256) void k_tconv3(const u16* __restrict__ A, const u16* __restrict__ Wtb,
                                                const float* __restrict__ braw, const void* __restrict__ tb,
                                                const int* __restrict__ flag, float* __restrict__ out,
                                                float* __restrict__ stats){
  constexpr int K  = 3*Kin;
  constexpr int SA = Kin + 8;
  constexpr int SW = K + 8;
  constexpr int JH = Kin/2;
  constexpr int JL = (Kin==64) ? 5 : 4;
  __shared__ alignas(16) u16 At[130*SA];
  __shared__ alignas(16) u16 Wl[64*SW];
  __shared__ float ball[64], bs0[64], bs2[64];
  __shared__ float wsum[4][64], wsum2[4][64];

  int isbf = *flag;
  int bid = blockIdx.x;
  int b = bid>>3, v = bid&7;
  const int tid = threadIdx.x;

  if (tid < 64){
    float b0=braw[tid], b1=braw[64+tid], b2=braw[128+tid];
    ball[tid] = ldmix(tb, tid, isbf) + b0 + b1 + b2;
    bs0[tid] = b0; bs2[tid] = b2;
  }
  {
    const uint32_t* Wg = (const uint32_t*)Wtb;
    uint32_t* Wd = (uint32_t*)Wl;
    for (int u=tid; u<64*(K/2); u+=256){
      int co = u/(K/2), jd = u - co*(K/2);
      Wd[co*(SW/2) + jd] = Wg[u];
    }
  }
  {
    uint32_t* Ad = (uint32_t*)At;
    const uint32_t* Ag = (const uint32_t*)A;
    for (int u=tid; u<130*JH; u+=256){
      int t1 = u >> JL, jd = u & (JH-1);
      int t = t1 - 1;
      uint32_t pack = 0;
      if (t >= 0 && t < 128)
        pack = Ag[((((b*128+t)*8+v))*Kin >> 1) + jd];
      Ad[t1*(SA/2) + jd] = pack;
    }
  }
  __syncthreads();

  int wv_ = tid >> 6, lane = tid & 63;
  int q = lane >> 4, l16 = lane & 15;
  int tb0 = wv_ * 32;

  f32x4 acc[2][4];
  #pragma unroll
  for (int mt=0; mt<2; mt++)
    #pragma unroll
    for (int nt=0; nt<4; nt++)
      acc[mt][nt] = (f32x4){0.f,0.f,0.f,0.f};

  #pragma unroll
  for (int s=0; s<K/32; s++){
    int kk = (32*s)/Kin;
    int j0 = 32*s - kk*Kin;
    int col = j0 + q*8;
    bf16x8 afr[2], bfr[4];
    #pragma unroll
    for (int mt=0; mt<2; mt++){
      int row = tb0 + mt*16 + l16 + kk;
      afr[mt] = *(const bf16x8*)&At[row*SA + col];
    }
    #pragma unroll
    for (int nt=0; nt<4; nt++){
      int co = nt*16 + l16;
      bfr[nt] = *(const bf16x8*)&Wl[co*SW + 32*s + q*8];
    }
    #pragma unroll
    for (int mt=0; mt<2; mt++)
      #pragma unroll
      for (int nt=0; nt<4; nt++)
        acc[mt][nt] = __builtin_amdgcn_mfma_f32_16x16x32_bf16(afr[mt], bfr[nt], acc[mt][nt], 0, 0, 0);
  }

  float ls[4] = {0,0,0,0}, ls2[4] = {0,0,0,0};
  #pragma unroll
  for (int mt=0; mt<2; mt++){
    #pragma unroll
    for (int r=0; r<4; r++){
      int t = tb0 + mt*16 + q*4 + r;
      int base = (((b*128+t)*8+v)) << 6;
      #pragma unroll
      for (int nt=0; nt<4; nt++){
        int co = nt*16 + l16;
        float val = acc[mt][nt][r] + ball[co];
        if (t == 0)   val -= bs0[co];
        if (t == 127) val -= bs2[co];
        out[base + co] = val;
        ls[nt] += val; ls2[nt] += val*val;
      }
    }
  }
  // fused BN stats: reduce across quads (same co), then waves, then one atomic per co
  #pragma unroll
  for (int nt=0; nt<4; nt++){
    ls[nt]  += __shfl_xor(ls[nt], 16);  ls[nt]  += __shfl_xor(ls[nt], 32);
    ls2[nt] += __shfl_xor(ls2[nt], 16); ls2[nt] += __shfl_xor(ls2[nt], 32);
  }
  if (q == 0){
    #pragma unroll
    for (int nt=0; nt<4; nt++){
      wsum[wv_][nt*16 + l16]  = ls[nt];
      wsum2[wv_][nt*16 + l16] = ls2[nt];
    }
  }
  __syncthreads();
  if (tid < 64){
    float a = wsum[0][tid]+wsum[1][tid]+wsum[2][tid]+wsum[3][tid];
    float a2 = wsum2[0][tid]+wsum2[1][tid]+wsum2[2][tid]+wsum2[3][tid];
    atomicAdd(&stats[tid], a);
    atomicAdd(&stats[64+tid], a2);
  }
}

// ---- BN-apply + ReLU + 1x1 conv via bf16 MFMA + tanh; FINAL fuses regression+mean ----
template<bool FINAL>
__global__ __launch_bounds__(256) void k_bnfuse3(const float* __restrict__ X, const float* __restrict__ stats,
                                                 const void* __restrict__ gam, const void* __restrict__ bet,
                                                 const void* __restrict__ ow, const void* __restrict__ ob,
                                                 const int* __restrict__ flag, const float* __restrict__ presc,
                                                 u16* __restrict__ out16,
                                                 float* __restrict__ zacc, const void* __restrict__ rw){
  constexpr int SA = 72;
  __shared__ alignas(16) u16 Yl[128*SA];       // reused as Zl in epilogue
  __shared__ alignas(16) u16 Wl[64*SA];
  __shared__ float kk[64], bsh[64], obs[64];
  __shared__ float rw_s[64];
  __shared__ float wred[4];
  int isbf = *flag;
  int bid = blockIdx.x;
  int b = bid>>3, v = bid&7;
  const int tid = threadIdx.x;
  const float invM = 1.0f/131072.0f;

  if (tid < 64){
    int ci = tid;
    float mu = stats[ci]*invM;
    float var = stats[64+ci]*invM - mu*mu;
    float rs = rsqrtf(fmaxf(var, 0.f) + 1e-5f);
    float kv = rs*ldmix(gam, ci, isbf);
    kk[ci] = kv;
    bsh[ci] = ldmix(bet, ci, isbf) - mu*kv;
    obs[ci] = ldmix(ob, ci, isbf);
    if (FINAL){
      float s = 0.f;
      #pragma unroll
      for (int f=0; f<8; f++) s += ldmix(rw, ci*8 + f, isbf);
      rw_s[ci] = s;
    }
  }
  {
    uint32_t* Wd = (uint32_t*)Wl;
    for (int u=tid; u<64*32; u+=256){
      int co = u>>5, jd = u&31;
      float w0 = ldmix(ow, (co<<6) + (jd<<1), isbf);
      float w1 = ldmix(ow, (co<<6) + (jd<<1) + 1, isbf);
      Wd[co*(SA/2) + jd] = (uint32_t)f2u(w0) | ((uint32_t)f2u(w1) << 16);
    }
  }
  __syncthreads();
  {
    uint32_t* Yd = (uint32_t*)Yl;
    for (int u=tid; u<128*32; u+=256){
      int t = u>>5, jd = u&31;
      int ci = jd<<1;
      int base = (((b*128+t)*8+v)) << 6;
      float y0 = fmaxf(X[base+ci]*kk[ci] + bsh[ci], 0.f);
      float y1 = fmaxf(X[base+ci+1]*kk[ci+1] + bsh[ci+1], 0.f);
      Yd[t*(SA/2) + jd] = (uint32_t)f2u(y0) | ((uint32_t)f2u(y1) << 16);
    }
  }
  __syncthreads();

  int wv_ = tid >> 6, lane = tid & 63;
  int q = lane >> 4, l16 = lane & 15;
  int tb0 = wv_ * 32;

  f32x4 acc[2][4];
  #pragma unroll
  for (int mt=0; mt<2; mt++)
    #pragma unroll
    for (int nt=0; nt<4; nt++)
      acc[mt][nt] = (f32x4){0.f,0.f,0.f,0.f};

  #pragma unroll
  for (int s=0; s<2; s++){
    int col = 32*s + q*8;
    bf16x8 afr[2], bfr[4];
    #pragma unroll
    for (int mt=0; mt<2; mt++){
      int row = tb0 + mt*16 + l16;
      afr[mt] = *(const bf16x8*)&Yl[row*SA + col];
    }
    #pragma unroll
    for (int nt=0; nt<4; nt++){
      int co = nt*16 + l16;
      bfr[nt] = *(const bf16x8*)&Wl[co*SA + col];
    }
    #pragma unroll
    for (int mt=0; mt<2; mt++)
      #pragma unroll
      for (int nt=0; nt<4; nt++)
        acc[mt][nt] = __builtin_amdgcn_mfma_f32_16x16x32_bf16(afr[mt], bfr[nt], acc[mt][nt], 0, 0, 0);
  }

  __syncthreads();   // MFMA reads of Yl done; reuse as Zl
  #pragma unroll
  for (int mt=0; mt<2; mt++){
    #pragma unroll
    for (int r=0; r<4; r++){
      int t = tb0 + mt*16 + q*4 + r;
      #pragma unroll
      for (int nt=0; nt<4; nt++){
        int co = nt*16 + l16;
        Yl[t*SA + co] = f2u(acc[mt][nt][r] + obs[co]);
      }
    }
  }
  __syncthreads();
  if (!FINAL){
    // transpose-write epilogue: coalesced global stores
    for (int u=tid; u<8192; u+=256){
      int l = u & 63;
      int idx = u >> 6;
      int co = idx >> 1, thi = idx & 1;
      int t = (thi<<6) + l;
      float z = tanhf(u2f(Yl[t*SA + co]));
      int r = (b<<10) + (co<<4) + (v<<1) + thi;
      if (presc) z *= presc[r];       // lane-uniform
      out16[(r<<6) + l] = f2u(z);
    }
  } else {
    // fused regression+mean: each thread's idx-parity is constant -> one thi per wave
    float zsum = 0.f;
    for (int u=tid; u<8192; u+=256){
      int l = u & 63;
      int idx = u >> 6;
      int co = idx >> 1;
      int t = ((idx & 1)<<6) + l;
      float z = tanhf(u2f(Yl[t*SA + co]));
      zsum += z * rw_s[l];
    }
    for (int off=32; off; off>>=1) zsum += __shfl_down(zsum, off);
    if (lane == 0) wred[wv_] = zsum;
    __syncthreads();
    if (tid == 0){
      int base = (b<<3) + ((v&3)<<1);
      atomicAdd(&zacc[base],   wred[0] + wred[2]);   // thi=0 (waves 0,2)
      atomicAdd(&zacc[base+1], wred[1] + wred[3]);   // thi=1 (waves 1,3)
    }
  }
}

// ---- finish: out[i] = zacc[i]/1024 + sum(rb)/8 ----
__global__ __launch_bounds__(256) void k_fin2(const float* __restrict__ zacc, const void* __restrict__ rb,
                                              const int* __restrict__ flag, void* __restrict__ out){
  int i = blockIdx.x*256 + threadIdx.x;
  if (i >= 1024) return;
  int isbf = *flag;
  float rbs = 0.f;
  #pragma unroll
  for (int f=0; f<8; f++) rbs += ldmix(rb, f, isbf);
  float val = zacc[i]*(1.0f/1024.0f) + rbs*0.125f;
  if (isbf) ((u16*)out)[i] = f2u(val);
  else      ((float*)out)[i] = val;
}

extern "C" void kernel_launch(void* const* d_in, const int* in_sizes, int n_in,
                              void* d_out, int out_size, void* d_ws, size_t ws_size,
                              hipStream_t stream){
  (void)in_sizes; (void)n_in; (void)out_size; (void)ws_size;
  char* p = (char*)d_ws;
  auto alloc = [&](size_t bytes){ void* r = (void*)p; p += (bytes + 255) & ~(size_t)255; return r; };
  u16*   U1   = (u16*)  alloc(sizeof(u16)*(size_t)N_NODES*64);  // Bs16 | A16 ; later D16
  u16*   U2   = (u16*)  alloc(sizeof(u16)*(size_t)N_NODES*64);  // E16
  float* C    = (float*)alloc(sizeof(float)*(size_t)N_NODES*64);// tconv out (fp32)
  int*   deg  = (int*)  alloc(sizeof(int)*N_NODES);
  float* dinv = (float*)alloc(sizeof(float)*N_NODES);
  int*   offs = (int*)  alloc(sizeof(int)*N_NODES);
  int*   adj  = (int*)  alloc(sizeof(int)*N_EDGES);
  int*   H    = (int*)  alloc(sizeof(int)*256*256);
  int*   P    = (int*)  alloc(sizeof(int)*256*256);
  int*   bt   = (int*)  alloc(sizeof(int)*256);
  int*   bb   = (int*)  alloc(sizeof(int)*260);
  float* stats= (float*)alloc(sizeof(float)*128);
  int*   flag = (int*)  alloc(sizeof(int)*64);
  u16*   Wtb  = (u16*)  alloc(sizeof(u16)*192*64);
  float* braw = (float*)alloc(sizeof(float)*192);
  float* zacc = (float*)alloc(sizeof(float)*1024);
  uint32_t* ebuf = (uint32_t*)C;             // alias: C dead until tconv1
  u16* Bs16 = U1;                            // N x 32 bf16 (prescaled x)
  u16* A16  = U1 + (size_t)N_NODES*32;       // N x 32 bf16 (agg1 out)
  u16* D16  = U1;                            // N x 64 bf16 (bnfuse1 out, prescaled)
  u16* E16  = U2;                            // N x 64 bf16 (agg2 out)

  const void* x   = d_in[0];
  const int* edge = (const int*)d_in[1];
  const void* g1w = d_in[2];  const void* g1b = d_in[3];
  const void* t1w = d_in[4];  const void* t1b = d_in[5];
  const void* bn1g= d_in[6];  const void* bn1b= d_in[7];
  const void* o1w = d_in[8];  const void* o1b = d_in[9];
  const void* g2w = d_in[10]; const void* g2b = d_in[11];
  const void* t2w = d_in[12]; const void* t2b = d_in[13];
  const void* bn2g= d_in[14]; const void* bn2b= d_in[15];
  const void* o2w = d_in[16]; const void* o2b = d_in[17];
  const void* rw  = d_in[18]; const void* rb  = d_in[19];
  const int* src = edge;
  const int* dst = edge + N_EDGES;

  k_detect<<<1, 64, 0, stream>>>((const uint32_t*)x, flag);

  // graph prep: two-pass counting sort, zero global atomics
  k_hist    <<<256, 256, 0, stream>>>(dst, H);
  k_colscan <<<256, 256, 0, stream>>>(H, P, bt);
  k_bbscan  <<<1, 256, 0, stream>>>(bt, bb);
  k_scatter2<<<256, 256, 0, stream>>>(src, dst, P, bb, ebuf);
  k_bsort2  <<<256, 512, 0, stream>>>(ebuf, bb, x, flag, adj, offs, deg, dinv, Bs16);

  // ---- layer 1 ----
  k_aggp2<32>  <<<N_NODES/64, 256, 0, stream>>>(Bs16, adj, offs, deg, dinv, A16);
  k_wcomb<32>  <<<3*32+3, 64, 0, stream>>>(g1w, g1b, t1w, flag, Wtb, braw);
  hipMemsetAsync(stats, 0, sizeof(float)*128, stream);
  k_tconv3<32> <<<1024, 256, 0, stream>>>(A16, Wtb, braw, t1b, flag, C, stats);
  k_bnfuse3<false><<<1024, 256, 0, stream>>>(C, stats, bn1g, bn1b, o1w, o1b, flag, dinv, D16,
                                             (float*)nullptr, (const void*)nullptr);

  // ---- layer 2 ----
  k_aggp2<64>  <<<N_NODES/32, 256, 0, stream>>>(D16, adj, offs, deg, dinv, E16);
  k_wcomb<64>  <<<3*64+3, 64, 0, stream>>>(g2w, g2b, t2w, flag, Wtb, braw);
  hipMemsetAsync(stats, 0, sizeof(float)*128, stream);
  k_tconv3<64> <<<1024, 256, 0, stream>>>(E16, Wtb, braw, t2b, flag, C, stats);
  hipMemsetAsync(zacc, 0, sizeof(float)*1024, stream);
  k_bnfuse3<true><<<1024, 256, 0, stream>>>(C, stats, bn2g, bn2b, o2w, o2b, flag, (const float*)nullptr,
                                            (u16*)nullptr, zacc, rw);
  k_fin2<<<4, 256, 0, stream>>>(zacc, rb, flag, d_out);
}

// Round 14
// 322.472 us; speedup vs baseline: 1.9341x; 1.0407x over previous
//
#include <hip/hip_runtime.h>
#include <stdint.h>

typedef unsigned short u16;
typedef __attribute__((ext_vector_type(8))) short bf16x8;
typedef __attribute__((ext_vector_type(4))) float f32x4;

static const int N_NODES = 131072;   // B*T*NN = 128*128*8
static const int N_EDGES = 1048576;

__device__ __forceinline__ float u2f(u16 u){
  union{uint32_t i; float f;} w; w.i = ((uint32_t)u)<<16; return w.f;
}
__device__ __forceinline__ u16 f2u(float f){
  union{float f; uint32_t u;} v; v.f=f;
  uint32_t u=v.u;
  u += 0x7fff + ((u>>16)&1);   // round-to-nearest-even
  return (u16)(u>>16);
}
__device__ __forceinline__ float bits2f(uint32_t b){
  union{uint32_t i; float f;} w; w.i = b; return w.f;
}
__device__ __forceinline__ float ldv(const float* p, int i){ return p[i]; }
__device__ __forceinline__ float ldv(const u16* p, int i){ return u2f(p[i]); }
__device__ __forceinline__ void stv(float* p, int i, float v){ p[i]=v; }
__device__ __forceinline__ void stv(u16* p, int i, float v){ p[i]=f2u(v); }
__device__ __forceinline__ float ldmix(const void* p, int i, int isbf){
  return isbf ? u2f(((const u16*)p)[i]) : ((const float*)p)[i];
}

// ---------------- detect dtype + zero all accumulators (replaces 3 memsets) ----------------
__global__ __launch_bounds__(256) void k_detect(const uint32_t* __restrict__ x, int* __restrict__ flag,
                                                float* __restrict__ stats1, float* __restrict__ stats2,
                                                float* __restrict__ zacc){
  int tid = threadIdx.x;
  if (tid < 128){ stats1[tid] = 0.f; stats2[tid] = 0.f; }
  for (int i=tid; i<1024; i+=256) zacc[i] = 0.f;
  if (tid == 0){
    int cnt=0;
    for (int i=0;i<256;i++){
      uint32_t e=(x[i]>>7)&0xFFu;
      if (e>=0x6Fu && e<=0x85u) cnt++;
    }
    *flag = (cnt>=128) ? 1 : 0;
  }
}

// ---------------- graph prep: two-pass counting sort, NO global atomics ----------------
__global__ __launch_bounds__(256) void k_hist(const int* __restrict__ dst, int* __restrict__ H){
  __shared__ int h[256];
  int tid = threadIdx.x;
  h[tid] = 0;
  __syncthreads();
  int base = blockIdx.x*4096;
  #pragma unroll
  for (int i=0;i<16;i++){
    int e = base + i*256 + tid;
    atomicAdd(&h[(dst[e] & (N_NODES-1))>>9], 1);
  }
  __syncthreads();
  H[blockIdx.x*256 + tid] = h[tid];
}

__global__ __launch_bounds__(256) void k_colscan(const int* __restrict__ H, int* __restrict__ P,
                                                 int* __restrict__ bt){
  __shared__ int sc[256];
  int b = blockIdx.x, tid = threadIdx.x;
  int v = H[tid*256 + b];
  sc[tid] = v; __syncthreads();
  for (int d=1; d<256; d<<=1){
    int o = (tid>=d) ? sc[tid-d] : 0; __syncthreads();
    sc[tid] += o; __syncthreads();
  }
  P[tid*256 + b] = sc[tid] - v;
  if (tid==255) bt[b] = sc[255];
}

// scatter with bucket bases derived in-block from bt (k_bbscan eliminated)
__global__ __launch_bounds__(256) void k_scatter2(const int* __restrict__ src, const int* __restrict__ dst,
                                                  const int* __restrict__ P, const int* __restrict__ bt,
                                                  uint32_t* __restrict__ ebuf){
  __shared__ int cu[256], sc[256];
  int tid = threadIdx.x;
  int v = bt[tid];
  sc[tid] = v; __syncthreads();
  for (int d=1; d<256; d<<=1){
    int o = (tid>=d) ? sc[tid-d] : 0; __syncthreads();
    sc[tid] += o; __syncthreads();
  }
  cu[tid] = (sc[tid] - v) + P[blockIdx.x*256 + tid];   // bb[tid] + P
  __syncthreads();
  int base = blockIdx.x*4096;
  #pragma unroll
  for (int i=0;i<16;i++){
    int e = base + i*256 + tid;
    int s = src[e] & (N_NODES-1);
    int d = dst[e] & (N_NODES-1);
    int pos = atomicAdd(&cu[d>>9], 1);           // LDS atomic only
    ebuf[pos] = (uint32_t)s | ((uint32_t)(d & 511) << 17);
  }
}

// per-bucket counting sort + emit offs/deg/dinv + fused dinv-prescale of x -> bf16 (F=32)
__global__ __launch_bounds__(512) void k_bsort2(const uint32_t* __restrict__ ebuf, const int* __restrict__ bt,
                                                const void* __restrict__ x, const int* __restrict__ flag,
                                                int* __restrict__ adj, int* __restrict__ offs,
                                                int* __restrict__ deg, float* __restrict__ dinv,
                                                u16* __restrict__ Bout){
  __shared__ uint32_t ein[5120], outs[5120];
  __shared__ int hist[512], sc[512], cu[512];
  __shared__ int sct[256];
  __shared__ float dv[512];
  int b = blockIdx.x, tid = threadIdx.x;
  // derive lo/hi from bt scan
  if (tid < 256){ sct[tid] = bt[tid]; }
  __syncthreads();
  for (int d=1; d<256; d<<=1){
    int o = (tid < 256 && tid>=d) ? sct[tid-d] : 0; __syncthreads();
    if (tid < 256) sct[tid] += o; __syncthreads();
  }
  int lo = sct[b] - bt[b], hi = sct[b];
  int cnt = hi - lo; if (cnt > 5120) cnt = 5120; if (cnt < 0) cnt = 0;
  hist[tid] = 0;
  __syncthreads();
  for (int i=tid; i<cnt; i+=512){
    uint32_t p = ebuf[lo+i];
    ein[i] = p;
    atomicAdd(&hist[(p>>17)&511], 1);
  }
  __syncthreads();
  sc[tid] = hist[tid];
  __syncthreads();
  for (int d=1; d<512; d<<=1){
    int v = (tid>=d) ? sc[tid-d] : 0;
    __syncthreads();
    sc[tid] += v;
    __syncthreads();
  }
  {
    int ex = sc[tid] - hist[tid];
    int node = b*512 + tid;
    offs[node] = lo + ex;
    deg[node]  = hist[tid];
    float rs = rsqrtf((float)hist[tid] + 1.0f);
    dinv[node] = rs;
    dv[tid] = rs;
    cu[tid] = ex;
  }
  __syncthreads();
  for (int i=tid; i<cnt; i+=512){
    uint32_t p = ein[i];
    int pos = atomicAdd(&cu[(p>>17)&511], 1);
    outs[pos] = p & 0x1FFFFu;
  }
  __syncthreads();
  for (int i=tid; i<cnt; i+=512) adj[lo+i] = (int)outs[i];
  int isbf = *flag;
  for (int u=tid; u<16384; u+=512){
    int nl = u>>5, c = u&31;
    int idx = ((b<<9) + nl)*32 + c;
    stv(Bout, idx, dv[nl]*ldmix(x, idx, isbf));
  }
}

// ---- GCN aggregation, chunked multi-node-per-wave gather, 8 outstanding loads ----
__device__ __forceinline__ void acc16(uint4 a, float* acc){
  acc[0] += bits2f(a.x<<16); acc[1] += bits2f(a.x&0xFFFF0000u);
  acc[2] += bits2f(a.y<<16); acc[3] += bits2f(a.y&0xFFFF0000u);
  acc[4] += bits2f(a.z<<16); acc[5] += bits2f(a.z&0xFFFF0000u);
  acc[6] += bits2f(a.w<<16); acc[7] += bits2f(a.w&0xFFFF0000u);
}
template<int F>
__global__ __launch_bounds__(256) void k_aggp2(const u16* __restrict__ Xs,
                                               const int* __restrict__ adj, const int* __restrict__ offs,
                                               const int* __restrict__ deg, const float* __restrict__ dinv,
                                               u16* __restrict__ out){
  constexpr int CH  = F/8;            // 16B chunks per row
  constexpr int GPW = 64/CH;          // nodes per wave
  int tid = threadIdx.x;
  int wv = tid>>6, lane = tid&63;
  int g = lane / CH;
  int k = lane % CH;
  int n = blockIdx.x*(4*GPW) + wv*GPW + g;
  int o = offs[n] & (N_EDGES-1);
  int cnt = min(deg[n], 8192);
  const uint4* X4 = (const uint4*)Xs;
  uint4 sv = X4[(size_t)n*CH + k];
  float acc[8] = {0,0,0,0,0,0,0,0};
  acc16(sv, acc);
  int e = 0;
  for (; e+8 <= cnt; e += 8){
    int i0 = adj[o+e+0] & (N_NODES-1);
    int i1 = adj[o+e+1] & (N_NODES-1);
    int i2 = adj[o+e+2] & (N_NODES-1);
    int i3 = adj[o+e+3] & (N_NODES-1);
    int i4 = adj[o+e+4] & (N_NODES-1);
    int i5 = adj[o+e+5] & (N_NODES-1);
    int i6 = adj[o+e+6] & (N_NODES-1);
    int i7 = adj[o+e+7] & (N_NODES-1);
    uint4 a0 = X4[(size_t)i0*CH + k];
    uint4 a1 = X4[(size_t)i1*CH + k];
    uint4 a2 = X4[(size_t)i2*CH + k];
    uint4 a3 = X4[(size_t)i3*CH + k];
    uint4 a4 = X4[(size_t)i4*CH + k];
    uint4 a5 = X4[(size_t)i5*CH + k];
    uint4 a6 = X4[(size_t)i6*CH + k];
    uint4 a7 = X4[(size_t)i7*CH + k];
    acc16(a0, acc); acc16(a1, acc); acc16(a2, acc); acc16(a3, acc);
    acc16(a4, acc); acc16(a5, acc); acc16(a6, acc); acc16(a7, acc);
  }
  if (e+4 <= cnt){
    int i0 = adj[o+e+0] & (N_NODES-1);
    int i1 = adj[o+e+1] & (N_NODES-1);
    int i2 = adj[o+e+2] & (N_NODES-1);
    int i3 = adj[o+e+3] & (N_NODES-1);
    uint4 a0 = X4[(size_t)i0*CH + k];
    uint4 a1 = X4[(size_t)i1*CH + k];
    uint4 a2 = X4[(size_t)i2*CH + k];
    uint4 a3 = X4[(size_t)i3*CH + k];
    acc16(a0, acc); acc16(a1, acc); acc16(a2, acc); acc16(a3, acc);
    e += 4;
  }
  for (; e < cnt; e++){
    int s = adj[o+e] & (N_NODES-1);
    uint4 a = X4[(size_t)s*CH + k];
    acc16(a, acc);
  }
  float dv = dinv[n];
  uint4 r;
  r.x = (uint32_t)f2u(acc[0]*dv) | ((uint32_t)f2u(acc[1]*dv) << 16);
  r.y = (uint32_t)f2u(acc[2]*dv) | ((uint32_t)f2u(acc[3]*dv) << 16);
  r.z = (uint32_t)f2u(acc[4]*dv) | ((uint32_t)f2u(acc[5]*dv) << 16);
  r.w = (uint32_t)f2u(acc[6]*dv) | ((uint32_t)f2u(acc[7]*dv) << 16);
  ((uint4*)out)[(size_t)n*CH + k] = r;
}

// ---- combined weight-fold for BOTH layers in one launch ----
__device__ __forceinline__ void wcomb_one(int Kin, const void* gW, const void* gb, const void* tw,
                                          int isbf, u16* Wtb, float* braw, int r, int co){
  if (r < 3*Kin){
    int k = r / Kin, j = r - (r/Kin)*Kin;
    float acc = 0.f;
    for (int c=0; c<64; c++)
      acc += ldmix(gW, j*64+c, isbf) * ldmix(tw, co*192 + c*3 + k, isbf);
    Wtb[co*(3*Kin) + r] = f2u(acc);
  } else {
    int k = r - 3*Kin;
    float acc = 0.f;
    for (int c=0; c<64; c++)
      acc += ldmix(gb, c, isbf) * ldmix(tw, co*192 + c*3 + k, isbf);
    braw[k*64 + co] = acc;
  }
}
__global__ __launch_bounds__(64) void k_wcombB(const void* __restrict__ g1w, const void* __restrict__ g1b,
                                               const void* __restrict__ t1w,
                                               const void* __restrict__ g2w, const void* __restrict__ g2b,
                                               const void* __restrict__ t2w,
                                               const int* __restrict__ flag,
                                               u16* __restrict__ Wtb1, float* __restrict__ braw1,
                                               u16* __restrict__ Wtb2, float* __restrict__ braw2){
  int isbf = *flag;
  int r = blockIdx.x, co = threadIdx.x;
  if (r < 99) wcomb_one(32, g1w, g1b, t1w, isbf, Wtb1, braw1, r, co);
  else        wcomb_one(64, g2w, g2b, t2w, isbf, Wtb2, braw2, r-99, co);
}

// ---- fused linear+temporal-conv via bf16 MFMA + fused BN-stats; in bf16, out bf16 ----
template<int Kin>
__global__ __launch_bounds__(256) void k_tconv3(const u16* __restrict__ A, const u16* __restrict__ Wtb,
                                                const float* __restrict__ braw, const void* __restrict__ tb,
                                                const int* __restrict__ flag, u16* __restrict__ out,
                                                float* __restrict__ stats){
  constexpr int K  = 3*Kin;
  constexpr int SA = Kin + 8;
  constexpr int SW = K + 8;
  constexpr int JH = Kin/2;
  constexpr int JL = (Kin==64) ? 5 : 4;
  __shared__ alignas(16) u16 At[130*SA];
  __shared__ alignas(16) u16 Wl[64*SW];
  __shared__ float ball[64], bs0[64], bs2[64];
  __shared__ float wsum[4][64], wsum2[4][64];

  int isbf = *flag;
  int bid = blockIdx.x;
  int b = bid>>3, v = bid&7;
  const int tid = threadIdx.x;

  if (tid < 64){
    float b0=braw[tid], b1=braw[64+tid], b2=braw[128+tid];
    ball[tid] = ldmix(tb, tid, isbf) + b0 + b1 + b2;
    bs0[tid] = b0; bs2[tid] = b2;
  }
  {
    const uint32_t* Wg = (const uint32_t*)Wtb;
    uint32_t* Wd = (uint32_t*)Wl;
    for (int u=tid; u<64*(K/2); u+=256){
      int co = u/(K/2), jd = u - co*(K/2);
      Wd[co*(SW/2) + jd] = Wg[u];
    }
  }
  {
    uint32_t* Ad = (uint32_t*)At;
    const uint32_t* Ag = (const uint32_t*)A;
    for (int u=tid; u<130*JH; u+=256){
      int t1 = u >> JL, jd = u & (JH-1);
      int t = t1 - 1;
      uint32_t pack = 0;
      if (t >= 0 && t < 128)
        pack = Ag[((((b*128+t)*8+v))*Kin >> 1) + jd];
      Ad[t1*(SA/2) + jd] = pack;
    }
  }
  __syncthreads();

  int wv_ = tid >> 6, lane = tid & 63;
  int q = lane >> 4, l16 = lane & 15;
  int tb0 = wv_ * 32;

  f32x4 acc[2][4];
  #pragma unroll
  for (int mt=0; mt<2; mt++)
    #pragma unroll
    for (int nt=0; nt<4; nt++)
      acc[mt][nt] = (f32x4){0.f,0.f,0.f,0.f};

  #pragma unroll
  for (int s=0; s<K/32; s++){
    int kk = (32*s)/Kin;
    int j0 = 32*s - kk*Kin;
    int col = j0 + q*8;
    bf16x8 afr[2], bfr[4];
    #pragma unroll
    for (int mt=0; mt<2; mt++){
      int row = tb0 + mt*16 + l16 + kk;
      afr[mt] = *(const bf16x8*)&At[row*SA + col];
    }
    #pragma unroll
    for (int nt=0; nt<4; nt++){
      int co = nt*16 + l16;
      bfr[nt] = *(const bf16x8*)&Wl[co*SW + 32*s + q*8];
    }
    #pragma unroll
    for (int mt=0; mt<2; mt++)
      #pragma unroll
      for (int nt=0; nt<4; nt++)
        acc[mt][nt] = __builtin_amdgcn_mfma_f32_16x16x32_bf16(afr[mt], bfr[nt], acc[mt][nt], 0, 0, 0);
  }

  float ls[4] = {0,0,0,0}, ls2[4] = {0,0,0,0};
  #pragma unroll
  for (int mt=0; mt<2; mt++){
    #pragma unroll
    for (int r=0; r<4; r++){
      int t = tb0 + mt*16 + q*4 + r;
      int base = (((b*128+t)*8+v)) << 6;
      #pragma unroll
      for (int nt=0; nt<4; nt++){
        int co = nt*16 + l16;
        float val = acc[mt][nt][r] + ball[co];
        if (t == 0)   val -= bs0[co];
        if (t == 127) val -= bs2[co];
        out[base + co] = f2u(val);
        ls[nt] += val; ls2[nt] += val*val;
      }
    }
  }
  #pragma unroll
  for (int nt=0; nt<4; nt++){
    ls[nt]  += __shfl_xor(ls[nt], 16);  ls[nt]  += __shfl_xor(ls[nt], 32);
    ls2[nt] += __shfl_xor(ls2[nt], 16); ls2[nt] += __shfl_xor(ls2[nt], 32);
  }
  if (q == 0){
    #pragma unroll
    for (int nt=0; nt<4; nt++){
      wsum[wv_][nt*16 + l16]  = ls[nt];
      wsum2[wv_][nt*16 + l16] = ls2[nt];
    }
  }
  __syncthreads();
  if (tid < 64){
    float a = wsum[0][tid]+wsum[1][tid]+wsum[2][tid]+wsum[3][tid];
    float a2 = wsum2[0][tid]+wsum2[1][tid]+wsum2[2][tid]+wsum2[3][tid];
    atomicAdd(&stats[tid], a);
    atomicAdd(&stats[64+tid], a2);
  }
}

// ---- BN-apply + ReLU + 1x1 conv via bf16 MFMA + tanh; FINAL fuses regression+mean ----
template<bool FINAL>
__global__ __launch_bounds__(256) void k_bnfuse3(const u16* __restrict__ X, const float* __restrict__ stats,
                                                 const void* __restrict__ gam, const void* __restrict__ bet,
                                                 const void* __restrict__ ow, const void* __restrict__ ob,
                                                 const int* __restrict__ flag, const float* __restrict__ presc,
                                                 u16* __restrict__ out16,
                                                 float* __restrict__ zacc, const void* __restrict__ rw){
  constexpr int SA = 72;
  __shared__ alignas(16) u16 Yl[128*SA];       // reused as Zl in epilogue
  __shared__ alignas(16) u16 Wl[64*SA];
  __shared__ float kk[64], bsh[64], obs[64];
  __shared__ float rw_s[64];
  __shared__ float wred[4];
  int isbf = *flag;
  int bid = blockIdx.x;
  int b = bid>>3, v = bid&7;
  const int tid = threadIdx.x;
  const float invM = 1.0f/131072.0f;

  if (tid < 64){
    int ci = tid;
    float mu = stats[ci]*invM;
    float var = stats[64+ci]*invM - mu*mu;
    float rs = rsqrtf(fmaxf(var, 0.f) + 1e-5f);
    float kv = rs*ldmix(gam, ci, isbf);
    kk[ci] = kv;
    bsh[ci] = ldmix(bet, ci, isbf) - mu*kv;
    obs[ci] = ldmix(ob, ci, isbf);
    if (FINAL){
      float s = 0.f;
      #pragma unroll
      for (int f=0; f<8; f++) s += ldmix(rw, ci*8 + f, isbf);
      rw_s[ci] = s;
    }
  }
  {
    uint32_t* Wd = (uint32_t*)Wl;
    for (int u=tid; u<64*32; u+=256){
      int co = u>>5, jd = u&31;
      float w0 = ldmix(ow, (co<<6) + (jd<<1), isbf);
      float w1 = ldmix(ow, (co<<6) + (jd<<1) + 1, isbf);
      Wd[co*(SA/2) + jd] = (uint32_t)f2u(w0) | ((uint32_t)f2u(w1) << 16);
    }
  }
  __syncthreads();
  {
    uint32_t* Yd = (uint32_t*)Yl;
    const uint32_t* Xg = (const uint32_t*)X;
    for (int u=tid; u<128*32; u+=256){
      int t = u>>5, jd = u&31;
      int ci = jd<<1;
      int rowbase = (((b*128+t)*8+v)) << 6;
      uint32_t pr = Xg[(rowbase>>1) + jd];
      float x0 = bits2f(pr<<16);
      float x1 = bits2f(pr & 0xFFFF0000u);
      float y0 = fmaxf(x0*kk[ci] + bsh[ci], 0.f);
      float y1 = fmaxf(x1*kk[ci+1] + bsh[ci+1], 0.f);
      Yd[t*(SA/2) + jd] = (uint32_t)f2u(y0) | ((uint32_t)f2u(y1) << 16);
    }
  }
  __syncthreads();

  int wv_ = tid >> 6, lane = tid & 63;
  int q = lane >> 4, l16 = lane & 15;
  int tb0 = wv_ * 32;

  f32x4 acc[2][4];
  #pragma unroll
  for (int mt=0; mt<2; mt++)
    #pragma unroll
    for (int nt=0; nt<4; nt++)
      acc[mt][nt] = (f32x4){0.f,0.f,0.f,0.f};

  #pragma unroll
  for (int s=0; s<2; s++){
    int col = 32*s + q*8;
    bf16x8 afr[2], bfr[4];
    #pragma unroll
    for (int mt=0; mt<2; mt++){
      int row = tb0 + mt*16 + l16;
      afr[mt] = *(const bf16x8*)&Yl[row*SA + col];
    }
    #pragma unroll
    for (int nt=0; nt<4; nt++){
      int co = nt*16 + l16;
      bfr[nt] = *(const bf16x8*)&Wl[co*SA + col];
    }
    #pragma unroll
    for (int mt=0; mt<2; mt++)
      #pragma unroll
      for (int nt=0; nt<4; nt++)
        acc[mt][nt] = __builtin_amdgcn_mfma_f32_16x16x32_bf16(afr[mt], bfr[nt], acc[mt][nt], 0, 0, 0);
  }

  __syncthreads();   // MFMA reads of Yl done; reuse as Zl
  #pragma unroll
  for (int mt=0; mt<2; mt++){
    #pragma unroll
    for (int r=0; r<4; r++){
      int t = tb0 + mt*16 + q*4 + r;
      #pragma unroll
      for (int nt=0; nt<4; nt++){
        int co = nt*16 + l16;
        Yl[t*SA + co] = f2u(acc[mt][nt][r] + obs[co]);
      }
    }
  }
  __syncthreads();
  if (!FINAL){
    for (int u=tid; u<8192; u+=256){
      int l = u & 63;
      int idx = u >> 6;
      int co = idx >> 1, thi = idx & 1;
      int t = (thi<<6) + l;
      float z = tanhf(u2f(Yl[t*SA + co]));
      int r = (b<<10) + (co<<4) + (v<<1) + thi;
      if (presc) z *= presc[r];       // lane-uniform
      out16[(r<<6) + l] = f2u(z);
    }
  } else {
    float zsum = 0.f;
    for (int u=tid; u<8192; u+=256){
      int l = u & 63;
      int idx = u >> 6;
      int co = idx >> 1;
      int t = ((idx & 1)<<6) + l;
      float z = tanhf(u2f(Yl[t*SA + co]));
      zsum += z * rw_s[l];
    }
    for (int off=32; off; off>>=1) zsum += __shfl_down(zsum, off);
    if (lane == 0) wred[wv_] = zsum;
    __syncthreads();
    if (tid == 0){
      int base = (b<<3) + ((v&3)<<1);
      atomicAdd(&zacc[base],   wred[0] + wred[2]);   // thi=0 (waves 0,2)
      atomicAdd(&zacc[base+1], wred[1] + wred[3]);   // thi=1 (waves 1,3)
    }
  }
}

// ---- finish: out[i] = zacc[i]/1024 + sum(rb)/8 ----
__global__ __launch_bounds__(256) void k_fin2(const float* __restrict__ zacc, const void* __restrict__ rb,
                                              const int* __restrict__ flag, void* __restrict__ out){
  int i = blockIdx.x*256 + threadIdx.x;
  if (i >= 1024) return;
  int isbf = *flag;
  float rbs = 0.f;
  #pragma unroll
  for (int f=0; f<8; f++) rbs += ldmix(rb, f, isbf);
  float val = zacc[i]*(1.0f/1024.0f) + rbs*0.125f;
  if (isbf) ((u16*)out)[i] = f2u(val);
  else      ((float*)out)[i] = val;
}

extern "C" void kernel_launch(void* const* d_in, const int* in_sizes, int n_in,
                              void* d_out, int out_size, void* d_ws, size_t ws_size,
                              hipStream_t stream){
  (void)in_sizes; (void)n_in; (void)out_size; (void)ws_size;
  char* p = (char*)d_ws;
  auto alloc = [&](size_t bytes){ void* r = (void*)p; p += (bytes + 255) & ~(size_t)255; return r; };
  u16*   U1   = (u16*)  alloc(sizeof(u16)*(size_t)N_NODES*64);  // Bs16|A16 ; later D16
  u16*   U2   = (u16*)  alloc(sizeof(u16)*(size_t)N_NODES*64);  // E16
  u16*   C16  = (u16*)  alloc(sizeof(u16)*(size_t)N_NODES*64);  // tconv out (bf16)
  int*   deg  = (int*)  alloc(sizeof(int)*N_NODES);
  float* dinv = (float*)alloc(sizeof(float)*N_NODES);
  int*   offs = (int*)  alloc(sizeof(int)*N_NODES);
  int*   adj  = (int*)  alloc(sizeof(int)*N_EDGES);
  int*   H    = (int*)  alloc(sizeof(int)*256*256);
  int*   P    = (int*)  alloc(sizeof(int)*256*256);
  int*   bt   = (int*)  alloc(sizeof(int)*256);
  float* stats1=(float*)alloc(sizeof(float)*128);
  float* stats2=(float*)alloc(sizeof(float)*128);
  int*   flag = (int*)  alloc(sizeof(int)*64);
  u16*   Wtb1 = (u16*)  alloc(sizeof(u16)*96*64);
  float* braw1= (float*)alloc(sizeof(float)*192);
  u16*   Wtb2 = (u16*)  alloc(sizeof(u16)*192*64);
  float* braw2= (float*)alloc(sizeof(float)*192);
  float* zacc = (float*)alloc(sizeof(float)*1024);
  uint32_t* ebuf = (uint32_t*)C16;           // alias: C16 dead until tconv1
  u16* Bs16 = U1;                            // N x 32 bf16 (prescaled x)
  u16* A16  = U1 + (size_t)N_NODES*32;       // N x 32 bf16 (agg1 out)
  u16* D16  = U1;                            // N x 64 bf16 (bnfuse1 out, prescaled)
  u16* E16  = U2;                            // N x 64 bf16 (agg2 out)

  const void* x   = d_in[0];
  const int* edge = (const int*)d_in[1];
  const void* g1w = d_in[2];  const void* g1b = d_in[3];
  const void* t1w = d_in[4];  const void* t1b = d_in[5];
  const void* bn1g= d_in[6];  const void* bn1b= d_in[7];
  const void* o1w = d_in[8];  const void* o1b = d_in[9];
  const void* g2w = d_in[10]; const void* g2b = d_in[11];
  const void* t2w = d_in[12]; const void* t2b = d_in[13];
  const void* bn2g= d_in[14]; const void* bn2b= d_in[15];
  const void* o2w = d_in[16]; const void* o2b = d_in[17];
  const void* rw  = d_in[18]; const void* rb  = d_in[19];
  const int* src = edge;
  const int* dst = edge + N_EDGES;

  k_detect<<<1, 256, 0, stream>>>((const uint32_t*)x, flag, stats1, stats2, zacc);

  // graph prep: two-pass counting sort, zero global atomics (bb derived in-block)
  k_hist    <<<256, 256, 0, stream>>>(dst, H);
  k_colscan <<<256, 256, 0, stream>>>(H, P, bt);
  k_scatter2<<<256, 256, 0, stream>>>(src, dst, P, bt, ebuf);
  k_bsort2  <<<256, 512, 0, stream>>>(ebuf, bt, x, flag, adj, offs, deg, dinv, Bs16);

  // weight folding for both layers (independent of graph)
  k_wcombB<<<294, 64, 0, stream>>>(g1w, g1b, t1w, g2w, g2b, t2w, flag, Wtb1, braw1, Wtb2, braw2);

  // ---- layer 1 ----
  k_aggp2<32>  <<<N_NODES/64, 256, 0, stream>>>(Bs16, adj, offs, deg, dinv, A16);
  k_tconv3<32> <<<1024, 256, 0, stream>>>(A16, Wtb1, braw1, t1b, flag, C16, stats1);
  k_bnfuse3<false><<<1024, 256, 0, stream>>>(C16, stats1, bn1g, bn1b, o1w, o1b, flag, dinv, D16,
                                             (float*)nullptr, (const void*)nullptr);

  // ---- layer 2 ----
  k_aggp2<64>  <<<N_NODES/32, 256, 0, stream>>>(D16, adj, offs, deg, dinv, E16);
  k_tconv3<64> <<<1024, 256, 0, stream>>>(E16, Wtb2, braw2, t2b, flag, C16, stats2);
  k_bnfuse3<true><<<1024, 256, 0, stream>>>(C16, stats2, bn2g, bn2b, o2w, o2b, flag, (const float*)nullptr,
                                            (u16*)nullptr, zacc, rw);
  k_fin2<<<4, 256, 0, stream>>>(zacc, rb, flag, d_out);
}

// Round 16
// 316.305 us; speedup vs baseline: 1.9718x; 1.0195x over previous
//
#include <hip/hip_runtime.h>
#include <stdint.h>

typedef unsigned short u16;
typedef __attribute__((ext_vector_type(8))) short bf16x8;
typedef __attribute__((ext_vector_type(4))) float f32x4;

static const int N_NODES = 131072;   // B*T*NN = 128*128*8
static const int N_EDGES = 1048576;

__device__ __forceinline__ float u2f(u16 u){
  union{uint32_t i; float f;} w; w.i = ((uint32_t)u)<<16; return w.f;
}
__device__ __forceinline__ u16 f2u(float f){
  union{float f; uint32_t u;} v; v.f=f;
  uint32_t u=v.u;
  u += 0x7fff + ((u>>16)&1);   // round-to-nearest-even
  return (u16)(u>>16);
}
__device__ __forceinline__ float bits2f(uint32_t b){
  union{uint32_t i; float f;} w; w.i = b; return w.f;
}
__device__ __forceinline__ float ldv(const float* p, int i){ return p[i]; }
__device__ __forceinline__ float ldv(const u16* p, int i){ return u2f(p[i]); }
__device__ __forceinline__ void stv(float* p, int i, float v){ p[i]=v; }
__device__ __forceinline__ void stv(u16* p, int i, float v){ p[i]=f2u(v); }
__device__ __forceinline__ float ldmix(const void* p, int i, int isbf){
  return isbf ? u2f(((const u16*)p)[i]) : ((const float*)p)[i];
}

// ---------------- detect dtype + zero all accumulators ----------------
__global__ __launch_bounds__(256) void k_detect(const uint32_t* __restrict__ x, int* __restrict__ flag,
                                                float* __restrict__ stats1, float* __restrict__ stats2,
                                                float* __restrict__ zacc){
  int tid = threadIdx.x;
  if (tid < 128){ stats1[tid] = 0.f; stats2[tid] = 0.f; }
  for (int i=tid; i<1024; i+=256) zacc[i] = 0.f;
  if (tid == 0){
    int cnt=0;
    for (int i=0;i<256;i++){
      uint32_t e=(x[i]>>7)&0xFFu;
      if (e>=0x6Fu && e<=0x85u) cnt++;
    }
    *flag = (cnt>=128) ? 1 : 0;
  }
}

// ---------------- graph prep: two-pass counting sort, NO global atomics ----------------
__global__ __launch_bounds__(256) void k_hist(const int* __restrict__ dst, int* __restrict__ H){
  __shared__ int h[256];
  int tid = threadIdx.x;
  h[tid] = 0;
  __syncthreads();
  int base = blockIdx.x*4096;
  #pragma unroll
  for (int i=0;i<16;i++){
    int e = base + i*256 + tid;
    atomicAdd(&h[(dst[e] & (N_NODES-1))>>9], 1);
  }
  __syncthreads();
  H[blockIdx.x*256 + tid] = h[tid];
}

__global__ __launch_bounds__(256) void k_colscan(const int* __restrict__ H, int* __restrict__ P,
                                                 int* __restrict__ bt){
  __shared__ int sc[256];
  int b = blockIdx.x, tid = threadIdx.x;
  int v = H[tid*256 + b];
  sc[tid] = v; __syncthreads();
  for (int d=1; d<256; d<<=1){
    int o = (tid>=d) ? sc[tid-d] : 0; __syncthreads();
    sc[tid] += o; __syncthreads();
  }
  P[tid*256 + b] = sc[tid] - v;
  if (tid==255) bt[b] = sc[255];
}

__global__ __launch_bounds__(256) void k_scatter2(const int* __restrict__ src, const int* __restrict__ dst,
                                                  const int* __restrict__ P, const int* __restrict__ bt,
                                                  uint32_t* __restrict__ ebuf){
  __shared__ int cu[256], sc[256];
  int tid = threadIdx.x;
  int v = bt[tid];
  sc[tid] = v; __syncthreads();
  for (int d=1; d<256; d<<=1){
    int o = (tid>=d) ? sc[tid-d] : 0; __syncthreads();
    sc[tid] += o; __syncthreads();
  }
  cu[tid] = (sc[tid] - v) + P[blockIdx.x*256 + tid];   // bb[tid] + P
  __syncthreads();
  int base = blockIdx.x*4096;
  #pragma unroll
  for (int i=0;i<16;i++){
    int e = base + i*256 + tid;
    int s = src[e] & (N_NODES-1);
    int d = dst[e] & (N_NODES-1);
    int pos = atomicAdd(&cu[d>>9], 1);           // LDS atomic only
    ebuf[pos] = (uint32_t)s | ((uint32_t)(d & 511) << 17);
  }
}

// per-bucket counting sort + emit offs/deg/dinv + fused dinv-prescale of x -> bf16 (F=32)
__global__ __launch_bounds__(512) void k_bsort2(const uint32_t* __restrict__ ebuf, const int* __restrict__ bt,
                                                const void* __restrict__ x, const int* __restrict__ flag,
                                                int* __restrict__ adj, int* __restrict__ offs,
                                                int* __restrict__ deg, float* __restrict__ dinv,
                                                u16* __restrict__ Bout){
  __shared__ uint32_t ein[5120], outs[5120];
  __shared__ int hist[512], sc[512], cu[512];
  __shared__ int sct[256];
  __shared__ float dv[512];
  int b = blockIdx.x, tid = threadIdx.x;
  if (tid < 256){ sct[tid] = bt[tid]; }
  __syncthreads();
  for (int d=1; d<256; d<<=1){
    int o = (tid < 256 && tid>=d) ? sct[tid-d] : 0; __syncthreads();
    if (tid < 256) sct[tid] += o; __syncthreads();
  }
  int lo = sct[b] - bt[b], hi = sct[b];
  int cnt = hi - lo; if (cnt > 5120) cnt = 5120; if (cnt < 0) cnt = 0;
  hist[tid] = 0;
  __syncthreads();
  for (int i=tid; i<cnt; i+=512){
    uint32_t p = ebuf[lo+i];
    ein[i] = p;
    atomicAdd(&hist[(p>>17)&511], 1);
  }
  __syncthreads();
  sc[tid] = hist[tid];
  __syncthreads();
  for (int d=1; d<512; d<<=1){
    int v = (tid>=d) ? sc[tid-d] : 0;
    __syncthreads();
    sc[tid] += v;
    __syncthreads();
  }
  {
    int ex = sc[tid] - hist[tid];
    int node = b*512 + tid;
    offs[node] = lo + ex;
    deg[node]  = hist[tid];
    float rs = rsqrtf((float)hist[tid] + 1.0f);
    dinv[node] = rs;
    dv[tid] = rs;
    cu[tid] = ex;
  }
  __syncthreads();
  for (int i=tid; i<cnt; i+=512){
    uint32_t p = ein[i];
    int pos = atomicAdd(&cu[(p>>17)&511], 1);
    outs[pos] = p & 0x1FFFFu;
  }
  __syncthreads();
  for (int i=tid; i<cnt; i+=512) adj[lo+i] = (int)outs[i];
  int isbf = *flag;
  for (int u=tid; u<16384; u+=512){
    int nl = u>>5, c = u&31;
    int idx = ((b<<9) + nl)*32 + c;
    stv(Bout, idx, dv[nl]*ldmix(x, idx, isbf));
  }
}

// ---- GCN aggregation, chunked multi-node-per-wave gather, 8 outstanding loads ----
__device__ __forceinline__ void acc16(uint4 a, float* acc){
  acc[0] += bits2f(a.x<<16); acc[1] += bits2f(a.x&0xFFFF0000u);
  acc[2] += bits2f(a.y<<16); acc[3] += bits2f(a.y&0xFFFF0000u);
  acc[4] += bits2f(a.z<<16); acc[5] += bits2f(a.z&0xFFFF0000u);
  acc[6] += bits2f(a.w<<16); acc[7] += bits2f(a.w&0xFFFF0000u);
}
template<int F>
__global__ __launch_bounds__(256) void k_aggp2(const u16* __restrict__ Xs,
                                               const int* __restrict__ adj, const int* __restrict__ offs,
                                               const int* __restrict__ deg, const float* __restrict__ dinv,
                                               u16* __restrict__ out){
  constexpr int CH  = F/8;            // 16B chunks per row
  constexpr int GPW = 64/CH;          // nodes per wave
  int tid = threadIdx.x;
  int wv = tid>>6, lane = tid&63;
  int g = lane / CH;
  int k = lane % CH;
  int n = blockIdx.x*(4*GPW) + wv*GPW + g;
  int o = offs[n] & (N_EDGES-1);
  int cnt = min(deg[n], 8192);
  const uint4* X4 = (const uint4*)Xs;
  uint4 sv = X4[(size_t)n*CH + k];
  float acc[8] = {0,0,0,0,0,0,0,0};
  acc16(sv, acc);
  int e = 0;
  for (; e+8 <= cnt; e += 8){
    int i0 = adj[o+e+0] & (N_NODES-1);
    int i1 = adj[o+e+1] & (N_NODES-1);
    int i2 = adj[o+e+2] & (N_NODES-1);
    int i3 = adj[o+e+3] & (N_NODES-1);
    int i4 = adj[o+e+4] & (N_NODES-1);
    int i5 = adj[o+e+5] & (N_NODES-1);
    int i6 = adj[o+e+6] & (N_NODES-1);
    int i7 = adj[o+e+7] & (N_NODES-1);
    uint4 a0 = X4[(size_t)i0*CH + k];
    uint4 a1 = X4[(size_t)i1*CH + k];
    uint4 a2 = X4[(size_t)i2*CH + k];
    uint4 a3 = X4[(size_t)i3*CH + k];
    uint4 a4 = X4[(size_t)i4*CH + k];
    uint4 a5 = X4[(size_t)i5*CH + k];
    uint4 a6 = X4[(size_t)i6*CH + k];
    uint4 a7 = X4[(size_t)i7*CH + k];
    acc16(a0, acc); acc16(a1, acc); acc16(a2, acc); acc16(a3, acc);
    acc16(a4, acc); acc16(a5, acc); acc16(a6, acc); acc16(a7, acc);
  }
  if (e+4 <= cnt){
    int i0 = adj[o+e+0] & (N_NODES-1);
    int i1 = adj[o+e+1] & (N_NODES-1);
    int i2 = adj[o+e+2] & (N_NODES-1);
    int i3 = adj[o+e+3] & (N_NODES-1);
    uint4 a0 = X4[(size_t)i0*CH + k];
    uint4 a1 = X4[(size_t)i1*CH + k];
    uint4 a2 = X4[(size_t)i2*CH + k];
    uint4 a3 = X4[(size_t)i3*CH + k];
    acc16(a0, acc); acc16(a1, acc); acc16(a2, acc); acc16(a3, acc);
    e += 4;
  }
  for (; e < cnt; e++){
    int s = adj[o+e] & (N_NODES-1);
    uint4 a = X4[(size_t)s*CH + k];
    acc16(a, acc);
  }
  float dv = dinv[n];
  uint4 r;
  r.x = (uint32_t)f2u(acc[0]*dv) | ((uint32_t)f2u(acc[1]*dv) << 16);
  r.y = (uint32_t)f2u(acc[2]*dv) | ((uint32_t)f2u(acc[3]*dv) << 16);
  r.z = (uint32_t)f2u(acc[4]*dv) | ((uint32_t)f2u(acc[5]*dv) << 16);
  r.w = (uint32_t)f2u(acc[6]*dv) | ((uint32_t)f2u(acc[7]*dv) << 16);
  ((uint4*)out)[(size_t)n*CH + k] = r;
}

// ---- combined weight-fold for BOTH layers + bf16 copies of 1x1 weights ----
__device__ __forceinline__ void wcomb_one(int Kin, const void* gW, const void* gb, const void* tw,
                                          int isbf, u16* Wtb, float* braw, int r, int co){
  if (r < 3*Kin){
    int k = r / Kin, j = r - (r/Kin)*Kin;
    float acc = 0.f;
    for (int c=0; c<64; c++)
      acc += ldmix(gW, j*64+c, isbf) * ldmix(tw, co*192 + c*3 + k, isbf);
    Wtb[co*(3*Kin) + r] = f2u(acc);
  } else {
    int k = r - 3*Kin;
    float acc = 0.f;
    for (int c=0; c<64; c++)
      acc += ldmix(gb, c, isbf) * ldmix(tw, co*192 + c*3 + k, isbf);
    braw[k*64 + co] = acc;
  }
}
__global__ __launch_bounds__(64) void k_wcombB(const void* __restrict__ g1w, const void* __restrict__ g1b,
                                               const void* __restrict__ t1w,
                                               const void* __restrict__ g2w, const void* __restrict__ g2b,
                                               const void* __restrict__ t2w,
                                               const void* __restrict__ o1w, const void* __restrict__ o2w,
                                               const int* __restrict__ flag,
                                               u16* __restrict__ Wtb1, float* __restrict__ braw1,
                                               u16* __restrict__ Wtb2, float* __restrict__ braw2,
                                               u16* __restrict__ owb1, u16* __restrict__ owb2){
  int isbf = *flag;
  int r = blockIdx.x, co = threadIdx.x;
  if (r < 99) wcomb_one(32, g1w, g1b, t1w, isbf, Wtb1, braw1, r, co);
  else if (r < 294) wcomb_one(64, g2w, g2b, t2w, isbf, Wtb2, braw2, r-99, co);
  else if (r < 358){
    int row = r - 294;
    owb1[row*64 + co] = f2u(ldmix(o1w, row*64 + co, isbf));
  } else {
    int row = r - 358;
    owb2[row*64 + co] = f2u(ldmix(o2w, row*64 + co, isbf));
  }
}

// ---- fused linear+temporal-conv via bf16 MFMA + fused BN-stats (r14 256-thr structure,
//      weights read directly from global bf16 Wtb — no LDS weight staging) ----
template<int Kin>
__global__ __launch_bounds__(256) void k_tconv3(const u16* __restrict__ A, const u16* __restrict__ Wtb,
                                                const float* __restrict__ braw, const void* __restrict__ tb,
                                                const int* __restrict__ flag, u16* __restrict__ out,
                                                float* __restrict__ stats){
  constexpr int K  = 3*Kin;
  constexpr int SA = Kin + 8;
  constexpr int JH = Kin/2;
  constexpr int JL = (Kin==64) ? 5 : 4;
  __shared__ alignas(16) u16 At[130*SA];
  __shared__ float ball[64], bs0[64], bs2[64];
  __shared__ float wsum[4][64], wsum2[4][64];

  int isbf = *flag;
  int bid = blockIdx.x;
  int b = bid>>3, v = bid&7;
  const int tid = threadIdx.x;

  if (tid < 64){
    float b0=braw[tid], b1=braw[64+tid], b2=braw[128+tid];
    ball[tid] = ldmix(tb, tid, isbf) + b0 + b1 + b2;
    bs0[tid] = b0; bs2[tid] = b2;
  }
  {
    uint32_t* Ad = (uint32_t*)At;
    const uint32_t* Ag = (const uint32_t*)A;
    for (int u=tid; u<130*JH; u+=256){
      int t1 = u >> JL, jd = u & (JH-1);
      int t = t1 - 1;
      uint32_t pack = 0;
      if (t >= 0 && t < 128)
        pack = Ag[((((b*128+t)*8+v))*Kin >> 1) + jd];
      Ad[t1*(SA/2) + jd] = pack;
    }
  }
  __syncthreads();

  int wv_ = tid >> 6, lane = tid & 63;
  int q = lane >> 4, l16 = lane & 15;
  int tb0 = wv_ * 32;

  f32x4 acc[2][4];
  #pragma unroll
  for (int mt=0; mt<2; mt++)
    #pragma unroll
    for (int nt=0; nt<4; nt++)
      acc[mt][nt] = (f32x4){0.f,0.f,0.f,0.f};

  #pragma unroll
  for (int s=0; s<K/32; s++){
    int kk = (32*s)/Kin;
    int j0 = 32*s - kk*Kin;
    int col = j0 + q*8;
    bf16x8 afr[2], bfr[4];
    #pragma unroll
    for (int mt=0; mt<2; mt++){
      int row = tb0 + mt*16 + l16 + kk;
      afr[mt] = *(const bf16x8*)&At[row*SA + col];
    }
    #pragma unroll
    for (int nt=0; nt<4; nt++){
      int co = nt*16 + l16;
      bfr[nt] = *(const bf16x8*)&Wtb[co*K + 32*s + q*8];   // global, L1/L2-hot broadcast
    }
    #pragma unroll
    for (int mt=0; mt<2; mt++)
      #pragma unroll
      for (int nt=0; nt<4; nt++)
        acc[mt][nt] = __builtin_amdgcn_mfma_f32_16x16x32_bf16(afr[mt], bfr[nt], acc[mt][nt], 0, 0, 0);
  }

  float ls[4] = {0,0,0,0}, ls2[4] = {0,0,0,0};
  #pragma unroll
  for (int mt=0; mt<2; mt++){
    #pragma unroll
    for (int r=0; r<4; r++){
      int t = tb0 + mt*16 + q*4 + r;
      int base = (((b*128+t)*8+v)) << 6;
      #pragma unroll
      for (int nt=0; nt<4; nt++){
        int co = nt*16 + l16;
        float val = acc[mt][nt][r] + ball[co];
        if (t == 0)   val -= bs0[co];
        if (t == 127) val -= bs2[co];
        out[base + co] = f2u(val);
        ls[nt] += val; ls2[nt] += val*val;
      }
    }
  }
  #pragma unroll
  for (int nt=0; nt<4; nt++){
    ls[nt]  += __shfl_xor(ls[nt], 16);  ls[nt]  += __shfl_xor(ls[nt], 32);
    ls2[nt] += __shfl_xor(ls2[nt], 16); ls2[nt] += __shfl_xor(ls2[nt], 32);
  }
  if (q == 0){
    #pragma unroll
    for (int nt=0; nt<4; nt++){
      wsum[wv_][nt*16 + l16]  = ls[nt];
      wsum2[wv_][nt*16 + l16] = ls2[nt];
    }
  }
  __syncthreads();
  if (tid < 64){
    float a = wsum[0][tid]+wsum[1][tid]+wsum[2][tid]+wsum[3][tid];
    float a2 = wsum2[0][tid]+wsum2[1][tid]+wsum2[2][tid]+wsum2[3][tid];
    atomicAdd(&stats[tid], a);
    atomicAdd(&stats[64+tid], a2);
  }
}

// ---- BN-apply + ReLU + 1x1 conv via bf16 MFMA + tanh (r14 256-thr structure,
//      weights from global bf16 owb); FINAL fuses regression+mean ----
template<bool FINAL>
__global__ __launch_bounds__(256) void k_bnfuse3(const u16* __restrict__ X, const float* __restrict__ stats,
                                                 const void* __restrict__ gam, const void* __restrict__ bet,
                                                 const u16* __restrict__ owb, const void* __restrict__ ob,
                                                 const int* __restrict__ flag, const float* __restrict__ presc,
                                                 u16* __restrict__ out16,
                                                 float* __restrict__ zacc, const void* __restrict__ rw){
  constexpr int SA = 72;
  __shared__ alignas(16) u16 Yl[128*SA];       // reused as Zl in epilogue
  __shared__ float kk[64], bsh[64], obs[64];
  __shared__ float rw_s[64];
  __shared__ float wred[4];
  int isbf = *flag;
  int bid = blockIdx.x;
  int b = bid>>3, v = bid&7;
  const int tid = threadIdx.x;
  const float invM = 1.0f/131072.0f;

  if (tid < 64){
    int ci = tid;
    float mu = stats[ci]*invM;
    float var = stats[64+ci]*invM - mu*mu;
    float rs = rsqrtf(fmaxf(var, 0.f) + 1e-5f);
    float kv = rs*ldmix(gam, ci, isbf);
    kk[ci] = kv;
    bsh[ci] = ldmix(bet, ci, isbf) - mu*kv;
    obs[ci] = ldmix(ob, ci, isbf);
    if (FINAL){
      float s = 0.f;
      #pragma unroll
      for (int f=0; f<8; f++) s += ldmix(rw, ci*8 + f, isbf);
      rw_s[ci] = s;
    }
  }
  __syncthreads();
  {
    uint32_t* Yd = (uint32_t*)Yl;
    const uint32_t* Xg = (const uint32_t*)X;
    for (int u=tid; u<128*32; u+=256){
      int t = u>>5, jd = u&31;
      int ci = jd<<1;
      int rowbase = (((b*128+t)*8+v)) << 6;
      uint32_t pr = Xg[(rowbase>>1) + jd];
      float x0 = bits2f(pr<<16);
      float x1 = bits2f(pr & 0xFFFF0000u);
      float y0 = fmaxf(x0*kk[ci] + bsh[ci], 0.f);
      float y1 = fmaxf(x1*kk[ci+1] + bsh[ci+1], 0.f);
      Yd[t*(SA/2) + jd] = (uint32_t)f2u(y0) | ((uint32_t)f2u(y1) << 16);
    }
  }
  __syncthreads();

  int wv_ = tid >> 6, lane = tid & 63;
  int q = lane >> 4, l16 = lane & 15;
  int tb0 = wv_ * 32;

  f32x4 acc[2][4];
  #pragma unroll
  for (int mt=0; mt<2; mt++)
    #pragma unroll
    for (int nt=0; nt<4; nt++)
      acc[mt][nt] = (f32x4){0.f,0.f,0.f,0.f};

  #pragma unroll
  for (int s=0; s<2; s++){
    int col = 32*s + q*8;
    bf16x8 afr[2], bfr[4];
    #pragma unroll
    for (int mt=0; mt<2; mt++){
      int row = tb0 + mt*16 + l16;
      afr[mt] = *(const bf16x8*)&Yl[row*SA + col];
    }
    #pragma unroll
    for (int nt=0; nt<4; nt++){
      int co = nt*16 + l16;
      bfr[nt] = *(const bf16x8*)&owb[co*64 + col];   // global, L1/L2-hot broadcast
    }
    #pragma unroll
    for (int mt=0; mt<2; mt++)
      #pragma unroll
      for (int nt=0; nt<4; nt++)
        acc[mt][nt] = __builtin_amdgcn_mfma_f32_16x16x32_bf16(afr[mt], bfr[nt], acc[mt][nt], 0, 0, 0);
  }

  __syncthreads();   // MFMA reads of Yl done; reuse as Zl
  #pragma unroll
  for (int mt=0; mt<2; mt++){
    #pragma unroll
    for (int r=0; r<4; r++){
      int t = tb0 + mt*16 + q*4 + r;
      #pragma unroll
      for (int nt=0; nt<4; nt++){
        int co = nt*16 + l16;
        Yl[t*SA + co] = f2u(acc[mt][nt][r] + obs[co]);
      }
    }
  }
  __syncthreads();
  if (!FINAL){
    for (int u=tid; u<8192; u+=256){
      int l = u & 63;
      int idx = u >> 6;
      int co = idx >> 1, thi = idx & 1;
      int t = (thi<<6) + l;
      float z = tanhf(u2f(Yl[t*SA + co]));
      int r = (b<<10) + (co<<4) + (v<<1) + thi;
      if (presc) z *= presc[r];       // lane-uniform
      out16[(r<<6) + l] = f2u(z);
    }
  } else {
    // u-stride 256: idx = (tid>>6) + 4k -> parity(idx) == parity(wv_) constant per wave
    float zsum = 0.f;
    for (int u=tid; u<8192; u+=256){
      int l = u & 63;
      int idx = u >> 6;
      int co = idx >> 1;
      int t = ((idx & 1)<<6) + l;
      float z = tanhf(u2f(Yl[t*SA + co]));
      zsum += z * rw_s[l];
    }
    for (int off=32; off; off>>=1) zsum += __shfl_down(zsum, off);
    if (lane == 0) wred[wv_] = zsum;
    __syncthreads();
    if (tid == 0){
      int base = (b<<3) + ((v&3)<<1);
      atomicAdd(&zacc[base],   wred[0] + wred[2]);   // thi=0 (even waves)
      atomicAdd(&zacc[base+1], wred[1] + wred[3]);   // thi=1 (odd waves)
    }
  }
}

// ---- finish: out[i] = zacc[i]/1024 + sum(rb)/8 ----
__global__ __launch_bounds__(256) void k_fin2(const float* __restrict__ zacc, const void* __restrict__ rb,
                                              const int* __restrict__ flag, void* __restrict__ out){
  int i = blockIdx.x*256 + threadIdx.x;
  if (i >= 1024) return;
  int isbf = *flag;
  float rbs = 0.f;
  #pragma unroll
  for (int f=0; f<8; f++) rbs += ldmix(rb, f, isbf);
  float val = zacc[i]*(1.0f/1024.0f) + rbs*0.125f;
  if (isbf) ((u16*)out)[i] = f2u(val);
  else      ((float*)out)[i] = val;
}

extern "C" void kernel_launch(void* const* d_in, const int* in_sizes, int n_in,
                              void* d_out, int out_size, void* d_ws, size_t ws_size,
                              hipStream_t stream){
  (void)in_sizes; (void)n_in; (void)out_size; (void)ws_size;
  char* p = (char*)d_ws;
  auto alloc = [&](size_t bytes){ void* r = (void*)p; p += (bytes + 255) & ~(size_t)255; return r; };
  u16*   U1   = (u16*)  alloc(sizeof(u16)*(size_t)N_NODES*64);  // Bs16|A16 ; later D16
  u16*   U2   = (u16*)  alloc(sizeof(u16)*(size_t)N_NODES*64);  // E16
  u16*   C16  = (u16*)  alloc(sizeof(u16)*(size_t)N_NODES*64);  // tconv out (bf16)
  int*   deg  = (int*)  alloc(sizeof(int)*N_NODES);
  float* dinv = (float*)alloc(sizeof(float)*N_NODES);
  int*   offs = (int*)  alloc(sizeof(int)*N_NODES);
  int*   adj  = (int*)  alloc(sizeof(int)*N_EDGES);
  int*   H    = (int*)  alloc(sizeof(int)*256*256);
  int*   P    = (int*)  alloc(sizeof(int)*256*256);
  int*   bt   = (int*)  alloc(sizeof(int)*256);
  float* stats1=(float*)alloc(sizeof(float)*128);
  float* stats2=(float*)alloc(sizeof(float)*128);
  int*   flag = (int*)  alloc(sizeof(int)*64);
  u16*   Wtb1 = (u16*)  alloc(sizeof(u16)*96*64);
  float* braw1= (float*)alloc(sizeof(float)*192);
  u16*   Wtb2 = (u16*)  alloc(sizeof(u16)*192*64);
  float* braw2= (float*)alloc(sizeof(float)*192);
  u16*   owb1 = (u16*)  alloc(sizeof(u16)*64*64);
  u16*   owb2 = (u16*)  alloc(sizeof(u16)*64*64);
  float* zacc = (float*)alloc(sizeof(float)*1024);
  uint32_t* ebuf = (uint32_t*)C16;           // alias: C16 dead until tconv1
  u16* Bs16 = U1;                            // N x 32 bf16 (prescaled x)
  u16* A16  = U1 + (size_t)N_NODES*32;       // N x 32 bf16 (agg1 out)
  u16* D16  = U1;                            // N x 64 bf16 (bnfuse1 out, prescaled)
  u16* E16  = U2;                            // N x 64 bf16 (agg2 out)

  const void* x   = d_in[0];
  const int* edge = (const int*)d_in[1];
  const void* g1w = d_in[2];  const void* g1b = d_in[3];
  const void* t1w = d_in[4];  const void* t1b = d_in[5];
  const void* bn1g= d_in[6];  const void* bn1b= d_in[7];
  const void* o1w = d_in[8];  const void* o1b = d_in[9];
  const void* g2w = d_in[10]; const void* g2b = d_in[11];
  const void* t2w = d_in[12]; const void* t2b = d_in[13];
  const void* bn2g= d_in[14]; const void* bn2b= d_in[15];
  const void* o2w = d_in[16]; const void* o2b = d_in[17];
  const void* rw  = d_in[18]; const void* rb  = d_in[19];
  const int* src = edge;
  const int* dst = edge + N_EDGES;

  k_detect<<<1, 256, 0, stream>>>((const uint32_t*)x, flag, stats1, stats2, zacc);

  // graph prep: two-pass counting sort, zero global atomics
  k_hist    <<<256, 256, 0, stream>>>(dst, H);
  k_colscan <<<256, 256, 0, stream>>>(H, P, bt);
  k_scatter2<<<256, 256, 0, stream>>>(src, dst, P, bt, ebuf);
  k_bsort2  <<<256, 512, 0, stream>>>(ebuf, bt, x, flag, adj, offs, deg, dinv, Bs16);

  // weight folding for both layers + bf16 1x1-weight copies
  k_wcombB<<<422, 64, 0, stream>>>(g1w, g1b, t1w, g2w, g2b, t2w, o1w, o2w, flag,
                                   Wtb1, braw1, Wtb2, braw2, owb1, owb2);

  // ---- layer 1 ----
  k_aggp2<32>  <<<N_NODES/64, 256, 0, stream>>>(Bs16, adj, offs, deg, dinv, A16);
  k_tconv3<32> <<<1024, 256, 0, stream>>>(A16, Wtb1, braw1, t1b, flag, C16, stats1);
  k_bnfuse3<false><<<1024, 256, 0, stream>>>(C16, stats1, bn1g, bn1b, owb1, o1b, flag, dinv, D16,
                                             (float*)nullptr, (const void*)nullptr);

  // ---- layer 2 ----
  k_aggp2<64>  <<<N_NODES/32, 256, 0, stream>>>(D16, adj, offs, deg, dinv, E16);
  k_tconv3<64> <<<1024, 256, 0, stream>>>(E16, Wtb2, braw2, t2b, flag, C16, stats2);
  k_bnfuse3<true><<<1024, 256, 0, stream>>>(C16, stats2, bn2g, bn2b, owb2, o2b, flag, (const float*)nullptr,
                                            (u16*)nullptr, zacc, rw);
  k_fin2<<<4, 256, 0, stream>>>(zacc, rb, flag, d_out);
}

// Round 17
// 299.563 us; speedup vs baseline: 2.0820x; 1.0559x over previous
//
#include <hip/hip_runtime.h>
#include <stdint.h>

typedef unsigned short u16;
typedef __attribute__((ext_vector_type(8))) short bf16x8;
typedef __attribute__((ext_vector_type(4))) float f32x4;

static const int N_NODES = 131072;   // B*T*NN = 128*128*8
static const int N_EDGES = 1048576;

__device__ __forceinline__ float u2f(u16 u){
  union{uint32_t i; float f;} w; w.i = ((uint32_t)u)<<16; return w.f;
}
__device__ __forceinline__ u16 f2u(float f){
  union{float f; uint32_t u;} v; v.f=f;
  uint32_t u=v.u;
  u += 0x7fff + ((u>>16)&1);   // round-to-nearest-even
  return (u16)(u>>16);
}
__device__ __forceinline__ float bits2f(uint32_t b){
  union{uint32_t i; float f;} w; w.i = b; return w.f;
}
__device__ __forceinline__ float ldv(const float* p, int i){ return p[i]; }
__device__ __forceinline__ float ldv(const u16* p, int i){ return u2f(p[i]); }
__device__ __forceinline__ void stv(float* p, int i, float v){ p[i]=v; }
__device__ __forceinline__ void stv(u16* p, int i, float v){ p[i]=f2u(v); }
__device__ __forceinline__ float ldmix(const void* p, int i, int isbf){
  return isbf ? u2f(((const u16*)p)[i]) : ((const float*)p)[i];
}

// ---------------- detect dtype + zero all accumulators ----------------
__global__ __launch_bounds__(256) void k_detect(const uint32_t* __restrict__ x, int* __restrict__ flag,
                                                float* __restrict__ stats1, float* __restrict__ stats2,
                                                float* __restrict__ zacc){
  int tid = threadIdx.x;
  for (int i=tid; i<512; i+=256){ stats1[i] = 0.f; stats2[i] = 0.f; }
  for (int i=tid; i<1024; i+=256) zacc[i] = 0.f;
  if (tid == 0){
    int cnt=0;
    for (int i=0;i<256;i++){
      uint32_t e=(x[i]>>7)&0xFFu;
      if (e>=0x6Fu && e<=0x85u) cnt++;
    }
    *flag = (cnt>=128) ? 1 : 0;
  }
}

// ---------------- graph prep: two-pass counting sort, NO global atomics ----------------
__global__ __launch_bounds__(256) void k_hist(const int* __restrict__ dst, int* __restrict__ H){
  __shared__ int h[256];
  int tid = threadIdx.x;
  h[tid] = 0;
  __syncthreads();
  int base = blockIdx.x*4096;
  #pragma unroll
  for (int i=0;i<16;i++){
    int e = base + i*256 + tid;
    atomicAdd(&h[(dst[e] & (N_NODES-1))>>9], 1);
  }
  __syncthreads();
  H[blockIdx.x*256 + tid] = h[tid];
}

__global__ __launch_bounds__(256) void k_colscan(const int* __restrict__ H, int* __restrict__ P,
                                                 int* __restrict__ bt){
  __shared__ int sc[256];
  int b = blockIdx.x, tid = threadIdx.x;
  int v = H[tid*256 + b];
  sc[tid] = v; __syncthreads();
  for (int d=1; d<256; d<<=1){
    int o = (tid>=d) ? sc[tid-d] : 0; __syncthreads();
    sc[tid] += o; __syncthreads();
  }
  P[tid*256 + b] = sc[tid] - v;
  if (tid==255) bt[b] = sc[255];
}

__global__ __launch_bounds__(256) void k_scatter2(const int* __restrict__ src, const int* __restrict__ dst,
                                                  const int* __restrict__ P, const int* __restrict__ bt,
                                                  uint32_t* __restrict__ ebuf){
  __shared__ int cu[256], sc[256];
  int tid = threadIdx.x;
  int v = bt[tid];
  sc[tid] = v; __syncthreads();
  for (int d=1; d<256; d<<=1){
    int o = (tid>=d) ? sc[tid-d] : 0; __syncthreads();
    sc[tid] += o; __syncthreads();
  }
  cu[tid] = (sc[tid] - v) + P[blockIdx.x*256 + tid];   // bb[tid] + P
  __syncthreads();
  int base = blockIdx.x*4096;
  #pragma unroll
  for (int i=0;i<16;i++){
    int e = base + i*256 + tid;
    int s = src[e] & (N_NODES-1);
    int d = dst[e] & (N_NODES-1);
    int pos = atomicAdd(&cu[d>>9], 1);           // LDS atomic only
    ebuf[pos] = (uint32_t)s | ((uint32_t)(d & 511) << 17);
  }
}

// per-bucket counting sort + emit offs/deg/dinv + fused dinv-prescale of x -> bf16 (F=32)
__global__ __launch_bounds__(512) void k_bsort2(const uint32_t* __restrict__ ebuf, const int* __restrict__ bt,
                                                const void* __restrict__ x, const int* __restrict__ flag,
                                                int* __restrict__ adj, int* __restrict__ offs,
                                                int* __restrict__ deg, float* __restrict__ dinv,
                                                u16* __restrict__ Bout){
  __shared__ uint32_t ein[5120], outs[5120];
  __shared__ int hist[512], sc[512], cu[512];
  __shared__ int sct[256];
  __shared__ float dv[512];
  int b = blockIdx.x, tid = threadIdx.x;
  if (tid < 256){ sct[tid] = bt[tid]; }
  __syncthreads();
  for (int d=1; d<256; d<<=1){
    int o = (tid < 256 && tid>=d) ? sct[tid-d] : 0; __syncthreads();
    if (tid < 256) sct[tid] += o; __syncthreads();
  }
  int lo = sct[b] - bt[b], hi = sct[b];
  int cnt = hi - lo; if (cnt > 5120) cnt = 5120; if (cnt < 0) cnt = 0;
  hist[tid] = 0;
  __syncthreads();
  for (int i=tid; i<cnt; i+=512){
    uint32_t p = ebuf[lo+i];
    ein[i] = p;
    atomicAdd(&hist[(p>>17)&511], 1);
  }
  __syncthreads();
  sc[tid] = hist[tid];
  __syncthreads();
  for (int d=1; d<512; d<<=1){
    int v = (tid>=d) ? sc[tid-d] : 0;
    __syncthreads();
    sc[tid] += v;
    __syncthreads();
  }
  {
    int ex = sc[tid] - hist[tid];
    int node = b*512 + tid;
    offs[node] = lo + ex;
    deg[node]  = hist[tid];
    float rs = rsqrtf((float)hist[tid] + 1.0f);
    dinv[node] = rs;
    dv[tid] = rs;
    cu[tid] = ex;
  }
  __syncthreads();
  for (int i=tid; i<cnt; i+=512){
    uint32_t p = ein[i];
    int pos = atomicAdd(&cu[(p>>17)&511], 1);
    outs[pos] = p & 0x1FFFFu;
  }
  __syncthreads();
  for (int i=tid; i<cnt; i+=512) adj[lo+i] = (int)outs[i];
  int isbf = *flag;
  for (int u=tid; u<16384; u+=512){
    int nl = u>>5, c = u&31;
    int idx = ((b<<9) + nl)*32 + c;
    stv(Bout, idx, dv[nl]*ldmix(x, idx, isbf));
  }
}

// ---- GCN aggregation, chunked multi-node-per-wave gather, 8 outstanding loads ----
__device__ __forceinline__ void acc16(uint4 a, float* acc){
  acc[0] += bits2f(a.x<<16); acc[1] += bits2f(a.x&0xFFFF0000u);
  acc[2] += bits2f(a.y<<16); acc[3] += bits2f(a.y&0xFFFF0000u);
  acc[4] += bits2f(a.z<<16); acc[5] += bits2f(a.z&0xFFFF0000u);
  acc[6] += bits2f(a.w<<16); acc[7] += bits2f(a.w&0xFFFF0000u);
}
template<int F>
__global__ __launch_bounds__(256) void k_aggp2(const u16* __restrict__ Xs,
                                               const int* __restrict__ adj, const int* __restrict__ offs,
                                               const int* __restrict__ deg, const float* __restrict__ dinv,
                                               u16* __restrict__ out){
  constexpr int CH  = F/8;            // 16B chunks per row
  constexpr int GPW = 64/CH;          // nodes per wave
  int tid = threadIdx.x;
  int wv = tid>>6, lane = tid&63;
  int g = lane / CH;
  int k = lane % CH;
  int n = blockIdx.x*(4*GPW) + wv*GPW + g;
  int o = offs[n] & (N_EDGES-1);
  int cnt = min(deg[n], 8192);
  const uint4* X4 = (const uint4*)Xs;
  uint4 sv = X4[(size_t)n*CH + k];
  float acc[8] = {0,0,0,0,0,0,0,0};
  acc16(sv, acc);
  int e = 0;
  for (; e+8 <= cnt; e += 8){
    int i0 = adj[o+e+0] & (N_NODES-1);
    int i1 = adj[o+e+1] & (N_NODES-1);
    int i2 = adj[o+e+2] & (N_NODES-1);
    int i3 = adj[o+e+3] & (N_NODES-1);
    int i4 = adj[o+e+4] & (N_NODES-1);
    int i5 = adj[o+e+5] & (N_NODES-1);
    int i6 = adj[o+e+6] & (N_NODES-1);
    int i7 = adj[o+e+7] & (N_NODES-1);
    uint4 a0 = X4[(size_t)i0*CH + k];
    uint4 a1 = X4[(size_t)i1*CH + k];
    uint4 a2 = X4[(size_t)i2*CH + k];
    uint4 a3 = X4[(size_t)i3*CH + k];
    uint4 a4 = X4[(size_t)i4*CH + k];
    uint4 a5 = X4[(size_t)i5*CH + k];
    uint4 a6 = X4[(size_t)i6*CH + k];
    uint4 a7 = X4[(size_t)i7*CH + k];
    acc16(a0, acc); acc16(a1, acc); acc16(a2, acc); acc16(a3, acc);
    acc16(a4, acc); acc16(a5, acc); acc16(a6, acc); acc16(a7, acc);
  }
  if (e+4 <= cnt){
    int i0 = adj[o+e+0] & (N_NODES-1);
    int i1 = adj[o+e+1] & (N_NODES-1);
    int i2 = adj[o+e+2] & (N_NODES-1);
    int i3 = adj[o+e+3] & (N_NODES-1);
    uint4 a0 = X4[(size_t)i0*CH + k];
    uint4 a1 = X4[(size_t)i1*CH + k];
    uint4 a2 = X4[(size_t)i2*CH + k];
    uint4 a3 = X4[(size_t)i3*CH + k];
    acc16(a0, acc); acc16(a1, acc); acc16(a2, acc); acc16(a3, acc);
    e += 4;
  }
  for (; e < cnt; e++){
    int s = adj[o+e] & (N_NODES-1);
    uint4 a = X4[(size_t)s*CH + k];
    acc16(a, acc);
  }
  float dv = dinv[n];
  uint4 r;
  r.x = (uint32_t)f2u(acc[0]*dv) | ((uint32_t)f2u(acc[1]*dv) << 16);
  r.y = (uint32_t)f2u(acc[2]*dv) | ((uint32_t)f2u(acc[3]*dv) << 16);
  r.z = (uint32_t)f2u(acc[4]*dv) | ((uint32_t)f2u(acc[5]*dv) << 16);
  r.w = (uint32_t)f2u(acc[6]*dv) | ((uint32_t)f2u(acc[7]*dv) << 16);
  ((uint4*)out)[(size_t)n*CH + k] = r;
}

// ---- combined weight-fold for BOTH layers + bf16 copies of 1x1 weights ----
__device__ __forceinline__ void wcomb_one(int Kin, const void* gW, const void* gb, const void* tw,
                                          int isbf, u16* Wtb, float* braw, int r, int co){
  if (r < 3*Kin){
    int k = r / Kin, j = r - (r/Kin)*Kin;
    float acc = 0.f;
    for (int c=0; c<64; c++)
      acc += ldmix(gW, j*64+c, isbf) * ldmix(tw, co*192 + c*3 + k, isbf);
    Wtb[co*(3*Kin) + r] = f2u(acc);
  } else {
    int k = r - 3*Kin;
    float acc = 0.f;
    for (int c=0; c<64; c++)
      acc += ldmix(gb, c, isbf) * ldmix(tw, co*192 + c*3 + k, isbf);
    braw[k*64 + co] = acc;
  }
}
__global__ __launch_bounds__(64) void k_wcombB(const void* __restrict__ g1w, const void* __restrict__ g1b,
                                               const void* __restrict__ t1w,
                                               const void* __restrict__ g2w, const void* __restrict__ g2b,
                                               const void* __restrict__ t2w,
                                               const void* __restrict__ o1w, const void* __restrict__ o2w,
                                               const int* __restrict__ flag,
                                               u16* __restrict__ Wtb1, float* __restrict__ braw1,
                                               u16* __restrict__ Wtb2, float* __restrict__ braw2,
                                               u16* __restrict__ owb1, u16* __restrict__ owb2){
  int isbf = *flag;
  int r = blockIdx.x, co = threadIdx.x;
  if (r < 99) wcomb_one(32, g1w, g1b, t1w, isbf, Wtb1, braw1, r, co);
  else if (r < 294) wcomb_one(64, g2w, g2b, t2w, isbf, Wtb2, braw2, r-99, co);
  else if (r < 358){
    int row = r - 294;
    owb1[row*64 + co] = f2u(ldmix(o1w, row*64 + co, isbf));
  } else {
    int row = r - 358;
    owb2[row*64 + co] = f2u(ldmix(o2w, row*64 + co, isbf));
  }
}

// ---- fused linear+temporal-conv via bf16 MFMA + banked BN-stats ----
// grid 2048: block = (b, v, t-half). 256 thr / 4 waves, wave = 16t x 64co.
template<int Kin>
__global__ __launch_bounds__(256) void k_tconv3(const u16* __restrict__ A, const u16* __restrict__ Wtb,
                                                const float* __restrict__ braw, const void* __restrict__ tb,
                                                const int* __restrict__ flag, u16* __restrict__ out,
                                                float* __restrict__ stats){
  constexpr int K  = 3*Kin;
  constexpr int SA = Kin + 8;
  constexpr int JH = Kin/2;
  constexpr int JL = (Kin==64) ? 5 : 4;
  __shared__ alignas(16) u16 At[66*SA];
  __shared__ float ball[64], bs0[64], bs2[64];
  __shared__ float wsum[4][64], wsum2[4][64];

  int isbf = *flag;
  int bid = blockIdx.x;
  int b = bid>>4, rem = bid&15, v = rem>>1, th = rem&1;
  const int tid = threadIdx.x;

  if (tid < 64){
    float b0=braw[tid], b1=braw[64+tid], b2=braw[128+tid];
    ball[tid] = ldmix(tb, tid, isbf) + b0 + b1 + b2;
    bs0[tid] = b0; bs2[tid] = b2;
  }
  {
    uint32_t* Ad = (uint32_t*)At;
    const uint32_t* Ag = (const uint32_t*)A;
    for (int u=tid; u<66*JH; u+=256){
      int ls = u >> JL, jd = u & (JH-1);
      int t = th*64 + ls - 1;
      uint32_t pack = 0;
      if (t >= 0 && t < 128)
        pack = Ag[((((b*128+t)*8+v))*Kin >> 1) + jd];
      Ad[ls*(SA/2) + jd] = pack;
    }
  }
  __syncthreads();

  int wv_ = tid >> 6, lane = tid & 63;
  int q = lane >> 4, l16 = lane & 15;
  int ltb0 = wv_ * 16;

  f32x4 acc[4];
  #pragma unroll
  for (int nt=0; nt<4; nt++) acc[nt] = (f32x4){0.f,0.f,0.f,0.f};

  #pragma unroll
  for (int s=0; s<K/32; s++){
    int kk = (32*s)/Kin;
    int j0 = 32*s - kk*Kin;
    int col = j0 + q*8;
    bf16x8 afr = *(const bf16x8*)&At[(ltb0 + l16 + kk)*SA + col];
    bf16x8 bfr[4];
    #pragma unroll
    for (int nt=0; nt<4; nt++){
      int co = nt*16 + l16;
      bfr[nt] = *(const bf16x8*)&Wtb[co*K + 32*s + q*8];   // global, L1/L2-hot broadcast
    }
    #pragma unroll
    for (int nt=0; nt<4; nt++)
      acc[nt] = __builtin_amdgcn_mfma_f32_16x16x32_bf16(afr, bfr[nt], acc[nt], 0, 0, 0);
  }

  float ls_[4] = {0,0,0,0}, ls2_[4] = {0,0,0,0};
  #pragma unroll
  for (int r=0; r<4; r++){
    int t = th*64 + ltb0 + q*4 + r;
    int base = (((b*128+t)*8+v)) << 6;
    #pragma unroll
    for (int nt=0; nt<4; nt++){
      int co = nt*16 + l16;
      float val = acc[nt][r] + ball[co];
      if (t == 0)   val -= bs0[co];
      if (t == 127) val -= bs2[co];
      out[base + co] = f2u(val);
      ls_[nt] += val; ls2_[nt] += val*val;
    }
  }
  #pragma unroll
  for (int nt=0; nt<4; nt++){
    ls_[nt]  += __shfl_xor(ls_[nt], 16);  ls_[nt]  += __shfl_xor(ls_[nt], 32);
    ls2_[nt] += __shfl_xor(ls2_[nt], 16); ls2_[nt] += __shfl_xor(ls2_[nt], 32);
  }
  if (q == 0){
    #pragma unroll
    for (int nt=0; nt<4; nt++){
      wsum[wv_][nt*16 + l16]  = ls_[nt];
      wsum2[wv_][nt*16 + l16] = ls2_[nt];
    }
  }
  __syncthreads();
  if (tid < 64){
    float a = wsum[0][tid]+wsum[1][tid]+wsum[2][tid]+wsum[3][tid];
    float a2 = wsum2[0][tid]+wsum2[1][tid]+wsum2[2][tid]+wsum2[3][tid];
    int bank = (bid & 3) * 128;       // 4-way banked to cut atomic contention
    atomicAdd(&stats[bank + tid], a);
    atomicAdd(&stats[bank + 64 + tid], a2);
  }
}

// ---- BN-apply + ReLU + 1x1 conv via bf16 MFMA + tanh; grid 2048 (b,v,t-half) ----
template<bool FINAL>
__global__ __launch_bounds__(256) void k_bnfuse3(const u16* __restrict__ X, const float* __restrict__ stats,
                                                 const void* __restrict__ gam, const void* __restrict__ bet,
                                                 const u16* __restrict__ owb, const void* __restrict__ ob,
                                                 const int* __restrict__ flag, const float* __restrict__ presc,
                                                 u16* __restrict__ out16,
                                                 float* __restrict__ zacc, const void* __restrict__ rw){
  constexpr int SA = 72;
  __shared__ alignas(16) u16 Yl[64*SA];        // reused as Zl in epilogue
  __shared__ float kk[64], bsh[64], obs[64];
  __shared__ float rw_s[64];
  __shared__ float wred[4];
  int isbf = *flag;
  int bid = blockIdx.x;
  int b = bid>>4, rem = bid&15, v = rem>>1, th = rem&1;
  const int tid = threadIdx.x;
  const float invM = 1.0f/131072.0f;

  if (tid < 64){
    int ci = tid;
    float s1 = stats[ci] + stats[128+ci] + stats[256+ci] + stats[384+ci];
    float s2 = stats[64+ci] + stats[192+ci] + stats[320+ci] + stats[448+ci];
    float mu = s1*invM;
    float var = s2*invM - mu*mu;
    float rs = rsqrtf(fmaxf(var, 0.f) + 1e-5f);
    float kv = rs*ldmix(gam, ci, isbf);
    kk[ci] = kv;
    bsh[ci] = ldmix(bet, ci, isbf) - mu*kv;
    obs[ci] = ldmix(ob, ci, isbf);
    if (FINAL){
      float s = 0.f;
      #pragma unroll
      for (int f=0; f<8; f++) s += ldmix(rw, ci*8 + f, isbf);
      rw_s[ci] = s;
    }
  }
  __syncthreads();
  {
    uint32_t* Yd = (uint32_t*)Yl;
    const uint32_t* Xg = (const uint32_t*)X;
    for (int u=tid; u<64*32; u+=256){
      int lt = u>>5, jd = u&31;
      int ci = jd<<1;
      int t = th*64 + lt;
      int rowbase = (((b*128+t)*8+v)) << 6;
      uint32_t pr = Xg[(rowbase>>1) + jd];
      float x0 = bits2f(pr<<16);
      float x1 = bits2f(pr & 0xFFFF0000u);
      float y0 = fmaxf(x0*kk[ci] + bsh[ci], 0.f);
      float y1 = fmaxf(x1*kk[ci+1] + bsh[ci+1], 0.f);
      Yd[lt*(SA/2) + jd] = (uint32_t)f2u(y0) | ((uint32_t)f2u(y1) << 16);
    }
  }
  __syncthreads();

  int wv_ = tid >> 6, lane = tid & 63;
  int q = lane >> 4, l16 = lane & 15;
  int ltb0 = wv_ * 16;

  f32x4 acc[4];
  #pragma unroll
  for (int nt=0; nt<4; nt++) acc[nt] = (f32x4){0.f,0.f,0.f,0.f};

  #pragma unroll
  for (int s=0; s<2; s++){
    int col = 32*s + q*8;
    bf16x8 afr = *(const bf16x8*)&Yl[(ltb0 + l16)*SA + col];
    bf16x8 bfr[4];
    #pragma unroll
    for (int nt=0; nt<4; nt++){
      int co = nt*16 + l16;
      bfr[nt] = *(const bf16x8*)&owb[co*64 + col];   // global, L1/L2-hot broadcast
    }
    #pragma unroll
    for (int nt=0; nt<4; nt++)
      acc[nt] = __builtin_amdgcn_mfma_f32_16x16x32_bf16(afr, bfr[nt], acc[nt], 0, 0, 0);
  }

  __syncthreads();   // MFMA reads of Yl done; reuse as Zl
  #pragma unroll
  for (int r=0; r<4; r++){
    int lt = ltb0 + q*4 + r;
    #pragma unroll
    for (int nt=0; nt<4; nt++){
      int co = nt*16 + l16;
      Yl[lt*SA + co] = f2u(acc[nt][r] + obs[co]);
    }
  }
  __syncthreads();
  if (!FINAL){
    // element (co, l): from t = th*64 + l; write row r = b*1024+co*16+v*2+th, col l
    for (int u=tid; u<4096; u+=256){
      int l = u & 63;
      int co = u >> 6;
      float z = tanhf(u2f(Yl[l*SA + co]));
      int r = (b<<10) + (co<<4) + (v<<1) + th;
      if (presc) z *= presc[r];       // lane-uniform
      out16[(r<<6) + l] = f2u(z);
    }
  } else {
    float zsum = 0.f;
    for (int u=tid; u<4096; u+=256){
      int l = u & 63;
      int co = u >> 6;
      float z = tanhf(u2f(Yl[l*SA + co]));
      zsum += z * rw_s[l];
    }
    for (int off=32; off; off>>=1) zsum += __shfl_down(zsum, off);
    if (lane == 0) wred[wv_] = zsum;
    __syncthreads();
    if (tid == 0){
      int base = (b<<3) + ((v&3)<<1) + th;
      atomicAdd(&zacc[base], wred[0] + wred[1] + wred[2] + wred[3]);
    }
  }
}

// ---- finish: out[i] = zacc[i]/1024 + sum(rb)/8 ----
__global__ __launch_bounds__(256) void k_fin2(const float* __restrict__ zacc, const void* __restrict__ rb,
                                              const int* __restrict__ flag, void* __restrict__ out){
  int i = blockIdx.x*256 + threadIdx.x;
  if (i >= 1024) return;
  int isbf = *flag;
  float rbs = 0.f;
  #pragma unroll
  for (int f=0; f<8; f++) rbs += ldmix(rb, f, isbf);
  float val = zacc[i]*(1.0f/1024.0f) + rbs*0.125f;
  if (isbf) ((u16*)out)[i] = f2u(val);
  else      ((float*)out)[i] = val;
}

extern "C" void kernel_launch(void* const* d_in, const int* in_sizes, int n_in,
                              void* d_out, int out_size, void* d_ws, size_t ws_size,
                              hipStream_t stream){
  (void)in_sizes; (void)n_in; (void)out_size; (void)ws_size;
  char* p = (char*)d_ws;
  auto alloc = [&](size_t bytes){ void* r = (void*)p; p += (bytes + 255) & ~(size_t)255; return r; };
  u16*   U1   = (u16*)  alloc(sizeof(u16)*(size_t)N_NODES*64);  // Bs16|A16 ; later D16
  u16*   U2   = (u16*)  alloc(sizeof(u16)*(size_t)N_NODES*64);  // E16
  u16*   C16  = (u16*)  alloc(sizeof(u16)*(size_t)N_NODES*64);  // tconv out (bf16)
  int*   deg  = (int*)  alloc(sizeof(int)*N_NODES);
  float* dinv = (float*)alloc(sizeof(float)*N_NODES);
  int*   offs = (int*)  alloc(sizeof(int)*N_NODES);
  int*   adj  = (int*)  alloc(sizeof(int)*N_EDGES);
  int*   H    = (int*)  alloc(sizeof(int)*256*256);
  int*   P    = (int*)  alloc(sizeof(int)*256*256);
  int*   bt   = (int*)  alloc(sizeof(int)*256);
  float* stats1=(float*)alloc(sizeof(float)*512);
  float* stats2=(float*)alloc(sizeof(float)*512);
  int*   flag = (int*)  alloc(sizeof(int)*64);
  u16*   Wtb1 = (u16*)  alloc(sizeof(u16)*96*64);
  float* braw1= (float*)alloc(sizeof(float)*192);
  u16*   Wtb2 = (u16*)  alloc(sizeof(u16)*192*64);
  float* braw2= (float*)alloc(sizeof(float)*192);
  u16*   owb1 = (u16*)  alloc(sizeof(u16)*64*64);
  u16*   owb2 = (u16*)  alloc(sizeof(u16)*64*64);
  float* zacc = (float*)alloc(sizeof(float)*1024);
  uint32_t* ebuf = (uint32_t*)C16;           // alias: C16 dead until tconv1
  u16* Bs16 = U1;                            // N x 32 bf16 (prescaled x)
  u16* A16  = U1 + (size_t)N_NODES*32;       // N x 32 bf16 (agg1 out)
  u16* D16  = U1;                            // N x 64 bf16 (bnfuse1 out, prescaled)
  u16* E16  = U2;                            // N x 64 bf16 (agg2 out)

  const void* x   = d_in[0];
  const int* edge = (const int*)d_in[1];
  const void* g1w = d_in[2];  const void* g1b = d_in[3];
  const void* t1w = d_in[4];  const void* t1b = d_in[5];
  const void* bn1g= d_in[6];  const void* bn1b= d_in[7];
  const void* o1w = d_in[8];  const void* o1b = d_in[9];
  const void* g2w = d_in[10]; const void* g2b = d_in[11];
  const void* t2w = d_in[12]; const void* t2b = d_in[13];
  const void* bn2g= d_in[14]; const void* bn2b= d_in[15];
  const void* o2w = d_in[16]; const void* o2b = d_in[17];
  const void* rw  = d_in[18]; const void* rb  = d_in[19];
  const int* src = edge;
  const int* dst = edge + N_EDGES;

  k_detect<<<1, 256, 0, stream>>>((const uint32_t*)x, flag, stats1, stats2, zacc);

  // graph prep: two-pass counting sort, zero global atomics
  k_hist    <<<256, 256, 0, stream>>>(dst, H);
  k_colscan <<<256, 256, 0, stream>>>(H, P, bt);
  k_scatter2<<<256, 256, 0, stream>>>(src, dst, P, bt, ebuf);
  k_bsort2  <<<256, 512, 0, stream>>>(ebuf, bt, x, flag, adj, offs, deg, dinv, Bs16);

  // weight folding for both layers + bf16 1x1-weight copies
  k_wcombB<<<422, 64, 0, stream>>>(g1w, g1b, t1w, g2w, g2b, t2w, o1w, o2w, flag,
                                   Wtb1, braw1, Wtb2, braw2, owb1, owb2);

  // ---- layer 1 ----
  k_aggp2<32>  <<<N_NODES/64, 256, 0, stream>>>(Bs16, adj, offs, deg, dinv, A16);
  k_tconv3<32> <<<2048, 256, 0, stream>>>(A16, Wtb1, braw1, t1b, flag, C16, stats1);
  k_bnfuse3<false><<<2048, 256, 0, stream>>>(C16, stats1, bn1g, bn1b, owb1, o1b, flag, dinv, D16,
                                             (float*)nullptr, (const void*)nullptr);

  // ---- layer 2 ----
  k_aggp2<64>  <<<N_NODES/32, 256, 0, stream>>>(D16, adj, offs, deg, dinv, E16);
  k_tconv3<64> <<<2048, 256, 0, stream>>>(E16, Wtb2, braw2, t2b, flag, C16, stats2);
  k_bnfuse3<true><<<2048, 256, 0, stream>>>(C16, stats2, bn2g, bn2b, owb2, o2b, flag, (const float*)nullptr,
                                            (u16*)nullptr, zacc, rw);
  k_fin2<<<4, 256, 0, stream>>>(zacc, rb, flag, d_out);
}